// Round 16
// baseline (326.629 us; speedup 1.0000x reference)
//
#include <hip/hip_runtime.h>

typedef __attribute__((ext_vector_type(8))) short short8;
typedef __attribute__((ext_vector_type(4))) short s16x4;
typedef __attribute__((ext_vector_type(4))) float f32x4;
typedef unsigned short u16;
typedef unsigned int u32;

__device__ __forceinline__ u16 f2bf(float f) {
  union { float f; unsigned int u; } v; v.f = f;
  unsigned int r = (v.u + 0x7FFFu + ((v.u >> 16) & 1u)) >> 16;
  return (u16)r;
}
__device__ __forceinline__ float bf2f(u16 b) {
  union { unsigned int u; float f; } v; v.u = ((unsigned int)b) << 16;
  return v.f;
}
__device__ __forceinline__ void load_lds16(const void* g, void* l) {
  __builtin_amdgcn_global_load_lds((const __attribute__((address_space(1))) void*)g,
                                   (__attribute__((address_space(3))) void*)l, 16, 0, 0);
}

// ---------------- fp32 -> bf16 elementwise ----------------
__global__ void cvt_f32_bf16_kernel(const float* __restrict__ in, u16* __restrict__ out, int n4) {
  int i = blockIdx.x * blockDim.x + threadIdx.x;
  if (i >= n4) return;
  float4 v = ((const float4*)in)[i];
  ushort4 o;
  o.x = f2bf(v.x); o.y = f2bf(v.y); o.z = f2bf(v.z); o.w = f2bf(v.w);
  ((ushort4*)out)[i] = o;
}

// out_f32 = bf16(p0) + bf16(p1)
__global__ void combine2_f32_kernel(float* __restrict__ out, const u16* __restrict__ p0,
                                    const u16* __restrict__ p1, int n8) {
  int i = blockIdx.x * blockDim.x + threadIdx.x;
  if (i >= n8) return;
  short8 a = ((const short8*)p0)[i];
  short8 b = ((const short8*)p1)[i];
  float4 o0, o1;
  o0.x = bf2f((u16)a[0]) + bf2f((u16)b[0]);
  o0.y = bf2f((u16)a[1]) + bf2f((u16)b[1]);
  o0.z = bf2f((u16)a[2]) + bf2f((u16)b[2]);
  o0.w = bf2f((u16)a[3]) + bf2f((u16)b[3]);
  o1.x = bf2f((u16)a[4]) + bf2f((u16)b[4]);
  o1.y = bf2f((u16)a[5]) + bf2f((u16)b[5]);
  o1.z = bf2f((u16)a[6]) + bf2f((u16)b[6]);
  o1.w = bf2f((u16)a[7]) + bf2f((u16)b[7]);
  ((float4*)out)[i * 2]     = o0;
  ((float4*)out)[i * 2 + 1] = o1;
}

// sum 4 KV split-K partials -> Kb [2048][1024] and Vt [1024][2048]
__global__ void combine_kv_kernel(const u16* __restrict__ PKV, u16* __restrict__ Kb,
                                  u16* __restrict__ Vt) {
  int i = blockIdx.x * blockDim.x + threadIdx.x;   // 0..524287
  const u16* src; u16* dst; size_t off;
  if (i < 262144) { off = (size_t)i; dst = Kb; src = PKV; }
  else            { off = (size_t)(i - 262144); dst = Vt; src = PKV + 2097152; }
  float s[8] = {0.f, 0.f, 0.f, 0.f, 0.f, 0.f, 0.f, 0.f};
#pragma unroll
  for (int z = 0; z < 4; ++z) {
    short8 v = *(const short8*)(src + (size_t)z * 4194304 + off * 8);
#pragma unroll
    for (int j = 0; j < 8; ++j) s[j] += bf2f((u16)v[j]);
  }
  short8 o;
#pragma unroll
  for (int j = 0; j < 8; ++j) o[j] = (short)f2bf(s[j]);
  ((short8*)dst)[off] = o;
}

// ---------------- 64x64-tile fp32 [K][N] -> bf16 [N][K] transpose core ----------------
__device__ __forceinline__ void tconv64_tile(const float* __restrict__ W, u16* __restrict__ Wt,
                                             int K, int N, int nb, int kb, int tid) {
  __shared__ float tile[64][65];
  int tx = tid & 15, ty = tid >> 4;          // 16 x 16
  const float* src = W + (size_t)(kb + ty) * N + nb + tx * 4;
#pragma unroll
  for (int i = 0; i < 4; ++i) {
    float4 v = *(const float4*)(src + (size_t)i * 16 * N);
    tile[ty + i * 16][tx * 4 + 0] = v.x;
    tile[ty + i * 16][tx * 4 + 1] = v.y;
    tile[ty + i * 16][tx * 4 + 2] = v.z;
    tile[ty + i * 16][tx * 4 + 3] = v.w;
  }
  __syncthreads();
  u16* dst = Wt + (size_t)(nb + ty) * K + kb + tx * 4;
#pragma unroll
  for (int i = 0; i < 4; ++i) {
    s16x4 o;
#pragma unroll
    for (int j = 0; j < 4; ++j) o[j] = (short)f2bf(tile[tx * 4 + j][ty + i * 16]);
    *(s16x4*)(dst + (size_t)i * 16 * K) = o;
  }
}

// fused Wq/Wk/Wv transpose-convert (64x64 tiles)
__global__ void tconv3_kernel(const float* __restrict__ Wq, const float* __restrict__ Wk,
                              const float* __restrict__ Wv, u16* __restrict__ WqT,
                              u16* __restrict__ WkvT) {
  int id = blockIdx.x;
  if (id < 4096)      tconv64_tile(Wq, WqT, 4096, 4096, (id & 63) * 64, (id >> 6) * 64, threadIdx.x);
  else if (id < 5120) { int t = id - 4096; tconv64_tile(Wk, WkvT, 4096, 1024, (t & 15) * 64, (t >> 4) * 64, threadIdx.x); }
  else                { int t = id - 5120; tconv64_tile(Wv, WkvT + (size_t)1024 * 4096, 4096, 1024, (t & 15) * 64, (t >> 4) * 64, threadIdx.x); }
}

// single-weight transpose (Wo)
__global__ void tconv1_kernel(const float* __restrict__ W, u16* __restrict__ Wt) {
  int id = blockIdx.x;
  tconv64_tile(W, Wt, 4096, 4096, (id & 63) * 64, (id >> 6) * 64, threadIdx.x);
}

// ---------------- fused RoPE: Q = rope(P0q+P1q) in-place on P0q; K in-place ----------------
__global__ void rope_kernel(u16* __restrict__ Qb, const u16* __restrict__ Qp1, u16* __restrict__ Kb) {
  int idx = blockIdx.x * blockDim.x + threadIdx.x;
  int j, t, hh, s;
  if (idx < 4194304) {
    j = idx & 63; t = idx >> 6; hh = t & 31; s = t >> 5;
    float invf = exp2f(-(float)j * (13.287712379549449f / 64.0f));
    float ang = (float)s * invf;
    float sn, cs;
    sincosf(ang, &sn, &cs);
    size_t base = (size_t)s * 4096 + hh * 128 + j;
    u16* p = Qb + base;
    const u16* p1 = Qp1 + base;
    float a = bf2f(p[0]) + bf2f(p1[0]);
    float b = bf2f(p[64]) + bf2f(p1[64]);
    const float scale = 0.12751781828987514f;   // log2(e)/sqrt(128)
    p[0]  = f2bf((a * cs - b * sn) * scale);
    p[64] = f2bf((b * cs + a * sn) * scale);
  } else {
    int id = idx - 4194304;
    j = id & 63; t = id >> 6; hh = t & 7; s = t >> 3;
    float invf = exp2f(-(float)j * (13.287712379549449f / 64.0f));
    float ang = (float)s * invf;
    float sn, cs;
    sincosf(ang, &sn, &cs);
    u16* p = Kb + (size_t)s * 1024 + hh * 128 + j;
    float a = bf2f(p[0]), b = bf2f(p[64]);
    p[0]  = f2bf(a * cs - b * sn);
    p[64] = f2bf(b * cs + a * sn);
  }
}

// ---------------- 256x256 split-K bf16 GEMM, 8-phase half-tile pipeline ----------------
// LDS [buf][mat][kh][256][32] (128KB). 8 waves (2M x 4N), per-wave 128x64 (acc[8][4]).
// Per 8-phase iteration: 2 K-tiles; each phase = {ds_read quadrant frags,
// stage ONE half-tile (2 global_load_lds), barrier, lgkm0, 16 MFMA, barrier}.
// K-half recycling: after (fm-lo,kb0)+(fm-hi,kb0) phases, the kh0 region is
// fully consumed by ALL waves -> restage per-phase. vmcnt(6)@ph4, vmcnt(4)@ph7.
// KVEPI=0: write bf16 partial to (z? C1 : C0). KVEPI=1: KV epilogue into arena C0.
template<int KVEPI>
__global__ __launch_bounds__(512, 1) void gemm8p_kernel(
    const u16* __restrict__ A, const u16* __restrict__ B,
    u16* __restrict__ C0, u16* __restrict__ C1, int N, int K, int KH) {
  __shared__ u16 Sh[2][2][2][8192];   // [buf][mat(0=A,1=B)][kh][256*32]
  int tid = threadIdx.x, lane = tid & 63, wid = tid >> 6;
  int wr = wid >> 2, wc = wid & 3;
  int g = lane >> 4, q = lane & 15;
  int id = blockIdx.z * gridDim.x * gridDim.y + blockIdx.y * gridDim.x + blockIdx.x;
  int tot = gridDim.x * gridDim.y * gridDim.z;
  int swz = (id & 7) * (tot >> 3) + (id >> 3);
  int perh = gridDim.x * gridDim.y;
  int z = swz / perh, rem = swz % perh;
  int m0 = (rem / gridDim.x) * 256, n0 = (rem % gridDim.x) * 256;
  int k0 = z * KH;
  f32x4 acc[8][4];
#pragma unroll
  for (int i = 0; i < 8; ++i)
#pragma unroll
    for (int j = 0; j < 4; ++j) acc[i][j] = (f32x4){0.f, 0.f, 0.f, 0.f};
  int srow = tid >> 2;            // 0..127
  int scol = (tid & 3) * 8;       // within 32-wide k-half
  const u16* ga = A + (size_t)(m0 + srow) * K + k0 + scol;
  const u16* gb = B + (size_t)(n0 + srow) * K + k0 + scol;
  int arow = wr * 128 + q;
  int brow = wc * 64 + q;
  int nt = KH >> 6;               // even

  auto stageH = [&](int b, int mat, int h, int t) {
    const u16* gp = (mat ? gb : ga) + t * 64 + h * 32;
    char* dst = (char*)&Sh[b][mat][h][0];
#pragma unroll
    for (int it = 0; it < 2; ++it)
      load_lds16(gp + (size_t)it * 128 * K, dst + it * 8192 + tid * 16);
  };
  auto readA = [&](int b, int h, int fb, short8 (&af)[4]) {
    const u16* s = &Sh[b][0][h][0];
#pragma unroll
    for (int m = 0; m < 4; ++m)
      af[m] = *(const short8*)&s[(arow + (fb + m) * 16) * 32 + g * 8];
  };
  auto readB = [&](int b, int h, short8 (&bf)[4]) {
    const u16* s = &Sh[b][1][h][0];
#pragma unroll
    for (int n = 0; n < 4; ++n)
      bf[n] = *(const short8*)&s[(brow + n * 16) * 32 + g * 8];
  };

  // prologue: tile0 complete (buf0), tile1 kh0 (buf1)
  stageH(0, 0, 0, 0); stageH(0, 1, 0, 0);
  stageH(0, 0, 1, 0); stageH(0, 1, 1, 0);
  stageH(1, 0, 0, 1); stageH(1, 1, 0, 1);
  asm volatile("s_waitcnt vmcnt(4)" ::: "memory");   // tile0 fully landed
  __builtin_amdgcn_s_barrier();

#define PHASE(FB)                                                        \
  __builtin_amdgcn_s_barrier();                                          \
  asm volatile("s_waitcnt lgkmcnt(0)" ::: "memory");                     \
  __builtin_amdgcn_sched_barrier(0);                                     \
  __builtin_amdgcn_s_setprio(1);                                         \
  _Pragma("unroll")                                                      \
  for (int m = 0; m < 4; ++m)                                            \
    _Pragma("unroll")                                                    \
    for (int n = 0; n < 4; ++n)                                          \
      acc[FB + m][n] = __builtin_amdgcn_mfma_f32_16x16x32_bf16(          \
          af[m], bf[n], acc[FB + m][n], 0, 0, 0);                        \
  __builtin_amdgcn_s_setprio(0);                                         \
  __builtin_amdgcn_s_barrier();

  for (int t = 0; t < nt; t += 2) {
    bool s2 = (t + 2 < nt);
    short8 af[4], bf[4];
    // ph0: tile t, kb0, fm0-3  | stage A(t+1).kh1
    readA(0, 0, 0, af); readB(0, 0, bf);
    stageH(1, 0, 1, t + 1);
    PHASE(0)
    // ph1: tile t, kb0, fm4-7 (B reuse) | stage B(t+1).kh1
    readA(0, 0, 4, af);
    stageH(1, 1, 1, t + 1);
    PHASE(4)
    // ph2: tile t, kb1, fm0-3 | stage A(t+2).kh0 (buf0.kh0 fully consumed)
    readA(0, 1, 0, af); readB(0, 1, bf);
    if (s2) stageH(0, 0, 0, t + 2);
    PHASE(0)
    // ph3: tile t, kb1, fm4-7 | stage B(t+2).kh0
    readA(0, 1, 4, af);
    if (s2) stageH(0, 1, 0, t + 2);
    PHASE(4)
    // ph4: tile t+1, kb0, fm0-3 | stage A(t+2).kh1 ; counted vmcnt
    readA(1, 0, 0, af); readB(1, 0, bf);
    if (s2) { stageH(0, 0, 1, t + 2); asm volatile("s_waitcnt vmcnt(6)" ::: "memory"); }
    else    { asm volatile("s_waitcnt vmcnt(0)" ::: "memory"); }
    PHASE(0)
    // ph5: tile t+1, kb0, fm4-7 | stage B(t+2).kh1
    readA(1, 0, 4, af);
    if (s2) stageH(0, 1, 1, t + 2);
    PHASE(4)
    // ph6: tile t+1, kb1, fm0-3 | stage A(t+3).kh0 (buf1.kh0 consumed)
    readA(1, 1, 0, af); readB(1, 1, bf);
    if (s2) stageH(1, 0, 0, t + 3);
    PHASE(0)
    // ph7: tile t+1, kb1, fm4-7 | stage B(t+3).kh0 ; counted vmcnt
    readA(1, 1, 4, af);
    if (s2) { stageH(1, 1, 0, t + 3); asm volatile("s_waitcnt vmcnt(4)" ::: "memory"); }
    PHASE(4)
  }
#undef PHASE

  int crow = m0 + wr * 128 + g * 4;
  int ccol = n0 + wc * 64 + q;
  if (KVEPI) {
    u16* Kpart = C0 + (size_t)z * 4194304;
    u16* Vpart = Kpart + 2097152;
    if (n0 < 1024) {
#pragma unroll
      for (int fm = 0; fm < 8; ++fm)
#pragma unroll
        for (int fn = 0; fn < 4; ++fn)
#pragma unroll
          for (int r = 0; r < 4; ++r)
            Kpart[(size_t)(crow + fm * 16 + r) * 1024 + ccol + fn * 16] = f2bf(acc[fm][fn][r]);
    } else {
#pragma unroll
      for (int fn = 0; fn < 4; ++fn) {
        int vcol = ccol + fn * 16 - 1024;
#pragma unroll
        for (int fm = 0; fm < 8; ++fm) {
          s16x4 o;
#pragma unroll
          for (int r = 0; r < 4; ++r) o[r] = (short)f2bf(acc[fm][fn][r]);
          *(s16x4*)(Vpart + (size_t)vcol * 2048 + crow + fm * 16) = o;
        }
      }
    }
  } else {
    u16* dst = z ? C1 : C0;
#pragma unroll
    for (int fm = 0; fm < 8; ++fm)
#pragma unroll
      for (int fn = 0; fn < 4; ++fn)
#pragma unroll
        for (int r = 0; r < 4; ++r)
          dst[(size_t)(crow + fm * 16 + r) * N + ccol + fn * 16] = f2bf(acc[fm][fn][r]);
  }
}

// ---------------- flash attention, sliding window 1024, GQA 32/8 ----------------
// grid (S/128, H). block 512 = 8 waves; waves 0-3 own rows [q0,q0+64),
// waves 4-7 own [q0+64,q0+128). ONE K/V stage shared by both q-halves.
__global__ __launch_bounds__(512, 4) void attn_kernel(
    const u16* __restrict__ Q, const u16* __restrict__ Kg,
    const u16* __restrict__ Vt, u16* __restrict__ O) {
  __shared__ u16 Ks[2][64 * 128];
  __shared__ u16 Vs[2][128 * 64];
  int tid = threadIdx.x, lane = tid & 63, w = tid >> 6;
  int wg = w >> 2;
  int g = lane >> 4, q = lane & 15;
  int q0 = blockIdx.x * 128;
  int h = blockIdx.y, hk = h >> 2;
  int qbase = q0 + wg * 64;
  int qrow = qbase + (w & 3) * 16;
  int xorm = (lane & 7) << 3;
  short8 qf[4];
  {
    const u16* qp = Q + (size_t)(qrow + q) * 4096 + h * 128 + g * 8;
#pragma unroll
    for (int kk = 0; kk < 4; ++kk) qf[kk] = *(const short8*)(qp + kk * 32);
  }
  float mrow = -1e30f, lsum = 0.f;
  f32x4 of[8];
#pragma unroll
  for (int d = 0; d < 8; ++d) of[d] = (f32x4){0.f, 0.f, 0.f, 0.f};
  int bjt_lo = (q0 >= 1024) ? ((q0 - 1023) >> 6) : 0;
  int bjt_hi = (q0 + 64) >> 6;
  int wjt_lo = (qbase >= 1024) ? ((qbase - 1023) >> 6) : 0;
  int wjt_hi = qbase >> 6;
  int krow = tid >> 4;
  int kchunk = (tid & 15) ^ (krow & 7);
  const u16* kbase = Kg + (size_t)krow * 1024 + hk * 128 + (kchunk << 3);
  int vrow = tid >> 3;
  int vchunk = (tid & 7) ^ (vrow & 7);
  const u16* vbase = Vt + (size_t)(hk * 128 + vrow) * 2048 + (vchunk << 3);

  auto stageK = [&](int buf, int j0) {
    const u16* gp = kbase + (size_t)j0 * 1024;
#pragma unroll
    for (int it = 0; it < 2; ++it)
      load_lds16(gp + (size_t)it * 32 * 1024, (char*)(&Ks[buf][0]) + it * 8192 + tid * 16);
  };
  auto stageV = [&](int buf, int j0) {
    const u16* gp = vbase + j0;
#pragma unroll
    for (int it = 0; it < 2; ++it)
      load_lds16(gp + (size_t)it * 64 * 2048, (char*)(&Vs[buf][0]) + it * 8192 + tid * 16);
  };

  int cur = 0;
  stageK(0, bjt_lo << 6);
  stageV(0, bjt_lo << 6);
  asm volatile("s_waitcnt vmcnt(0)" ::: "memory");
  __syncthreads();
  for (int jt = bjt_lo; jt <= bjt_hi; ++jt) {
    int j0 = jt << 6;
    if (jt < bjt_hi) { stageK(cur ^ 1, j0 + 64); stageV(cur ^ 1, j0 + 64); }
    if (jt >= wjt_lo && jt <= wjt_hi) {
      f32x4 sf[4];
#pragma unroll
      for (int nt = 0; nt < 4; ++nt) sf[nt] = (f32x4){0.f, 0.f, 0.f, 0.f};
      const u16* ks = &Ks[cur][0];
      __builtin_amdgcn_s_setprio(1);
#pragma unroll
      for (int kk = 0; kk < 4; ++kk) {
        short8 qv = qf[kk];
        int col = (kk * 32 + g * 8) ^ xorm;
#pragma unroll
        for (int nt = 0; nt < 4; ++nt) {
          short8 kf = *(const short8*)&ks[(nt * 16 + q) * 128 + col];
          sf[nt] = __builtin_amdgcn_mfma_f32_16x16x32_bf16(kf, qv, sf[nt], 0, 0, 0);
        }
      }
      __builtin_amdgcn_s_setprio(0);
      float p[4][4];
#pragma unroll
      for (int nt = 0; nt < 4; ++nt)
#pragma unroll
        for (int r = 0; r < 4; ++r) p[nt][r] = sf[nt][r];
      if (j0 + 63 > qrow || j0 + 1009 <= qrow) {
        int qq = qrow + q;
        int kb = j0 + g * 4;
#pragma unroll
        for (int nt = 0; nt < 4; ++nt)
#pragma unroll
          for (int r = 0; r < 4; ++r) {
            int key = kb + nt * 16 + r;
            if (key > qq || key + 1024 <= qq) p[nt][r] = -1e9f;
          }
      }
      float tm = p[0][0];
#pragma unroll
      for (int nt = 0; nt < 4; ++nt)
#pragma unroll
        for (int r = 0; r < 4; ++r) tm = fmaxf(tm, p[nt][r]);
      tm = fmaxf(tm, __shfl_xor(tm, 16));
      tm = fmaxf(tm, __shfl_xor(tm, 32));
      if (__any(tm > mrow + 8.f)) {
        float nm = fmaxf(mrow, tm);
        float sc = __builtin_amdgcn_exp2f(mrow - nm);
        mrow = nm;
        lsum *= sc;
#pragma unroll
        for (int d = 0; d < 8; ++d) of[d] *= sc;
      }
      float ps = 0.f;
#pragma unroll
      for (int nt = 0; nt < 4; ++nt)
#pragma unroll
        for (int r = 0; r < 4; ++r) {
          float e = __builtin_amdgcn_exp2f(p[nt][r] - mrow);
          p[nt][r] = e;
          ps += e;
        }
      ps += __shfl_xor(ps, 16);
      ps += __shfl_xor(ps, 32);
      lsum += ps;
      u32 pk[4][2];
#pragma unroll
      for (int nt = 0; nt < 4; ++nt) {
        pk[nt][0] = __builtin_amdgcn_perm(__float_as_uint(p[nt][1]), __float_as_uint(p[nt][0]), 0x07060302u);
        pk[nt][1] = __builtin_amdgcn_perm(__float_as_uint(p[nt][3]), __float_as_uint(p[nt][2]), 0x07060302u);
      }
      int s0 = q + ((g & 1) ? 32 : 0);
      int s1 = s0 + 16;
      bool hi_sel = g >= 2;
      const u16* vs = &Vs[cur][0];
      __builtin_amdgcn_s_setprio(1);
#pragma unroll
      for (int kh = 0; kh < 2; ++kh) {
        int lo = kh * 2, hi = lo + 1;
        u32 a0 = (u32)__shfl((int)pk[lo][0], s0);
        u32 a1 = (u32)__shfl((int)pk[lo][1], s0);
        u32 b0 = (u32)__shfl((int)pk[hi][0], s0);
        u32 b1 = (u32)__shfl((int)pk[hi][1], s0);
        u32 a2 = (u32)__shfl((int)pk[lo][0], s1);
        u32 a3 = (u32)__shfl((int)pk[lo][1], s1);
        u32 b2 = (u32)__shfl((int)pk[hi][0], s1);
        u32 b3 = (u32)__shfl((int)pk[hi][1], s1);
        union { u32 u[4]; short8 s; } pb;
        pb.u[0] = hi_sel ? b0 : a0;
        pb.u[1] = hi_sel ? b1 : a1;
        pb.u[2] = hi_sel ? b2 : a2;
        pb.u[3] = hi_sel ? b3 : a3;
        int col = (kh * 32 + g * 8) ^ xorm;
#pragma unroll
        for (int dt = 0; dt < 8; ++dt) {
          short8 vv = *(const short8*)&vs[(dt * 16 + q) * 64 + col];
          of[dt] = __builtin_amdgcn_mfma_f32_16x16x32_bf16(vv, pb.s, of[dt], 0, 0, 0);
        }
      }
      __builtin_amdgcn_s_setprio(0);
    }
    asm volatile("s_waitcnt vmcnt(0)" ::: "memory");
    __builtin_amdgcn_s_barrier();
    cur ^= 1;
  }
  float inv = 1.f / lsum;
  u16* op = O + (size_t)(qrow + q) * 4096 + h * 128 + g * 4;
#pragma unroll
  for (int dt = 0; dt < 8; ++dt) {
    s16x4 o4;
#pragma unroll
    for (int r = 0; r < 4; ++r) o4[r] = (short)f2bf(of[dt][r] * inv);
    *(s16x4*)(op + dt * 16) = o4;
  }
}

extern "C" void kernel_launch(void* const* d_in, const int* in_sizes, int n_in,
                              void* d_out, int out_size, void* d_ws, size_t ws_size,
                              hipStream_t stream) {
  (void)in_sizes; (void)n_in; (void)out_size;
  const float* hs = (const float*)d_in[0];
  const float* Wq = (const float*)d_in[3];
  const float* Wk = (const float*)d_in[4];
  const float* Wv = (const float*)d_in[5];
  const float* Wo = (const float*)d_in[6];
  float* out = (float*)d_out;
  char* ws = (char*)d_ws;

  u16* Xb   = (u16*)(ws + 0);          // 16 MB : X bf16 [2048][4096]
  u16* Wt   = (u16*)(ws + 16777216);   // 32 MB : WqT, then KV partial arena, then WoT
  u16* WkvT = (u16*)(ws + 50331648);   // 16 MB : [Wk^T;Wv^T] [2048][4096]
  u16* Qb   = (u16*)(ws + 67108864);   // 16 MB : Q [2048][4096]
  u16* Kb   = (u16*)(ws + 83886080);   // 4 MB  : K [2048][1024]
  u16* Vtb  = (u16*)(ws + 88080384);   // 4 MB  : V^T [1024][2048]
  u16* Ab   = (u16*)(ws + 96468992);   // 16 MB : attn out [2048][4096]
  u16* P1q  = Ab;                      // Q-proj half-1 partial (Ab free pre-attn)
  u16* PKV  = Wt;                      // KV split-K partial arena (WqT dead post-Q-proj)
  u16* P0o  = WkvT;                    // O-proj half-0 partial (WkvT dead post-KV-proj)
  u16* P1o  = Qb;                      // O-proj half-1 partial (Qb dead post-attn)
  if (ws_size < 113246208u) return;

  cvt_f32_bf16_kernel<<<dim3(2097152 / 256), 256, 0, stream>>>(hs, Xb, 2097152);

  // fused Wq/Wk/Wv transpose-convert (64x64 tiles)
  tconv3_kernel<<<dim3(6144), 256, 0, stream>>>(Wq, Wk, Wv, Wt, WkvT);

  // Q projection: 256^2 8-phase split-K=2, bf16 partials (combine fused into rope)
  gemm8p_kernel<0><<<dim3(16, 8, 2), 512, 0, stream>>>(Xb, Wt, Qb, P1q, 4096, 4096, 2048);

  // fused K+V projection: 256^2 8-phase split-K=4 into partial arena
  gemm8p_kernel<1><<<dim3(8, 8, 4), 512, 0, stream>>>(Xb, WkvT, PKV, nullptr, 2048, 4096, 1024);
  combine_kv_kernel<<<dim3(2048), 256, 0, stream>>>(PKV, Kb, Vtb);

  // fused RoPE: Q = rope(P0q + P1q) with log2e/sqrt(D); K = rope(K)
  rope_kernel<<<dim3(20480), 256, 0, stream>>>(Qb, P1q, Kb);

  // attention: 128 q-rows per block, shared K/V staging
  attn_kernel<<<dim3(16, 32), 512, 0, stream>>>(Qb, Kb, Vtb, Ab);

  // output projection: transpose Wo, 256^2 8-phase split-K=2, combine to f32
  tconv1_kernel<<<dim3(4096), 256, 0, stream>>>(Wo, Wt);
  gemm8p_kernel<0><<<dim3(16, 8, 2), 512, 0, stream>>>(Ab, Wt, P0o, P1o, 4096, 4096, 2048);
  combine2_f32_kernel<<<dim3(4096), 256, 0, stream>>>(out, P0o, P1o, 1048576);
}

// Round 17
// 321.660 us; speedup vs baseline: 1.0154x; 1.0154x over previous
//
#include <hip/hip_runtime.h>

typedef __attribute__((ext_vector_type(8))) short short8;
typedef __attribute__((ext_vector_type(4))) short s16x4;
typedef __attribute__((ext_vector_type(4))) float f32x4;
typedef unsigned short u16;
typedef unsigned int u32;

__device__ __forceinline__ u16 f2bf(float f) {
  union { float f; unsigned int u; } v; v.f = f;
  unsigned int r = (v.u + 0x7FFFu + ((v.u >> 16) & 1u)) >> 16;
  return (u16)r;
}
__device__ __forceinline__ float bf2f(u16 b) {
  union { unsigned int u; float f; } v; v.u = ((unsigned int)b) << 16;
  return v.f;
}
__device__ __forceinline__ void load_lds16(const void* g, void* l) {
  __builtin_amdgcn_global_load_lds((const __attribute__((address_space(1))) void*)g,
                                   (__attribute__((address_space(3))) void*)l, 16, 0, 0);
}

// ---------------- fp32 -> bf16 elementwise ----------------
__global__ void cvt_f32_bf16_kernel(const float* __restrict__ in, u16* __restrict__ out, int n4) {
  int i = blockIdx.x * blockDim.x + threadIdx.x;
  if (i >= n4) return;
  float4 v = ((const float4*)in)[i];
  ushort4 o;
  o.x = f2bf(v.x); o.y = f2bf(v.y); o.z = f2bf(v.z); o.w = f2bf(v.w);
  ((ushort4*)out)[i] = o;
}

// out_f32 = bf16(p0) + bf16(p1)
__global__ void combine2_f32_kernel(float* __restrict__ out, const u16* __restrict__ p0,
                                    const u16* __restrict__ p1, int n8) {
  int i = blockIdx.x * blockDim.x + threadIdx.x;
  if (i >= n8) return;
  short8 a = ((const short8*)p0)[i];
  short8 b = ((const short8*)p1)[i];
  float4 o0, o1;
  o0.x = bf2f((u16)a[0]) + bf2f((u16)b[0]);
  o0.y = bf2f((u16)a[1]) + bf2f((u16)b[1]);
  o0.z = bf2f((u16)a[2]) + bf2f((u16)b[2]);
  o0.w = bf2f((u16)a[3]) + bf2f((u16)b[3]);
  o1.x = bf2f((u16)a[4]) + bf2f((u16)b[4]);
  o1.y = bf2f((u16)a[5]) + bf2f((u16)b[5]);
  o1.z = bf2f((u16)a[6]) + bf2f((u16)b[6]);
  o1.w = bf2f((u16)a[7]) + bf2f((u16)b[7]);
  ((float4*)out)[i * 2]     = o0;
  ((float4*)out)[i * 2 + 1] = o1;
}

// sum 4 KV split-K partials -> Kb [2048][1024] and Vt [1024][2048]
__global__ void combine_kv_kernel(const u16* __restrict__ PKV, u16* __restrict__ Kb,
                                  u16* __restrict__ Vt) {
  int i = blockIdx.x * blockDim.x + threadIdx.x;   // 0..524287
  const u16* src; u16* dst; size_t off;
  if (i < 262144) { off = (size_t)i; dst = Kb; src = PKV; }
  else            { off = (size_t)(i - 262144); dst = Vt; src = PKV + 2097152; }
  float s[8] = {0.f, 0.f, 0.f, 0.f, 0.f, 0.f, 0.f, 0.f};
#pragma unroll
  for (int z = 0; z < 4; ++z) {
    short8 v = *(const short8*)(src + (size_t)z * 4194304 + off * 8);
#pragma unroll
    for (int j = 0; j < 8; ++j) s[j] += bf2f((u16)v[j]);
  }
  short8 o;
#pragma unroll
  for (int j = 0; j < 8; ++j) o[j] = (short)f2bf(s[j]);
  ((short8*)dst)[off] = o;
}

// ---------------- 64x64-tile fp32 [K][N] -> bf16 [N][K] transpose core ----------------
__device__ __forceinline__ void tconv64_tile(const float* __restrict__ W, u16* __restrict__ Wt,
                                             int K, int N, int nb, int kb, int tid) {
  __shared__ float tile[64][65];
  int tx = tid & 15, ty = tid >> 4;          // 16 x 16
  const float* src = W + (size_t)(kb + ty) * N + nb + tx * 4;
#pragma unroll
  for (int i = 0; i < 4; ++i) {
    float4 v = *(const float4*)(src + (size_t)i * 16 * N);
    tile[ty + i * 16][tx * 4 + 0] = v.x;
    tile[ty + i * 16][tx * 4 + 1] = v.y;
    tile[ty + i * 16][tx * 4 + 2] = v.z;
    tile[ty + i * 16][tx * 4 + 3] = v.w;
  }
  __syncthreads();
  u16* dst = Wt + (size_t)(nb + ty) * K + kb + tx * 4;
#pragma unroll
  for (int i = 0; i < 4; ++i) {
    s16x4 o;
#pragma unroll
    for (int j = 0; j < 4; ++j) o[j] = (short)f2bf(tile[tx * 4 + j][ty + i * 16]);
    *(s16x4*)(dst + (size_t)i * 16 * K) = o;
  }
}

// fused Wq/Wk/Wv transpose-convert (64x64 tiles)
__global__ void tconv3_kernel(const float* __restrict__ Wq, const float* __restrict__ Wk,
                              const float* __restrict__ Wv, u16* __restrict__ WqT,
                              u16* __restrict__ WkvT) {
  int id = blockIdx.x;
  if (id < 4096)      tconv64_tile(Wq, WqT, 4096, 4096, (id & 63) * 64, (id >> 6) * 64, threadIdx.x);
  else if (id < 5120) { int t = id - 4096; tconv64_tile(Wk, WkvT, 4096, 1024, (t & 15) * 64, (t >> 4) * 64, threadIdx.x); }
  else                { int t = id - 5120; tconv64_tile(Wv, WkvT + (size_t)1024 * 4096, 4096, 1024, (t & 15) * 64, (t >> 4) * 64, threadIdx.x); }
}

// single-weight transpose (Wo)
__global__ void tconv1_kernel(const float* __restrict__ W, u16* __restrict__ Wt) {
  int id = blockIdx.x;
  tconv64_tile(W, Wt, 4096, 4096, (id & 63) * 64, (id >> 6) * 64, threadIdx.x);
}

// ---------------- fused RoPE: Q = rope(P0q+P1q) in-place on P0q; K in-place ----------------
__global__ void rope_kernel(u16* __restrict__ Qb, const u16* __restrict__ Qp1, u16* __restrict__ Kb) {
  int idx = blockIdx.x * blockDim.x + threadIdx.x;
  int j, t, hh, s;
  if (idx < 4194304) {
    j = idx & 63; t = idx >> 6; hh = t & 31; s = t >> 5;
    float invf = exp2f(-(float)j * (13.287712379549449f / 64.0f));
    float ang = (float)s * invf;
    float sn, cs;
    sincosf(ang, &sn, &cs);
    size_t base = (size_t)s * 4096 + hh * 128 + j;
    u16* p = Qb + base;
    const u16* p1 = Qp1 + base;
    float a = bf2f(p[0]) + bf2f(p1[0]);
    float b = bf2f(p[64]) + bf2f(p1[64]);
    const float scale = 0.12751781828987514f;   // log2(e)/sqrt(128)
    p[0]  = f2bf((a * cs - b * sn) * scale);
    p[64] = f2bf((b * cs + a * sn) * scale);
  } else {
    int id = idx - 4194304;
    j = id & 63; t = id >> 6; hh = t & 7; s = t >> 3;
    float invf = exp2f(-(float)j * (13.287712379549449f / 64.0f));
    float ang = (float)s * invf;
    float sn, cs;
    sincosf(ang, &sn, &cs);
    u16* p = Kb + (size_t)s * 1024 + hh * 128 + j;
    float a = bf2f(p[0]), b = bf2f(p[64]);
    p[0]  = f2bf(a * cs - b * sn);
    p[64] = f2bf(b * cs + a * sn);
  }
}

// ---------------- 256x256 split-K bf16 GEMM, 8-phase half-tile pipeline (fixed) ----------
// LDS [buf][mat][kh][256 rows][32 elems], XOR chunk swizzle: physical chunk =
// logical ^ ((row>>1)&3). Staging pre-swizzles GLOBAL source (linear LDS dest);
// reads use g ^ ((q>>1)&3) (per-lane constant). 16 lanes -> 8 (parity,chunk)
// groups = 2-way = free.
// vmcnt(8) at the END of every odd phase (before closing barrier) seals the
// next even phase's reads across all waves (tail: 8/4/0). Never drain-0 mid-loop.
template<int KVEPI>
__global__ __launch_bounds__(512, 1) void gemm8p_kernel(
    const u16* __restrict__ A, const u16* __restrict__ B,
    u16* __restrict__ C0, u16* __restrict__ C1, int N, int K, int KH) {
  __shared__ u16 Sh[2][2][2][8192];   // [buf][mat(0=A,1=B)][kh][256*32]
  int tid = threadIdx.x, lane = tid & 63, wid = tid >> 6;
  int wr = wid >> 2, wc = wid & 3;
  int g = lane >> 4, q = lane & 15;
  int id = blockIdx.z * gridDim.x * gridDim.y + blockIdx.y * gridDim.x + blockIdx.x;
  int tot = gridDim.x * gridDim.y * gridDim.z;
  int swz = (id & 7) * (tot >> 3) + (id >> 3);
  int perh = gridDim.x * gridDim.y;
  int z = swz / perh, rem = swz % perh;
  int m0 = (rem / gridDim.x) * 256, n0 = (rem % gridDim.x) * 256;
  int k0 = z * KH;
  f32x4 acc[8][4];
#pragma unroll
  for (int i = 0; i < 8; ++i)
#pragma unroll
    for (int j = 0; j < 4; ++j) acc[i][j] = (f32x4){0.f, 0.f, 0.f, 0.f};
  int srow = tid >> 2;                                   // 0..127
  int scol = (((tid & 3) ^ ((tid >> 3) & 3)) << 3);      // pre-swizzled source chunk
  const u16* ga = A + (size_t)(m0 + srow) * K + k0 + scol;
  const u16* gb = B + (size_t)(n0 + srow) * K + k0 + scol;
  int rchunk = (g ^ ((q >> 1) & 3)) << 3;                // swizzled read col (elems)
  int arow = wr * 128 + q;
  int brow = wc * 64 + q;
  int nt = KH >> 6;               // even

  auto stageH = [&](int b, int mat, int h, int t) {
    const u16* gp = (mat ? gb : ga) + t * 64 + h * 32;
    char* dst = (char*)&Sh[b][mat][h][0];
#pragma unroll
    for (int it = 0; it < 2; ++it)
      load_lds16(gp + (size_t)it * 128 * K, dst + it * 8192 + tid * 16);
  };
  auto readA = [&](int b, int h, int fb, short8 (&af)[4]) {
    const u16* s = &Sh[b][0][h][0];
#pragma unroll
    for (int m = 0; m < 4; ++m)
      af[m] = *(const short8*)&s[(arow + (fb + m) * 16) * 32 + rchunk];
  };
  auto readB = [&](int b, int h, short8 (&bf)[4]) {
    const u16* s = &Sh[b][1][h][0];
#pragma unroll
    for (int n = 0; n < 4; ++n)
      bf[n] = *(const short8*)&s[(brow + n * 16) * 32 + rchunk];
  };

  // prologue: tile0 complete (buf0), tile1 kh0 (buf1); loads P1..P6 (12)
  stageH(0, 0, 0, 0); stageH(0, 1, 0, 0);
  stageH(0, 0, 1, 0); stageH(0, 1, 1, 0);
  stageH(1, 0, 0, 1); stageH(1, 1, 0, 1);
  asm volatile("s_waitcnt vmcnt(8)" ::: "memory");   // P1,P2 (tile0 kh0) landed
  __builtin_amdgcn_s_barrier();

  // PHASE body: [reads done by caller] [stage done by caller] barrier; lgkm0;
  // MFMA; [odd-end vmcnt by caller]; barrier.
#define PHASEA(FB)                                                       \
  __builtin_amdgcn_s_barrier();                                          \
  asm volatile("s_waitcnt lgkmcnt(0)" ::: "memory");                     \
  __builtin_amdgcn_sched_barrier(0);                                     \
  __builtin_amdgcn_s_setprio(1);                                         \
  _Pragma("unroll")                                                      \
  for (int m = 0; m < 4; ++m)                                            \
    _Pragma("unroll")                                                    \
    for (int n = 0; n < 4; ++n)                                          \
      acc[FB + m][n] = __builtin_amdgcn_mfma_f32_16x16x32_bf16(          \
          af[m], bf[n], acc[FB + m][n], 0, 0, 0);                        \
  __builtin_amdgcn_s_setprio(0);

  for (int t = 0; t < nt; t += 2) {
    bool s2 = (t + 2 < nt);
    short8 af[4], bf[4];
    // ph0: tile t, kb0, fm0-3 | stage A(t+1).kh1
    readA(0, 0, 0, af); readB(0, 0, bf);
    stageH(1, 0, 1, t + 1);
    PHASEA(0)
    __builtin_amdgcn_s_barrier();
    // ph1: tile t, kb0, fm4-7 (B reuse) | stage B(t+1).kh1 | vmcnt(8)
    readA(0, 0, 4, af);
    stageH(1, 1, 1, t + 1);
    PHASEA(4)
    asm volatile("s_waitcnt vmcnt(8)" ::: "memory");
    __builtin_amdgcn_s_barrier();
    // ph2: tile t, kb1, fm0-3 | stage A(t+2).kh0
    readA(0, 1, 0, af); readB(0, 1, bf);
    if (s2) stageH(0, 0, 0, t + 2);
    PHASEA(0)
    __builtin_amdgcn_s_barrier();
    // ph3: tile t, kb1, fm4-7 | stage B(t+2).kh0 | vmcnt
    readA(0, 1, 4, af);
    if (s2) stageH(0, 1, 0, t + 2);
    PHASEA(4)
    if (s2) { asm volatile("s_waitcnt vmcnt(8)" ::: "memory"); }
    else    { asm volatile("s_waitcnt vmcnt(4)" ::: "memory"); }
    __builtin_amdgcn_s_barrier();
    // ph4: tile t+1, kb0, fm0-3 | stage A(t+2).kh1
    readA(1, 0, 0, af); readB(1, 0, bf);
    if (s2) stageH(0, 0, 1, t + 2);
    PHASEA(0)
    __builtin_amdgcn_s_barrier();
    // ph5: tile t+1, kb0, fm4-7 | stage B(t+2).kh1 | vmcnt
    readA(1, 0, 4, af);
    if (s2) stageH(0, 1, 1, t + 2);
    PHASEA(4)
    if (s2) { asm volatile("s_waitcnt vmcnt(8)" ::: "memory"); }
    else    { asm volatile("s_waitcnt vmcnt(0)" ::: "memory"); }
    __builtin_amdgcn_s_barrier();
    // ph6: tile t+1, kb1, fm0-3 | stage A(t+3).kh0
    readA(1, 1, 0, af); readB(1, 1, bf);
    if (s2) stageH(1, 0, 0, t + 3);
    PHASEA(0)
    __builtin_amdgcn_s_barrier();
    // ph7: tile t+1, kb1, fm4-7 | stage B(t+3).kh0 | vmcnt
    readA(1, 1, 4, af);
    if (s2) stageH(1, 1, 0, t + 3);
    PHASEA(4)
    if (s2) { asm volatile("s_waitcnt vmcnt(8)" ::: "memory"); }
    __builtin_amdgcn_s_barrier();
  }
#undef PHASEA

  int crow = m0 + wr * 128 + g * 4;
  int ccol = n0 + wc * 64 + q;
  if (KVEPI) {
    u16* Kpart = C0 + (size_t)z * 4194304;
    u16* Vpart = Kpart + 2097152;
    if (n0 < 1024) {
#pragma unroll
      for (int fm = 0; fm < 8; ++fm)
#pragma unroll
        for (int fn = 0; fn < 4; ++fn)
#pragma unroll
          for (int r = 0; r < 4; ++r)
            Kpart[(size_t)(crow + fm * 16 + r) * 1024 + ccol + fn * 16] = f2bf(acc[fm][fn][r]);
    } else {
#pragma unroll
      for (int fn = 0; fn < 4; ++fn) {
        int vcol = ccol + fn * 16 - 1024;
#pragma unroll
        for (int fm = 0; fm < 8; ++fm) {
          s16x4 o;
#pragma unroll
          for (int r = 0; r < 4; ++r) o[r] = (short)f2bf(acc[fm][fn][r]);
          *(s16x4*)(Vpart + (size_t)vcol * 2048 + crow + fm * 16) = o;
        }
      }
    }
  } else {
    u16* dst = z ? C1 : C0;
#pragma unroll
    for (int fm = 0; fm < 8; ++fm)
#pragma unroll
      for (int fn = 0; fn < 4; ++fn)
#pragma unroll
        for (int r = 0; r < 4; ++r)
          dst[(size_t)(crow + fm * 16 + r) * N + ccol + fn * 16] = f2bf(acc[fm][fn][r]);
  }
}

// ---------------- flash attention, sliding window 1024, GQA 32/8 ----------------
// grid (S/128, H). block 512 = 8 waves; waves 0-3 own rows [q0,q0+64),
// waves 4-7 own [q0+64,q0+128). ONE K/V stage shared by both q-halves.
__global__ __launch_bounds__(512, 4) void attn_kernel(
    const u16* __restrict__ Q, const u16* __restrict__ Kg,
    const u16* __restrict__ Vt, u16* __restrict__ O) {
  __shared__ u16 Ks[2][64 * 128];
  __shared__ u16 Vs[2][128 * 64];
  int tid = threadIdx.x, lane = tid & 63, w = tid >> 6;
  int wg = w >> 2;
  int g = lane >> 4, q = lane & 15;
  int q0 = blockIdx.x * 128;
  int h = blockIdx.y, hk = h >> 2;
  int qbase = q0 + wg * 64;
  int qrow = qbase + (w & 3) * 16;
  int xorm = (lane & 7) << 3;
  short8 qf[4];
  {
    const u16* qp = Q + (size_t)(qrow + q) * 4096 + h * 128 + g * 8;
#pragma unroll
    for (int kk = 0; kk < 4; ++kk) qf[kk] = *(const short8*)(qp + kk * 32);
  }
  float mrow = -1e30f, lsum = 0.f;
  f32x4 of[8];
#pragma unroll
  for (int d = 0; d < 8; ++d) of[d] = (f32x4){0.f, 0.f, 0.f, 0.f};
  int bjt_lo = (q0 >= 1024) ? ((q0 - 1023) >> 6) : 0;
  int bjt_hi = (q0 + 64) >> 6;
  int wjt_lo = (qbase >= 1024) ? ((qbase - 1023) >> 6) : 0;
  int wjt_hi = qbase >> 6;
  int krow = tid >> 4;
  int kchunk = (tid & 15) ^ (krow & 7);
  const u16* kbase = Kg + (size_t)krow * 1024 + hk * 128 + (kchunk << 3);
  int vrow = tid >> 3;
  int vchunk = (tid & 7) ^ (vrow & 7);
  const u16* vbase = Vt + (size_t)(hk * 128 + vrow) * 2048 + (vchunk << 3);

  auto stageK = [&](int buf, int j0) {
    const u16* gp = kbase + (size_t)j0 * 1024;
#pragma unroll
    for (int it = 0; it < 2; ++it)
      load_lds16(gp + (size_t)it * 32 * 1024, (char*)(&Ks[buf][0]) + it * 8192 + tid * 16);
  };
  auto stageV = [&](int buf, int j0) {
    const u16* gp = vbase + j0;
#pragma unroll
    for (int it = 0; it < 2; ++it)
      load_lds16(gp + (size_t)it * 64 * 2048, (char*)(&Vs[buf][0]) + it * 8192 + tid * 16);
  };

  int cur = 0;
  stageK(0, bjt_lo << 6);
  stageV(0, bjt_lo << 6);
  asm volatile("s_waitcnt vmcnt(0)" ::: "memory");
  __syncthreads();
  for (int jt = bjt_lo; jt <= bjt_hi; ++jt) {
    int j0 = jt << 6;
    if (jt < bjt_hi) { stageK(cur ^ 1, j0 + 64); stageV(cur ^ 1, j0 + 64); }
    if (jt >= wjt_lo && jt <= wjt_hi) {
      f32x4 sf[4];
#pragma unroll
      for (int nt = 0; nt < 4; ++nt) sf[nt] = (f32x4){0.f, 0.f, 0.f, 0.f};
      const u16* ks = &Ks[cur][0];
      __builtin_amdgcn_s_setprio(1);
#pragma unroll
      for (int kk = 0; kk < 4; ++kk) {
        short8 qv = qf[kk];
        int col = (kk * 32 + g * 8) ^ xorm;
#pragma unroll
        for (int nt = 0; nt < 4; ++nt) {
          short8 kf = *(const short8*)&ks[(nt * 16 + q) * 128 + col];
          sf[nt] = __builtin_amdgcn_mfma_f32_16x16x32_bf16(kf, qv, sf[nt], 0, 0, 0);
        }
      }
      __builtin_amdgcn_s_setprio(0);
      float p[4][4];
#pragma unroll
      for (int nt = 0; nt < 4; ++nt)
#pragma unroll
        for (int r = 0; r < 4; ++r) p[nt][r] = sf[nt][r];
      if (j0 + 63 > qrow || j0 + 1009 <= qrow) {
        int qq = qrow + q;
        int kb = j0 + g * 4;
#pragma unroll
        for (int nt = 0; nt < 4; ++nt)
#pragma unroll
          for (int r = 0; r < 4; ++r) {
            int key = kb + nt * 16 + r;
            if (key > qq || key + 1024 <= qq) p[nt][r] = -1e9f;
          }
      }
      float tm = p[0][0];
#pragma unroll
      for (int nt = 0; nt < 4; ++nt)
#pragma unroll
        for (int r = 0; r < 4; ++r) tm = fmaxf(tm, p[nt][r]);
      tm = fmaxf(tm, __shfl_xor(tm, 16));
      tm = fmaxf(tm, __shfl_xor(tm, 32));
      if (__any(tm > mrow + 8.f)) {
        float nm = fmaxf(mrow, tm);
        float sc = __builtin_amdgcn_exp2f(mrow - nm);
        mrow = nm;
        lsum *= sc;
#pragma unroll
        for (int d = 0; d < 8; ++d) of[d] *= sc;
      }
      float ps = 0.f;
#pragma unroll
      for (int nt = 0; nt < 4; ++nt)
#pragma unroll
        for (int r = 0; r < 4; ++r) {
          float e = __builtin_amdgcn_exp2f(p[nt][r] - mrow);
          p[nt][r] = e;
          ps += e;
        }
      ps += __shfl_xor(ps, 16);
      ps += __shfl_xor(ps, 32);
      lsum += ps;
      u32 pk[4][2];
#pragma unroll
      for (int nt = 0; nt < 4; ++nt) {
        pk[nt][0] = __builtin_amdgcn_perm(__float_as_uint(p[nt][1]), __float_as_uint(p[nt][0]), 0x07060302u);
        pk[nt][1] = __builtin_amdgcn_perm(__float_as_uint(p[nt][3]), __float_as_uint(p[nt][2]), 0x07060302u);
      }
      int s0 = q + ((g & 1) ? 32 : 0);
      int s1 = s0 + 16;
      bool hi_sel = g >= 2;
      const u16* vs = &Vs[cur][0];
      __builtin_amdgcn_s_setprio(1);
#pragma unroll
      for (int kh = 0; kh < 2; ++kh) {
        int lo = kh * 2, hi = lo + 1;
        u32 a0 = (u32)__shfl((int)pk[lo][0], s0);
        u32 a1 = (u32)__shfl((int)pk[lo][1], s0);
        u32 b0 = (u32)__shfl((int)pk[hi][0], s0);
        u32 b1 = (u32)__shfl((int)pk[hi][1], s0);
        u32 a2 = (u32)__shfl((int)pk[lo][0], s1);
        u32 a3 = (u32)__shfl((int)pk[lo][1], s1);
        u32 b2 = (u32)__shfl((int)pk[hi][0], s1);
        u32 b3 = (u32)__shfl((int)pk[hi][1], s1);
        union { u32 u[4]; short8 s; } pb;
        pb.u[0] = hi_sel ? b0 : a0;
        pb.u[1] = hi_sel ? b1 : a1;
        pb.u[2] = hi_sel ? b2 : a2;
        pb.u[3] = hi_sel ? b3 : a3;
        int col = (kh * 32 + g * 8) ^ xorm;
#pragma unroll
        for (int dt = 0; dt < 8; ++dt) {
          short8 vv = *(const short8*)&vs[(dt * 16 + q) * 64 + col];
          of[dt] = __builtin_amdgcn_mfma_f32_16x16x32_bf16(vv, pb.s, of[dt], 0, 0, 0);
        }
      }
      __builtin_amdgcn_s_setprio(0);
    }
    asm volatile("s_waitcnt vmcnt(0)" ::: "memory");
    __builtin_amdgcn_s_barrier();
    cur ^= 1;
  }
  float inv = 1.f / lsum;
  u16* op = O + (size_t)(qrow + q) * 4096 + h * 128 + g * 4;
#pragma unroll
  for (int dt = 0; dt < 8; ++dt) {
    s16x4 o4;
#pragma unroll
    for (int r = 0; r < 4; ++r) o4[r] = (short)f2bf(of[dt][r] * inv);
    *(s16x4*)(op + dt * 16) = o4;
  }
}

extern "C" void kernel_launch(void* const* d_in, const int* in_sizes, int n_in,
                              void* d_out, int out_size, void* d_ws, size_t ws_size,
                              hipStream_t stream) {
  (void)in_sizes; (void)n_in; (void)out_size;
  const float* hs = (const float*)d_in[0];
  const float* Wq = (const float*)d_in[3];
  const float* Wk = (const float*)d_in[4];
  const float* Wv = (const float*)d_in[5];
  const float* Wo = (const float*)d_in[6];
  float* out = (float*)d_out;
  char* ws = (char*)d_ws;

  u16* Xb   = (u16*)(ws + 0);          // 16 MB : X bf16 [2048][4096]
  u16* Wt   = (u16*)(ws + 16777216);   // 32 MB : WqT, then KV partial arena, then WoT
  u16* WkvT = (u16*)(ws + 50331648);   // 16 MB : [Wk^T;Wv^T] [2048][4096]
  u16* Qb   = (u16*)(ws + 67108864);   // 16 MB : Q [2048][4096]
  u16* Kb   = (u16*)(ws + 83886080);   // 4 MB  : K [2048][1024]
  u16* Vtb  = (u16*)(ws + 88080384);   // 4 MB  : V^T [1024][2048]
  u16* Ab   = (u16*)(ws + 96468992);   // 16 MB : attn out [2048][4096]
  u16* P1q  = Ab;                      // Q-proj half-1 partial (Ab free pre-attn)
  u16* PKV  = Wt;                      // KV split-K partial arena (WqT dead post-Q-proj)
  u16* P0o  = WkvT;                    // O-proj half-0 partial (WkvT dead post-KV-proj)
  u16* P1o  = Qb;                      // O-proj half-1 partial (Qb dead post-attn)
  if (ws_size < 113246208u) return;

  cvt_f32_bf16_kernel<<<dim3(2097152 / 256), 256, 0, stream>>>(hs, Xb, 2097152);

  // fused Wq/Wk/Wv transpose-convert (64x64 tiles)
  tconv3_kernel<<<dim3(6144), 256, 0, stream>>>(Wq, Wk, Wv, Wt, WkvT);

  // Q projection: 256^2 8-phase split-K=2, bf16 partials (combine fused into rope)
  gemm8p_kernel<0><<<dim3(16, 8, 2), 512, 0, stream>>>(Xb, Wt, Qb, P1q, 4096, 4096, 2048);

  // fused K+V projection: 256^2 8-phase split-K=4 into partial arena
  gemm8p_kernel<1><<<dim3(8, 8, 4), 512, 0, stream>>>(Xb, WkvT, PKV, nullptr, 2048, 4096, 1024);
  combine_kv_kernel<<<dim3(2048), 256, 0, stream>>>(PKV, Kb, Vtb);

  // fused RoPE: Q = rope(P0q + P1q) with log2e/sqrt(D); K = rope(K)
  rope_kernel<<<dim3(20480), 256, 0, stream>>>(Qb, P1q, Kb);

  // attention: 128 q-rows per block, shared K/V staging
  attn_kernel<<<dim3(16, 32), 512, 0, stream>>>(Qb, Kb, Vtb, Ab);

  // output projection: transpose Wo, 256^2 8-phase split-K=2, combine to f32
  tconv1_kernel<<<dim3(4096), 256, 0, stream>>>(Wo, Wt);
  gemm8p_kernel<0><<<dim3(16, 8, 2), 512, 0, stream>>>(Ab, Wt, P0o, P1o, 4096, 4096, 2048);
  combine2_f32_kernel<<<dim3(4096), 256, 0, stream>>>(out, P0o, P1o, 1048576);
}

// Round 18
// 303.813 us; speedup vs baseline: 1.0751x; 1.0587x over previous
//
#include <hip/hip_runtime.h>

typedef __attribute__((ext_vector_type(8))) short short8;
typedef __attribute__((ext_vector_type(4))) short s16x4;
typedef __attribute__((ext_vector_type(4))) float f32x4;
typedef unsigned short u16;
typedef unsigned int u32;

__device__ __forceinline__ u16 f2bf(float f) {
  union { float f; unsigned int u; } v; v.f = f;
  unsigned int r = (v.u + 0x7FFFu + ((v.u >> 16) & 1u)) >> 16;
  return (u16)r;
}
__device__ __forceinline__ float bf2f(u16 b) {
  union { unsigned int u; float f; } v; v.u = ((unsigned int)b) << 16;
  return v.f;
}
__device__ __forceinline__ void load_lds16(const void* g, void* l) {
  __builtin_amdgcn_global_load_lds((const __attribute__((address_space(1))) void*)g,
                                   (__attribute__((address_space(3))) void*)l, 16, 0, 0);
}

// ---------------- fp32 -> bf16 elementwise ----------------
__global__ void cvt_f32_bf16_kernel(const float* __restrict__ in, u16* __restrict__ out, int n4) {
  int i = blockIdx.x * blockDim.x + threadIdx.x;
  if (i >= n4) return;
  float4 v = ((const float4*)in)[i];
  ushort4 o;
  o.x = f2bf(v.x); o.y = f2bf(v.y); o.z = f2bf(v.z); o.w = f2bf(v.w);
  ((ushort4*)out)[i] = o;
}

// out_f32 = bf16(p0) + bf16(p1)
__global__ void combine2_f32_kernel(float* __restrict__ out, const u16* __restrict__ p0,
                                    const u16* __restrict__ p1, int n8) {
  int i = blockIdx.x * blockDim.x + threadIdx.x;
  if (i >= n8) return;
  short8 a = ((const short8*)p0)[i];
  short8 b = ((const short8*)p1)[i];
  float4 o0, o1;
  o0.x = bf2f((u16)a[0]) + bf2f((u16)b[0]);
  o0.y = bf2f((u16)a[1]) + bf2f((u16)b[1]);
  o0.z = bf2f((u16)a[2]) + bf2f((u16)b[2]);
  o0.w = bf2f((u16)a[3]) + bf2f((u16)b[3]);
  o1.x = bf2f((u16)a[4]) + bf2f((u16)b[4]);
  o1.y = bf2f((u16)a[5]) + bf2f((u16)b[5]);
  o1.z = bf2f((u16)a[6]) + bf2f((u16)b[6]);
  o1.w = bf2f((u16)a[7]) + bf2f((u16)b[7]);
  ((float4*)out)[i * 2]     = o0;
  ((float4*)out)[i * 2 + 1] = o1;
}

// sum 4 KV split-K partials; apply RoPE to K; -> Kb [2048][1024], Vt [1024][2048]
__global__ void combine_kv_rope_kernel(const u16* __restrict__ PKV, u16* __restrict__ Kb,
                                       u16* __restrict__ Vt) {
  int i = blockIdx.x * blockDim.x + threadIdx.x;   // 0..393215
  if (i < 131072) {
    // K: thread handles chunk pair (j, j+64) of row (s, hh)
    int s = i >> 6, r = i & 63, hh = r >> 3, c = r & 7;
    size_t lo8 = (size_t)s * 128 + hh * 16 + c;    // short8 index
    size_t hi8 = lo8 + 8;
    float lo[8] = {0,0,0,0,0,0,0,0}, hi[8] = {0,0,0,0,0,0,0,0};
#pragma unroll
    for (int z = 0; z < 4; ++z) {
      short8 a = *(const short8*)(PKV + (size_t)z * 4194304 + lo8 * 8);
      short8 b = *(const short8*)(PKV + (size_t)z * 4194304 + hi8 * 8);
#pragma unroll
      for (int j = 0; j < 8; ++j) { lo[j] += bf2f((u16)a[j]); hi[j] += bf2f((u16)b[j]); }
    }
    short8 olo, ohi;
#pragma unroll
    for (int ii = 0; ii < 8; ++ii) {
      int j = c * 8 + ii;
      float invf = exp2f(-(float)j * (13.287712379549449f / 64.0f));
      float sn, cs;
      sincosf((float)s * invf, &sn, &cs);
      olo[ii] = (short)f2bf(lo[ii] * cs - hi[ii] * sn);
      ohi[ii] = (short)f2bf(hi[ii] * cs + lo[ii] * sn);
    }
    *(short8*)(Kb + lo8 * 8) = olo;
    *(short8*)(Kb + hi8 * 8) = ohi;
  } else {
    int v = i - 131072;                             // 0..262143
    const u16* src = PKV + 2097152;
    float sm[8] = {0,0,0,0,0,0,0,0};
#pragma unroll
    for (int z = 0; z < 4; ++z) {
      short8 a = *(const short8*)(src + (size_t)z * 4194304 + (size_t)v * 8);
#pragma unroll
      for (int j = 0; j < 8; ++j) sm[j] += bf2f((u16)a[j]);
    }
    short8 o;
#pragma unroll
    for (int j = 0; j < 8; ++j) o[j] = (short)f2bf(sm[j]);
    ((short8*)Vt)[v] = o;
  }
}

// ---------------- 64x64-tile fp32 [K][N] -> bf16 [N][K] transpose core ----------------
__device__ __forceinline__ void tconv64_tile(const float* __restrict__ W, u16* __restrict__ Wt,
                                             int K, int N, int nb, int kb, int tid) {
  __shared__ float tile[64][65];
  int tx = tid & 15, ty = tid >> 4;          // 16 x 16
  const float* src = W + (size_t)(kb + ty) * N + nb + tx * 4;
#pragma unroll
  for (int i = 0; i < 4; ++i) {
    float4 v = *(const float4*)(src + (size_t)i * 16 * N);
    tile[ty + i * 16][tx * 4 + 0] = v.x;
    tile[ty + i * 16][tx * 4 + 1] = v.y;
    tile[ty + i * 16][tx * 4 + 2] = v.z;
    tile[ty + i * 16][tx * 4 + 3] = v.w;
  }
  __syncthreads();
  u16* dst = Wt + (size_t)(nb + ty) * K + kb + tx * 4;
#pragma unroll
  for (int i = 0; i < 4; ++i) {
    s16x4 o;
#pragma unroll
    for (int j = 0; j < 4; ++j) o[j] = (short)f2bf(tile[tx * 4 + j][ty + i * 16]);
    *(s16x4*)(dst + (size_t)i * 16 * K) = o;
  }
}

// fused Wq/Wk/Wv transpose-convert (64x64 tiles)
__global__ void tconv3_kernel(const float* __restrict__ Wq, const float* __restrict__ Wk,
                              const float* __restrict__ Wv, u16* __restrict__ WqT,
                              u16* __restrict__ WkvT) {
  int id = blockIdx.x;
  if (id < 4096)      tconv64_tile(Wq, WqT, 4096, 4096, (id & 63) * 64, (id >> 6) * 64, threadIdx.x);
  else if (id < 5120) { int t = id - 4096; tconv64_tile(Wk, WkvT, 4096, 1024, (t & 15) * 64, (t >> 4) * 64, threadIdx.x); }
  else                { int t = id - 5120; tconv64_tile(Wv, WkvT + (size_t)1024 * 4096, 4096, 1024, (t & 15) * 64, (t >> 4) * 64, threadIdx.x); }
}

// single-weight transpose (Wo)
__global__ void tconv1_kernel(const float* __restrict__ W, u16* __restrict__ Wt) {
  int id = blockIdx.x;
  tconv64_tile(W, Wt, 4096, 4096, (id & 63) * 64, (id >> 6) * 64, threadIdx.x);
}

// ---------------- 256x256 split-K bf16 GEMM, fat per-wave tile (r15 verified) ----------------
// grid (N/256, M/256, 2); z = K-half. 8 waves (2M x 4N), per-wave 128x64 (acc[8][4]).
__global__ __launch_bounds__(512, 1) void gemm256_kernel(
    const u16* __restrict__ A, const u16* __restrict__ B,
    u16* __restrict__ C0, u16* __restrict__ C1, int N, int K, int KH) {
  __shared__ u16 As[2][256 * 64];
  __shared__ u16 Bs[2][256 * 64];
  int tid = threadIdx.x, lane = tid & 63, wid = tid >> 6;
  int wr = wid >> 2, wc = wid & 3;
  int g = lane >> 4, q = lane & 15;
  int id = blockIdx.z * gridDim.x * gridDim.y + blockIdx.y * gridDim.x + blockIdx.x;
  int tot = gridDim.x * gridDim.y * gridDim.z;
  int swz = (id & 7) * (tot >> 3) + (id >> 3);
  int perh = gridDim.x * gridDim.y;
  int z = swz / perh, rem = swz % perh;
  int m0 = (rem / gridDim.x) * 256, n0 = (rem % gridDim.x) * 256;
  int k0 = z * KH;
  f32x4 acc[8][4];
#pragma unroll
  for (int i = 0; i < 8; ++i)
#pragma unroll
    for (int j = 0; j < 4; ++j) acc[i][j] = (f32x4){0.f, 0.f, 0.f, 0.f};
  int srow = tid >> 3;
  int scol = ((tid & 7) ^ (srow & 7)) << 3;
  const u16* ga = A + (size_t)(m0 + srow) * K + k0 + scol;
  const u16* gb = B + (size_t)(n0 + srow) * K + k0 + scol;
  int xorm = (q & 7) << 3;
  int arow = wr * 128 + q;
  int brow = wc * 64 + q;
  int nt = KH >> 6;

  auto stage = [&](int buf, int t) {
    const u16* pa = ga + t * 64;
    const u16* pb = gb + t * 64;
#pragma unroll
    for (int it = 0; it < 4; ++it) {
      load_lds16(pa + (size_t)it * 64 * K, (char*)(&As[buf][0]) + it * 8192 + tid * 16);
      load_lds16(pb + (size_t)it * 64 * K, (char*)(&Bs[buf][0]) + it * 8192 + tid * 16);
    }
  };

  stage(0, 0);
  stage(1, 1);
  asm volatile("s_waitcnt vmcnt(8)" ::: "memory");
  __builtin_amdgcn_s_barrier();
  for (int t = 0; t < nt; ++t) {
    int cur = t & 1;
    int col0 = (g * 8) ^ xorm;
    short8 a0[8], b0[4];
#pragma unroll
    for (int m = 0; m < 8; ++m) a0[m] = *(const short8*)&As[cur][(arow + m * 16) * 64 + col0];
#pragma unroll
    for (int n = 0; n < 4; ++n) b0[n] = *(const short8*)&Bs[cur][(brow + n * 16) * 64 + col0];
    __builtin_amdgcn_s_setprio(1);
#pragma unroll
    for (int m = 0; m < 8; ++m)
#pragma unroll
      for (int n = 0; n < 4; ++n)
        acc[m][n] = __builtin_amdgcn_mfma_f32_16x16x32_bf16(a0[m], b0[n], acc[m][n], 0, 0, 0);
    __builtin_amdgcn_s_setprio(0);
    int col1 = (32 + g * 8) ^ xorm;
    short8 a1[8], b1[4];
#pragma unroll
    for (int m = 0; m < 8; ++m) a1[m] = *(const short8*)&As[cur][(arow + m * 16) * 64 + col1];
#pragma unroll
    for (int n = 0; n < 4; ++n) b1[n] = *(const short8*)&Bs[cur][(brow + n * 16) * 64 + col1];
    asm volatile("s_waitcnt lgkmcnt(0)" ::: "memory");
    __builtin_amdgcn_s_barrier();
    if (t + 2 < nt) stage(cur, t + 2);
    __builtin_amdgcn_sched_barrier(0);
    __builtin_amdgcn_s_setprio(1);
#pragma unroll
    for (int m = 0; m < 8; ++m)
#pragma unroll
      for (int n = 0; n < 4; ++n)
        acc[m][n] = __builtin_amdgcn_mfma_f32_16x16x32_bf16(a1[m], b1[n], acc[m][n], 0, 0, 0);
    __builtin_amdgcn_s_setprio(0);
    if (t + 2 < nt)      { asm volatile("s_waitcnt vmcnt(8)" ::: "memory"); }
    else if (t + 1 < nt) { asm volatile("s_waitcnt vmcnt(0)" ::: "memory"); }
    __builtin_amdgcn_s_barrier();
  }
  int crow = m0 + wr * 128 + g * 4;
  int ccol = n0 + wc * 64 + q;
  u16* dst = z ? C1 : C0;
#pragma unroll
  for (int fm = 0; fm < 8; ++fm)
#pragma unroll
    for (int fn = 0; fn < 4; ++fn)
#pragma unroll
      for (int r = 0; r < 4; ++r)
        dst[(size_t)(crow + fm * 16 + r) * N + ccol + fn * 16] = f2bf(acc[fm][fn][r]);
}

// ---------------- KV-proj: same fat-tile body, grid (8,8,4) split-K=4 (r15 verified) -------
__global__ __launch_bounds__(512, 1) void gemm_kv256_kernel(
    const u16* __restrict__ A, const u16* __restrict__ B,
    u16* __restrict__ PKV, int K, int KH) {
  __shared__ u16 As[2][256 * 64];
  __shared__ u16 Bs[2][256 * 64];
  int tid = threadIdx.x, lane = tid & 63, wid = tid >> 6;
  int wr = wid >> 2, wc = wid & 3;
  int g = lane >> 4, q = lane & 15;
  int id = blockIdx.z * 64 + blockIdx.y * 8 + blockIdx.x;   // 256 blocks
  int swz = (id & 7) * 32 + (id >> 3);
  int z = swz >> 6, rem = swz & 63;
  int m0 = (rem >> 3) * 256, n0 = (rem & 7) * 256;
  int k0 = z * KH;
  f32x4 acc[8][4];
#pragma unroll
  for (int i = 0; i < 8; ++i)
#pragma unroll
    for (int j = 0; j < 4; ++j) acc[i][j] = (f32x4){0.f, 0.f, 0.f, 0.f};
  int srow = tid >> 3;
  int scol = ((tid & 7) ^ (srow & 7)) << 3;
  const u16* ga = A + (size_t)(m0 + srow) * K + k0 + scol;
  const u16* gb = B + (size_t)(n0 + srow) * K + k0 + scol;
  int xorm = (q & 7) << 3;
  int arow = wr * 128 + q;
  int brow = wc * 64 + q;
  int nt = KH >> 6;   // 16

  auto stage = [&](int buf, int t) {
    const u16* pa = ga + t * 64;
    const u16* pb = gb + t * 64;
#pragma unroll
    for (int it = 0; it < 4; ++it) {
      load_lds16(pa + (size_t)it * 64 * K, (char*)(&As[buf][0]) + it * 8192 + tid * 16);
      load_lds16(pb + (size_t)it * 64 * K, (char*)(&Bs[buf][0]) + it * 8192 + tid * 16);
    }
  };

  stage(0, 0);
  stage(1, 1);
  asm volatile("s_waitcnt vmcnt(8)" ::: "memory");
  __builtin_amdgcn_s_barrier();
  for (int t = 0; t < nt; ++t) {
    int cur = t & 1;
    int col0 = (g * 8) ^ xorm;
    short8 a0[8], b0[4];
#pragma unroll
    for (int m = 0; m < 8; ++m) a0[m] = *(const short8*)&As[cur][(arow + m * 16) * 64 + col0];
#pragma unroll
    for (int n = 0; n < 4; ++n) b0[n] = *(const short8*)&Bs[cur][(brow + n * 16) * 64 + col0];
    __builtin_amdgcn_s_setprio(1);
#pragma unroll
    for (int m = 0; m < 8; ++m)
#pragma unroll
      for (int n = 0; n < 4; ++n)
        acc[m][n] = __builtin_amdgcn_mfma_f32_16x16x32_bf16(a0[m], b0[n], acc[m][n], 0, 0, 0);
    __builtin_amdgcn_s_setprio(0);
    int col1 = (32 + g * 8) ^ xorm;
    short8 a1[8], b1[4];
#pragma unroll
    for (int m = 0; m < 8; ++m) a1[m] = *(const short8*)&As[cur][(arow + m * 16) * 64 + col1];
#pragma unroll
    for (int n = 0; n < 4; ++n) b1[n] = *(const short8*)&Bs[cur][(brow + n * 16) * 64 + col1];
    asm volatile("s_waitcnt lgkmcnt(0)" ::: "memory");
    __builtin_amdgcn_s_barrier();
    if (t + 2 < nt) stage(cur, t + 2);
    __builtin_amdgcn_sched_barrier(0);
    __builtin_amdgcn_s_setprio(1);
#pragma unroll
    for (int m = 0; m < 8; ++m)
#pragma unroll
      for (int n = 0; n < 4; ++n)
        acc[m][n] = __builtin_amdgcn_mfma_f32_16x16x32_bf16(a1[m], b1[n], acc[m][n], 0, 0, 0);
    __builtin_amdgcn_s_setprio(0);
    if (t + 2 < nt)      { asm volatile("s_waitcnt vmcnt(8)" ::: "memory"); }
    else if (t + 1 < nt) { asm volatile("s_waitcnt vmcnt(0)" ::: "memory"); }
    __builtin_amdgcn_s_barrier();
  }
  int crow = m0 + wr * 128 + g * 4;
  int ccol = n0 + wc * 64 + q;
  u16* Kpart = PKV + (size_t)z * 4194304;
  u16* Vpart = Kpart + 2097152;
  if (n0 < 1024) {
#pragma unroll
    for (int fm = 0; fm < 8; ++fm)
#pragma unroll
      for (int fn = 0; fn < 4; ++fn)
#pragma unroll
        for (int r = 0; r < 4; ++r)
          Kpart[(size_t)(crow + fm * 16 + r) * 1024 + ccol + fn * 16] = f2bf(acc[fm][fn][r]);
  } else {
#pragma unroll
    for (int fn = 0; fn < 4; ++fn) {
      int vcol = ccol + fn * 16 - 1024;
#pragma unroll
      for (int fm = 0; fm < 8; ++fm) {
        s16x4 o;
#pragma unroll
        for (int r = 0; r < 4; ++r) o[r] = (short)f2bf(acc[fm][fn][r]);
        *(s16x4*)(Vpart + (size_t)vcol * 2048 + crow + fm * 16) = o;
      }
    }
  }
}

// ---------------- flash attention + fused Q combine/RoPE, sliding window 1024 -------------
// grid (S/128, H). block 512 = 8 waves; waves 0-3 own rows [q0,q0+64),
// waves 4-7 own [q0+64,q0+128). ONE K/V stage shared by both q-halves.
// Q = rope(P0 + P1) * log2e/sqrt(D), computed in-register at block start.
__global__ __launch_bounds__(512, 4) void attn_kernel(
    const u16* __restrict__ Q0, const u16* __restrict__ Q1,
    const u16* __restrict__ Kg, const u16* __restrict__ Vt, u16* __restrict__ O) {
  __shared__ u16 Ks[2][64 * 128];
  __shared__ u16 Vs[2][128 * 64];
  int tid = threadIdx.x, lane = tid & 63, w = tid >> 6;
  int wg = w >> 2;
  int g = lane >> 4, q = lane & 15;
  int q0 = blockIdx.x * 128;
  int h = blockIdx.y, hk = h >> 2;
  int qbase = q0 + wg * 64;
  int qrow = qbase + (w & 3) * 16;
  int xorm = (lane & 7) << 3;
  short8 qf[4];
  {
    size_t qoff = (size_t)(qrow + q) * 4096 + h * 128 + g * 8;
    float sum[4][8];
#pragma unroll
    for (int kk = 0; kk < 4; ++kk) {
      short8 a = *(const short8*)(Q0 + qoff + kk * 32);
      short8 b = *(const short8*)(Q1 + qoff + kk * 32);
#pragma unroll
      for (int i = 0; i < 8; ++i) sum[kk][i] = bf2f((u16)a[i]) + bf2f((u16)b[i]);
    }
    const float scale = 0.12751781828987514f;   // log2(e)/sqrt(128)
    float srow = (float)(qrow + q);
#pragma unroll
    for (int kk = 0; kk < 2; ++kk)
#pragma unroll
      for (int i = 0; i < 8; ++i) {
        int j = kk * 32 + g * 8 + i;
        float invf = exp2f(-(float)j * (13.287712379549449f / 64.0f));
        float sn, cs;
        sincosf(srow * invf, &sn, &cs);
        float lo = sum[kk][i], hi = sum[kk + 2][i];
        qf[kk][i]     = (short)f2bf((lo * cs - hi * sn) * scale);
        qf[kk + 2][i] = (short)f2bf((hi * cs + lo * sn) * scale);
      }
  }
  float mrow = -1e30f, lsum = 0.f;
  f32x4 of[8];
#pragma unroll
  for (int d = 0; d < 8; ++d) of[d] = (f32x4){0.f, 0.f, 0.f, 0.f};
  int bjt_lo = (q0 >= 1024) ? ((q0 - 1023) >> 6) : 0;
  int bjt_hi = (q0 + 64) >> 6;
  int wjt_lo = (qbase >= 1024) ? ((qbase - 1023) >> 6) : 0;
  int wjt_hi = qbase >> 6;
  int krow = tid >> 4;
  int kchunk = (tid & 15) ^ (krow & 7);
  const u16* kbase = Kg + (size_t)krow * 1024 + hk * 128 + (kchunk << 3);
  int vrow = tid >> 3;
  int vchunk = (tid & 7) ^ (vrow & 7);
  const u16* vbase = Vt + (size_t)(hk * 128 + vrow) * 2048 + (vchunk << 3);

  auto stageK = [&](int buf, int j0) {
    const u16* gp = kbase + (size_t)j0 * 1024;
#pragma unroll
    for (int it = 0; it < 2; ++it)
      load_lds16(gp + (size_t)it * 32 * 1024, (char*)(&Ks[buf][0]) + it * 8192 + tid * 16);
  };
  auto stageV = [&](int buf, int j0) {
    const u16* gp = vbase + j0;
#pragma unroll
    for (int it = 0; it < 2; ++it)
      load_lds16(gp + (size_t)it * 64 * 2048, (char*)(&Vs[buf][0]) + it * 8192 + tid * 16);
  };

  int cur = 0;
  stageK(0, bjt_lo << 6);
  stageV(0, bjt_lo << 6);
  asm volatile("s_waitcnt vmcnt(0)" ::: "memory");
  __syncthreads();
  for (int jt = bjt_lo; jt <= bjt_hi; ++jt) {
    int j0 = jt << 6;
    if (jt < bjt_hi) { stageK(cur ^ 1, j0 + 64); stageV(cur ^ 1, j0 + 64); }
    if (jt >= wjt_lo && jt <= wjt_hi) {
      f32x4 sf[4];
#pragma unroll
      for (int nt = 0; nt < 4; ++nt) sf[nt] = (f32x4){0.f, 0.f, 0.f, 0.f};
      const u16* ks = &Ks[cur][0];
      __builtin_amdgcn_s_setprio(1);
#pragma unroll
      for (int kk = 0; kk < 4; ++kk) {
        short8 qv = qf[kk];
        int col = (kk * 32 + g * 8) ^ xorm;
#pragma unroll
        for (int nt = 0; nt < 4; ++nt) {
          short8 kf = *(const short8*)&ks[(nt * 16 + q) * 128 + col];
          sf[nt] = __builtin_amdgcn_mfma_f32_16x16x32_bf16(kf, qv, sf[nt], 0, 0, 0);
        }
      }
      __builtin_amdgcn_s_setprio(0);
      float p[4][4];
#pragma unroll
      for (int nt = 0; nt < 4; ++nt)
#pragma unroll
        for (int r = 0; r < 4; ++r) p[nt][r] = sf[nt][r];
      if (j0 + 63 > qrow || j0 + 1009 <= qrow) {
        int qq = qrow + q;
        int kb = j0 + g * 4;
#pragma unroll
        for (int nt = 0; nt < 4; ++nt)
#pragma unroll
          for (int r = 0; r < 4; ++r) {
            int key = kb + nt * 16 + r;
            if (key > qq || key + 1024 <= qq) p[nt][r] = -1e9f;
          }
      }
      float tm = p[0][0];
#pragma unroll
      for (int nt = 0; nt < 4; ++nt)
#pragma unroll
        for (int r = 0; r < 4; ++r) tm = fmaxf(tm, p[nt][r]);
      tm = fmaxf(tm, __shfl_xor(tm, 16));
      tm = fmaxf(tm, __shfl_xor(tm, 32));
      if (__any(tm > mrow + 8.f)) {
        float nm = fmaxf(mrow, tm);
        float sc = __builtin_amdgcn_exp2f(mrow - nm);
        mrow = nm;
        lsum *= sc;
#pragma unroll
        for (int d = 0; d < 8; ++d) of[d] *= sc;
      }
      float ps = 0.f;
#pragma unroll
      for (int nt = 0; nt < 4; ++nt)
#pragma unroll
        for (int r = 0; r < 4; ++r) {
          float e = __builtin_amdgcn_exp2f(p[nt][r] - mrow);
          p[nt][r] = e;
          ps += e;
        }
      ps += __shfl_xor(ps, 16);
      ps += __shfl_xor(ps, 32);
      lsum += ps;
      u32 pk[4][2];
#pragma unroll
      for (int nt = 0; nt < 4; ++nt) {
        pk[nt][0] = __builtin_amdgcn_perm(__float_as_uint(p[nt][1]), __float_as_uint(p[nt][0]), 0x07060302u);
        pk[nt][1] = __builtin_amdgcn_perm(__float_as_uint(p[nt][3]), __float_as_uint(p[nt][2]), 0x07060302u);
      }
      int s0 = q + ((g & 1) ? 32 : 0);
      int s1 = s0 + 16;
      bool hi_sel = g >= 2;
      const u16* vs = &Vs[cur][0];
      __builtin_amdgcn_s_setprio(1);
#pragma unroll
      for (int kh = 0; kh < 2; ++kh) {
        int lo = kh * 2, hi = lo + 1;
        u32 a0 = (u32)__shfl((int)pk[lo][0], s0);
        u32 a1 = (u32)__shfl((int)pk[lo][1], s0);
        u32 b0 = (u32)__shfl((int)pk[hi][0], s0);
        u32 b1 = (u32)__shfl((int)pk[hi][1], s0);
        u32 a2 = (u32)__shfl((int)pk[lo][0], s1);
        u32 a3 = (u32)__shfl((int)pk[lo][1], s1);
        u32 b2 = (u32)__shfl((int)pk[hi][0], s1);
        u32 b3 = (u32)__shfl((int)pk[hi][1], s1);
        union { u32 u[4]; short8 s; } pb;
        pb.u[0] = hi_sel ? b0 : a0;
        pb.u[1] = hi_sel ? b1 : a1;
        pb.u[2] = hi_sel ? b2 : a2;
        pb.u[3] = hi_sel ? b3 : a3;
        int col = (kh * 32 + g * 8) ^ xorm;
#pragma unroll
        for (int dt = 0; dt < 8; ++dt) {
          short8 vv = *(const short8*)&vs[(dt * 16 + q) * 64 + col];
          of[dt] = __builtin_amdgcn_mfma_f32_16x16x32_bf16(vv, pb.s, of[dt], 0, 0, 0);
        }
      }
      __builtin_amdgcn_s_setprio(0);
    }
    asm volatile("s_waitcnt vmcnt(0)" ::: "memory");
    __builtin_amdgcn_s_barrier();
    cur ^= 1;
  }
  float inv = 1.f / lsum;
  u16* op = O + (size_t)(qrow + q) * 4096 + h * 128 + g * 4;
#pragma unroll
  for (int dt = 0; dt < 8; ++dt) {
    s16x4 o4;
#pragma unroll
    for (int r = 0; r < 4; ++r) o4[r] = (short)f2bf(of[dt][r] * inv);
    *(s16x4*)(op + dt * 16) = o4;
  }
}

extern "C" void kernel_launch(void* const* d_in, const int* in_sizes, int n_in,
                              void* d_out, int out_size, void* d_ws, size_t ws_size,
                              hipStream_t stream) {
  (void)in_sizes; (void)n_in; (void)out_size;
  const float* hs = (const float*)d_in[0];
  const float* Wq = (const float*)d_in[3];
  const float* Wk = (const float*)d_in[4];
  const float* Wv = (const float*)d_in[5];
  const float* Wo = (const float*)d_in[6];
  float* out = (float*)d_out;
  char* ws = (char*)d_ws;

  u16* Xb   = (u16*)(ws + 0);          // 16 MB : X bf16; reused as attn output Ao
  u16* Wt   = (u16*)(ws + 16777216);   // 32 MB : WqT, then KV partial arena, then WoT
  u16* WkvT = (u16*)(ws + 50331648);   // 16 MB : [Wk^T;Wv^T]; later P0o
  u16* Qb   = (u16*)(ws + 67108864);   // 16 MB : Q-proj half-0 partial; later P1o
  u16* Kb   = (u16*)(ws + 83886080);   // 4 MB  : K (rope'd) [2048][1024]
  u16* Vtb  = (u16*)(ws + 88080384);   // 4 MB  : V^T [1024][2048]
  u16* P1q  = (u16*)(ws + 96468992);   // 16 MB : Q-proj half-1 partial (read by attn)
  u16* PKV  = Wt;                      // KV split-K partial arena (WqT dead post-Q-proj)
  u16* P0o  = WkvT;                    // O-proj half-0 partial (WkvT dead post-KV-proj)
  u16* P1o  = Qb;                      // O-proj half-1 partial (Qb dead post-attn)
  u16* Ao   = Xb;                      // attn output (X dead post-KV-proj)
  if (ws_size < 113246208u) return;

  cvt_f32_bf16_kernel<<<dim3(2097152 / 256), 256, 0, stream>>>(hs, Xb, 2097152);

  // fused Wq/Wk/Wv transpose-convert (64x64 tiles)
  tconv3_kernel<<<dim3(6144), 256, 0, stream>>>(Wq, Wk, Wv, Wt, WkvT);

  // Q projection: 256^2 split-K=2, bf16 partials (combine+rope fused into attn)
  gemm256_kernel<<<dim3(16, 8, 2), 512, 0, stream>>>(Xb, Wt, Qb, P1q, 4096, 4096, 2048);

  // fused K+V projection: 256^2 split-K=4 into partial arena
  gemm_kv256_kernel<<<dim3(8, 8, 4), 512, 0, stream>>>(Xb, WkvT, PKV, 4096, 1024);
  // combine partials + K RoPE
  combine_kv_rope_kernel<<<dim3(1536), 256, 0, stream>>>(PKV, Kb, Vtb);

  // attention (Q combine + RoPE + scale fused); output -> Ao (=Xb)
  attn_kernel<<<dim3(16, 32), 512, 0, stream>>>(Qb, P1q, Kb, Vtb, Ao);

  // output projection: transpose Wo, 256^2 split-K=2 (bf16 partials), combine to f32
  tconv1_kernel<<<dim3(4096), 256, 0, stream>>>(Wo, Wt);
  gemm256_kernel<<<dim3(16, 8, 2), 512, 0, stream>>>(Ao, Wt, P0o, P1o, 4096, 4096, 2048);
  combine2_f32_kernel<<<dim3(4096), 256, 0, stream>>>(out, P0o, P1o, 1048576);
}

// Round 19
// 299.766 us; speedup vs baseline: 1.0896x; 1.0135x over previous
//
#include <hip/hip_runtime.h>

typedef __attribute__((ext_vector_type(8))) short short8;
typedef __attribute__((ext_vector_type(4))) short s16x4;
typedef __attribute__((ext_vector_type(4))) float f32x4;
typedef unsigned short u16;
typedef unsigned int u32;

__device__ __forceinline__ u16 f2bf(float f) {
  union { float f; unsigned int u; } v; v.f = f;
  unsigned int r = (v.u + 0x7FFFu + ((v.u >> 16) & 1u)) >> 16;
  return (u16)r;
}
__device__ __forceinline__ float bf2f(u16 b) {
  union { unsigned int u; float f; } v; v.u = ((unsigned int)b) << 16;
  return v.f;
}
__device__ __forceinline__ void load_lds16(const void* g, void* l) {
  __builtin_amdgcn_global_load_lds((const __attribute__((address_space(1))) void*)g,
                                   (__attribute__((address_space(3))) void*)l, 16, 0, 0);
}

// ---------------- 64x64-tile fp32 [K][N] -> bf16 [N][K] transpose core ----------------
__device__ __forceinline__ void tconv64_tile(const float* __restrict__ W, u16* __restrict__ Wt,
                                             int K, int N, int nb, int kb, int tid) {
  __shared__ float tile[64][65];
  int tx = tid & 15, ty = tid >> 4;          // 16 x 16
  const float* src = W + (size_t)(kb + ty) * N + nb + tx * 4;
#pragma unroll
  for (int i = 0; i < 4; ++i) {
    float4 v = *(const float4*)(src + (size_t)i * 16 * N);
    tile[ty + i * 16][tx * 4 + 0] = v.x;
    tile[ty + i * 16][tx * 4 + 1] = v.y;
    tile[ty + i * 16][tx * 4 + 2] = v.z;
    tile[ty + i * 16][tx * 4 + 3] = v.w;
  }
  __syncthreads();
  u16* dst = Wt + (size_t)(nb + ty) * K + kb + tx * 4;
#pragma unroll
  for (int i = 0; i < 4; ++i) {
    s16x4 o;
#pragma unroll
    for (int j = 0; j < 4; ++j) o[j] = (short)f2bf(tile[tx * 4 + j][ty + i * 16]);
    *(s16x4*)(dst + (size_t)i * 16 * K) = o;
  }
}

// fused: Wq/Wk/Wv transpose-convert + X cvt f32->bf16 + RoPE cos/sin table
__global__ void prep_kernel(const float* __restrict__ Wq, const float* __restrict__ Wk,
                            const float* __restrict__ Wv, u16* __restrict__ WqT,
                            u16* __restrict__ WkvT, const float* __restrict__ X,
                            u16* __restrict__ Xb, float* __restrict__ Tab) {
  int id = blockIdx.x;
  int tid = threadIdx.x;
  if (id < 4096) { tconv64_tile(Wq, WqT, 4096, 4096, (id & 63) * 64, (id >> 6) * 64, tid); return; }
  if (id < 5120) { int t = id - 4096; tconv64_tile(Wk, WkvT, 4096, 1024, (t & 15) * 64, (t >> 4) * 64, tid); return; }
  if (id < 6144) { int t = id - 5120; tconv64_tile(Wv, WkvT + (size_t)1024 * 4096, 4096, 1024, (t & 15) * 64, (t >> 4) * 64, tid); return; }
  if (id < 14336) {
    int i = (id - 6144) * 256 + tid;             // float4 index, 2097152 total
    float4 v = ((const float4*)X)[i];
    ushort4 o;
    o.x = f2bf(v.x); o.y = f2bf(v.y); o.z = f2bf(v.z); o.w = f2bf(v.w);
    ((ushort4*)Xb)[i] = o;
    return;
  }
  {
    int i = (id - 14336) * 256 + tid;            // 0..131071 : (s, j)
    int s = i >> 6, j = i & 63;
    float invf = exp2f(-(float)j * (13.287712379549449f / 64.0f)); // 10000^(-j/64)
    float sn, cs;
    sincosf((float)s * invf, &sn, &cs);
    Tab[(size_t)s * 128 + j * 2]     = cs;
    Tab[(size_t)s * 128 + j * 2 + 1] = sn;
  }
}

// single-weight transpose (Wo)
__global__ void tconv1_kernel(const float* __restrict__ W, u16* __restrict__ Wt) {
  int id = blockIdx.x;
  tconv64_tile(W, Wt, 4096, 4096, (id & 63) * 64, (id >> 6) * 64, threadIdx.x);
}

// out_f32 = bf16(p0) + bf16(p1)
__global__ void combine2_f32_kernel(float* __restrict__ out, const u16* __restrict__ p0,
                                    const u16* __restrict__ p1, int n8) {
  int i = blockIdx.x * blockDim.x + threadIdx.x;
  if (i >= n8) return;
  short8 a = ((const short8*)p0)[i];
  short8 b = ((const short8*)p1)[i];
  float4 o0, o1;
  o0.x = bf2f((u16)a[0]) + bf2f((u16)b[0]);
  o0.y = bf2f((u16)a[1]) + bf2f((u16)b[1]);
  o0.z = bf2f((u16)a[2]) + bf2f((u16)b[2]);
  o0.w = bf2f((u16)a[3]) + bf2f((u16)b[3]);
  o1.x = bf2f((u16)a[4]) + bf2f((u16)b[4]);
  o1.y = bf2f((u16)a[5]) + bf2f((u16)b[5]);
  o1.z = bf2f((u16)a[6]) + bf2f((u16)b[6]);
  o1.w = bf2f((u16)a[7]) + bf2f((u16)b[7]);
  ((float4*)out)[i * 2]     = o0;
  ((float4*)out)[i * 2 + 1] = o1;
}

// sum 4 KV split-K partials; apply RoPE (table) to K; -> Kb, Vt
__global__ void combine_kv_rope_kernel(const u16* __restrict__ PKV, u16* __restrict__ Kb,
                                       u16* __restrict__ Vt, const float* __restrict__ Tab) {
  int i = blockIdx.x * blockDim.x + threadIdx.x;   // 0..393215
  if (i < 131072) {
    int s = i >> 6, r = i & 63, hh = r >> 3, c = r & 7;
    size_t lo8 = (size_t)s * 128 + hh * 16 + c;    // short8 index
    size_t hi8 = lo8 + 8;
    float lo[8] = {0,0,0,0,0,0,0,0}, hi[8] = {0,0,0,0,0,0,0,0};
#pragma unroll
    for (int z = 0; z < 4; ++z) {
      short8 a = *(const short8*)(PKV + (size_t)z * 4194304 + lo8 * 8);
      short8 b = *(const short8*)(PKV + (size_t)z * 4194304 + hi8 * 8);
#pragma unroll
      for (int j = 0; j < 8; ++j) { lo[j] += bf2f((u16)a[j]); hi[j] += bf2f((u16)b[j]); }
    }
    const float* tr = Tab + (size_t)s * 128 + c * 16;
    short8 olo, ohi;
#pragma unroll
    for (int ii = 0; ii < 8; ++ii) {
      float cs = tr[ii * 2], sn = tr[ii * 2 + 1];
      olo[ii] = (short)f2bf(lo[ii] * cs - hi[ii] * sn);
      ohi[ii] = (short)f2bf(hi[ii] * cs + lo[ii] * sn);
    }
    *(short8*)(Kb + lo8 * 8) = olo;
    *(short8*)(Kb + hi8 * 8) = ohi;
  } else {
    int v = i - 131072;                             // 0..262143
    const u16* src = PKV + 2097152;
    float sm[8] = {0,0,0,0,0,0,0,0};
#pragma unroll
    for (int z = 0; z < 4; ++z) {
      short8 a = *(const short8*)(src + (size_t)z * 4194304 + (size_t)v * 8);
#pragma unroll
      for (int j = 0; j < 8; ++j) sm[j] += bf2f((u16)a[j]);
    }
    short8 o;
#pragma unroll
    for (int j = 0; j < 8; ++j) o[j] = (short)f2bf(sm[j]);
    ((short8*)Vt)[v] = o;
  }
}

// ---------------- 256x256 split-K bf16 GEMM, fat per-wave tile (r15 verified) ----------------
__global__ __launch_bounds__(512, 1) void gemm256_kernel(
    const u16* __restrict__ A, const u16* __restrict__ B,
    u16* __restrict__ C0, u16* __restrict__ C1, int N, int K, int KH) {
  __shared__ u16 As[2][256 * 64];
  __shared__ u16 Bs[2][256 * 64];
  int tid = threadIdx.x, lane = tid & 63, wid = tid >> 6;
  int wr = wid >> 2, wc = wid & 3;
  int g = lane >> 4, q = lane & 15;
  int id = blockIdx.z * gridDim.x * gridDim.y + blockIdx.y * gridDim.x + blockIdx.x;
  int tot = gridDim.x * gridDim.y * gridDim.z;
  int swz = (id & 7) * (tot >> 3) + (id >> 3);
  int perh = gridDim.x * gridDim.y;
  int z = swz / perh, rem = swz % perh;
  int m0 = (rem / gridDim.x) * 256, n0 = (rem % gridDim.x) * 256;
  int k0 = z * KH;
  f32x4 acc[8][4];
#pragma unroll
  for (int i = 0; i < 8; ++i)
#pragma unroll
    for (int j = 0; j < 4; ++j) acc[i][j] = (f32x4){0.f, 0.f, 0.f, 0.f};
  int srow = tid >> 3;
  int scol = ((tid & 7) ^ (srow & 7)) << 3;
  const u16* ga = A + (size_t)(m0 + srow) * K + k0 + scol;
  const u16* gb = B + (size_t)(n0 + srow) * K + k0 + scol;
  int xorm = (q & 7) << 3;
  int arow = wr * 128 + q;
  int brow = wc * 64 + q;
  int nt = KH >> 6;

  auto stage = [&](int buf, int t) {
    const u16* pa = ga + t * 64;
    const u16* pb = gb + t * 64;
#pragma unroll
    for (int it = 0; it < 4; ++it) {
      load_lds16(pa + (size_t)it * 64 * K, (char*)(&As[buf][0]) + it * 8192 + tid * 16);
      load_lds16(pb + (size_t)it * 64 * K, (char*)(&Bs[buf][0]) + it * 8192 + tid * 16);
    }
  };

  stage(0, 0);
  stage(1, 1);
  asm volatile("s_waitcnt vmcnt(8)" ::: "memory");
  __builtin_amdgcn_s_barrier();
  for (int t = 0; t < nt; ++t) {
    int cur = t & 1;
    int col0 = (g * 8) ^ xorm;
    short8 a0[8], b0[4];
#pragma unroll
    for (int m = 0; m < 8; ++m) a0[m] = *(const short8*)&As[cur][(arow + m * 16) * 64 + col0];
#pragma unroll
    for (int n = 0; n < 4; ++n) b0[n] = *(const short8*)&Bs[cur][(brow + n * 16) * 64 + col0];
    __builtin_amdgcn_s_setprio(1);
#pragma unroll
    for (int m = 0; m < 8; ++m)
#pragma unroll
      for (int n = 0; n < 4; ++n)
        acc[m][n] = __builtin_amdgcn_mfma_f32_16x16x32_bf16(a0[m], b0[n], acc[m][n], 0, 0, 0);
    __builtin_amdgcn_s_setprio(0);
    int col1 = (32 + g * 8) ^ xorm;
    short8 a1[8], b1[4];
#pragma unroll
    for (int m = 0; m < 8; ++m) a1[m] = *(const short8*)&As[cur][(arow + m * 16) * 64 + col1];
#pragma unroll
    for (int n = 0; n < 4; ++n) b1[n] = *(const short8*)&Bs[cur][(brow + n * 16) * 64 + col1];
    asm volatile("s_waitcnt lgkmcnt(0)" ::: "memory");
    __builtin_amdgcn_s_barrier();
    if (t + 2 < nt) stage(cur, t + 2);
    __builtin_amdgcn_sched_barrier(0);
    __builtin_amdgcn_s_setprio(1);
#pragma unroll
    for (int m = 0; m < 8; ++m)
#pragma unroll
      for (int n = 0; n < 4; ++n)
        acc[m][n] = __builtin_amdgcn_mfma_f32_16x16x32_bf16(a1[m], b1[n], acc[m][n], 0, 0, 0);
    __builtin_amdgcn_s_setprio(0);
    if (t + 2 < nt)      { asm volatile("s_waitcnt vmcnt(8)" ::: "memory"); }
    else if (t + 1 < nt) { asm volatile("s_waitcnt vmcnt(0)" ::: "memory"); }
    __builtin_amdgcn_s_barrier();
  }
  int crow = m0 + wr * 128 + g * 4;
  int ccol = n0 + wc * 64 + q;
  u16* dst = z ? C1 : C0;
#pragma unroll
  for (int fm = 0; fm < 8; ++fm)
#pragma unroll
    for (int fn = 0; fn < 4; ++fn)
#pragma unroll
      for (int r = 0; r < 4; ++r)
        dst[(size_t)(crow + fm * 16 + r) * N + ccol + fn * 16] = f2bf(acc[fm][fn][r]);
}

// ---------------- KV-proj: same fat-tile body, grid (8,8,4) split-K=4 (r15 verified) -------
__global__ __launch_bounds__(512, 1) void gemm_kv256_kernel(
    const u16* __restrict__ A, const u16* __restrict__ B,
    u16* __restrict__ PKV, int K, int KH) {
  __shared__ u16 As[2][256 * 64];
  __shared__ u16 Bs[2][256 * 64];
  int tid = threadIdx.x, lane = tid & 63, wid = tid >> 6;
  int wr = wid >> 2, wc = wid & 3;
  int g = lane >> 4, q = lane & 15;
  int id = blockIdx.z * 64 + blockIdx.y * 8 + blockIdx.x;   // 256 blocks
  int swz = (id & 7) * 32 + (id >> 3);
  int z = swz >> 6, rem = swz & 63;
  int m0 = (rem >> 3) * 256, n0 = (rem & 7) * 256;
  int k0 = z * KH;
  f32x4 acc[8][4];
#pragma unroll
  for (int i = 0; i < 8; ++i)
#pragma unroll
    for (int j = 0; j < 4; ++j) acc[i][j] = (f32x4){0.f, 0.f, 0.f, 0.f};
  int srow = tid >> 3;
  int scol = ((tid & 7) ^ (srow & 7)) << 3;
  const u16* ga = A + (size_t)(m0 + srow) * K + k0 + scol;
  const u16* gb = B + (size_t)(n0 + srow) * K + k0 + scol;
  int xorm = (q & 7) << 3;
  int arow = wr * 128 + q;
  int brow = wc * 64 + q;
  int nt = KH >> 6;   // 16

  auto stage = [&](int buf, int t) {
    const u16* pa = ga + t * 64;
    const u16* pb = gb + t * 64;
#pragma unroll
    for (int it = 0; it < 4; ++it) {
      load_lds16(pa + (size_t)it * 64 * K, (char*)(&As[buf][0]) + it * 8192 + tid * 16);
      load_lds16(pb + (size_t)it * 64 * K, (char*)(&Bs[buf][0]) + it * 8192 + tid * 16);
    }
  };

  stage(0, 0);
  stage(1, 1);
  asm volatile("s_waitcnt vmcnt(8)" ::: "memory");
  __builtin_amdgcn_s_barrier();
  for (int t = 0; t < nt; ++t) {
    int cur = t & 1;
    int col0 = (g * 8) ^ xorm;
    short8 a0[8], b0[4];
#pragma unroll
    for (int m = 0; m < 8; ++m) a0[m] = *(const short8*)&As[cur][(arow + m * 16) * 64 + col0];
#pragma unroll
    for (int n = 0; n < 4; ++n) b0[n] = *(const short8*)&Bs[cur][(brow + n * 16) * 64 + col0];
    __builtin_amdgcn_s_setprio(1);
#pragma unroll
    for (int m = 0; m < 8; ++m)
#pragma unroll
      for (int n = 0; n < 4; ++n)
        acc[m][n] = __builtin_amdgcn_mfma_f32_16x16x32_bf16(a0[m], b0[n], acc[m][n], 0, 0, 0);
    __builtin_amdgcn_s_setprio(0);
    int col1 = (32 + g * 8) ^ xorm;
    short8 a1[8], b1[4];
#pragma unroll
    for (int m = 0; m < 8; ++m) a1[m] = *(const short8*)&As[cur][(arow + m * 16) * 64 + col1];
#pragma unroll
    for (int n = 0; n < 4; ++n) b1[n] = *(const short8*)&Bs[cur][(brow + n * 16) * 64 + col1];
    asm volatile("s_waitcnt lgkmcnt(0)" ::: "memory");
    __builtin_amdgcn_s_barrier();
    if (t + 2 < nt) stage(cur, t + 2);
    __builtin_amdgcn_sched_barrier(0);
    __builtin_amdgcn_s_setprio(1);
#pragma unroll
    for (int m = 0; m < 8; ++m)
#pragma unroll
      for (int n = 0; n < 4; ++n)
        acc[m][n] = __builtin_amdgcn_mfma_f32_16x16x32_bf16(a1[m], b1[n], acc[m][n], 0, 0, 0);
    __builtin_amdgcn_s_setprio(0);
    if (t + 2 < nt)      { asm volatile("s_waitcnt vmcnt(8)" ::: "memory"); }
    else if (t + 1 < nt) { asm volatile("s_waitcnt vmcnt(0)" ::: "memory"); }
    __builtin_amdgcn_s_barrier();
  }
  int crow = m0 + wr * 128 + g * 4;
  int ccol = n0 + wc * 64 + q;
  u16* Kpart = PKV + (size_t)z * 4194304;
  u16* Vpart = Kpart + 2097152;
  if (n0 < 1024) {
#pragma unroll
    for (int fm = 0; fm < 8; ++fm)
#pragma unroll
      for (int fn = 0; fn < 4; ++fn)
#pragma unroll
        for (int r = 0; r < 4; ++r)
          Kpart[(size_t)(crow + fm * 16 + r) * 1024 + ccol + fn * 16] = f2bf(acc[fm][fn][r]);
  } else {
#pragma unroll
    for (int fn = 0; fn < 4; ++fn) {
      int vcol = ccol + fn * 16 - 1024;
#pragma unroll
      for (int fm = 0; fm < 8; ++fm) {
        s16x4 o;
#pragma unroll
        for (int r = 0; r < 4; ++r) o[r] = (short)f2bf(acc[fm][fn][r]);
        *(s16x4*)(Vpart + (size_t)vcol * 2048 + crow + fm * 16) = o;
      }
    }
  }
}

// ---------------- flash attention + fused Q combine/RoPE (table), window 1024 -------------
__global__ __launch_bounds__(512, 4) void attn_kernel(
    const u16* __restrict__ Q0, const u16* __restrict__ Q1,
    const u16* __restrict__ Kg, const u16* __restrict__ Vt,
    const float* __restrict__ Tab, u16* __restrict__ O) {
  __shared__ u16 Ks[2][64 * 128];
  __shared__ u16 Vs[2][128 * 64];
  int tid = threadIdx.x, lane = tid & 63, w = tid >> 6;
  int wg = w >> 2;
  int g = lane >> 4, q = lane & 15;
  int q0 = blockIdx.x * 128;
  int h = blockIdx.y, hk = h >> 2;
  int qbase = q0 + wg * 64;
  int qrow = qbase + (w & 3) * 16;
  int xorm = (lane & 7) << 3;
  int bjt_lo = (q0 >= 1024) ? ((q0 - 1023) >> 6) : 0;
  int bjt_hi = (q0 + 64) >> 6;
  int wjt_lo = (qbase >= 1024) ? ((qbase - 1023) >> 6) : 0;
  int wjt_hi = qbase >> 6;
  int krow = tid >> 4;
  int kchunk = (tid & 15) ^ (krow & 7);
  const u16* kbase = Kg + (size_t)krow * 1024 + hk * 128 + (kchunk << 3);
  int vrow = tid >> 3;
  int vchunk = (tid & 7) ^ (vrow & 7);
  const u16* vbase = Vt + (size_t)(hk * 128 + vrow) * 2048 + (vchunk << 3);

  auto stageK = [&](int buf, int j0) {
    const u16* gp = kbase + (size_t)j0 * 1024;
#pragma unroll
    for (int it = 0; it < 2; ++it)
      load_lds16(gp + (size_t)it * 32 * 1024, (char*)(&Ks[buf][0]) + it * 8192 + tid * 16);
  };
  auto stageV = [&](int buf, int j0) {
    const u16* gp = vbase + j0;
#pragma unroll
    for (int it = 0; it < 2; ++it)
      load_lds16(gp + (size_t)it * 64 * 2048, (char*)(&Vs[buf][0]) + it * 8192 + tid * 16);
  };

  // issue first K/V stage, then do Q combine+rope under the load latency
  stageK(0, bjt_lo << 6);
  stageV(0, bjt_lo << 6);
  short8 qf[4];
  {
    size_t qoff = (size_t)(qrow + q) * 4096 + h * 128 + g * 8;
    float sum[4][8];
#pragma unroll
    for (int kk = 0; kk < 4; ++kk) {
      short8 a = *(const short8*)(Q0 + qoff + kk * 32);
      short8 b = *(const short8*)(Q1 + qoff + kk * 32);
#pragma unroll
      for (int i = 0; i < 8; ++i) sum[kk][i] = bf2f((u16)a[i]) + bf2f((u16)b[i]);
    }
    const float scale = 0.12751781828987514f;   // log2(e)/sqrt(128)
    const float* tr = Tab + (size_t)(qrow + q) * 128;
#pragma unroll
    for (int kk = 0; kk < 2; ++kk)
#pragma unroll
      for (int i = 0; i < 8; ++i) {
        int j = kk * 32 + g * 8 + i;
        float cs = tr[j * 2], sn = tr[j * 2 + 1];
        float lo = sum[kk][i], hi = sum[kk + 2][i];
        qf[kk][i]     = (short)f2bf((lo * cs - hi * sn) * scale);
        qf[kk + 2][i] = (short)f2bf((hi * cs + lo * sn) * scale);
      }
  }
  float mrow = -1e30f, lsum = 0.f;
  f32x4 of[8];
#pragma unroll
  for (int d = 0; d < 8; ++d) of[d] = (f32x4){0.f, 0.f, 0.f, 0.f};

  int cur = 0;
  asm volatile("s_waitcnt vmcnt(0)" ::: "memory");
  __syncthreads();
  for (int jt = bjt_lo; jt <= bjt_hi; ++jt) {
    int j0 = jt << 6;
    if (jt < bjt_hi) { stageK(cur ^ 1, j0 + 64); stageV(cur ^ 1, j0 + 64); }
    if (jt >= wjt_lo && jt <= wjt_hi) {
      f32x4 sf[4];
#pragma unroll
      for (int nt = 0; nt < 4; ++nt) sf[nt] = (f32x4){0.f, 0.f, 0.f, 0.f};
      const u16* ks = &Ks[cur][0];
      __builtin_amdgcn_s_setprio(1);
#pragma unroll
      for (int kk = 0; kk < 4; ++kk) {
        short8 qv = qf[kk];
        int col = (kk * 32 + g * 8) ^ xorm;
#pragma unroll
        for (int nt = 0; nt < 4; ++nt) {
          short8 kf = *(const short8*)&ks[(nt * 16 + q) * 128 + col];
          sf[nt] = __builtin_amdgcn_mfma_f32_16x16x32_bf16(kf, qv, sf[nt], 0, 0, 0);
        }
      }
      __builtin_amdgcn_s_setprio(0);
      float p[4][4];
#pragma unroll
      for (int nt = 0; nt < 4; ++nt)
#pragma unroll
        for (int r = 0; r < 4; ++r) p[nt][r] = sf[nt][r];
      if (j0 + 63 > qrow || j0 + 1009 <= qrow) {
        int qq = qrow + q;
        int kb = j0 + g * 4;
#pragma unroll
        for (int nt = 0; nt < 4; ++nt)
#pragma unroll
          for (int r = 0; r < 4; ++r) {
            int key = kb + nt * 16 + r;
            if (key > qq || key + 1024 <= qq) p[nt][r] = -1e9f;
          }
      }
      float tm = p[0][0];
#pragma unroll
      for (int nt = 0; nt < 4; ++nt)
#pragma unroll
        for (int r = 0; r < 4; ++r) tm = fmaxf(tm, p[nt][r]);
      tm = fmaxf(tm, __shfl_xor(tm, 16));
      tm = fmaxf(tm, __shfl_xor(tm, 32));
      if (__any(tm > mrow + 8.f)) {
        float nm = fmaxf(mrow, tm);
        float sc = __builtin_amdgcn_exp2f(mrow - nm);
        mrow = nm;
        lsum *= sc;
#pragma unroll
        for (int d = 0; d < 8; ++d) of[d] *= sc;
      }
      float ps = 0.f;
#pragma unroll
      for (int nt = 0; nt < 4; ++nt)
#pragma unroll
        for (int r = 0; r < 4; ++r) {
          float e = __builtin_amdgcn_exp2f(p[nt][r] - mrow);
          p[nt][r] = e;
          ps += e;
        }
      ps += __shfl_xor(ps, 16);
      ps += __shfl_xor(ps, 32);
      lsum += ps;
      u32 pk[4][2];
#pragma unroll
      for (int nt = 0; nt < 4; ++nt) {
        pk[nt][0] = __builtin_amdgcn_perm(__float_as_uint(p[nt][1]), __float_as_uint(p[nt][0]), 0x07060302u);
        pk[nt][1] = __builtin_amdgcn_perm(__float_as_uint(p[nt][3]), __float_as_uint(p[nt][2]), 0x07060302u);
      }
      int s0 = q + ((g & 1) ? 32 : 0);
      int s1 = s0 + 16;
      bool hi_sel = g >= 2;
      const u16* vs = &Vs[cur][0];
      __builtin_amdgcn_s_setprio(1);
#pragma unroll
      for (int kh = 0; kh < 2; ++kh) {
        int lo = kh * 2, hi = lo + 1;
        u32 a0 = (u32)__shfl((int)pk[lo][0], s0);
        u32 a1 = (u32)__shfl((int)pk[lo][1], s0);
        u32 b0 = (u32)__shfl((int)pk[hi][0], s0);
        u32 b1 = (u32)__shfl((int)pk[hi][1], s0);
        u32 a2 = (u32)__shfl((int)pk[lo][0], s1);
        u32 a3 = (u32)__shfl((int)pk[lo][1], s1);
        u32 b2 = (u32)__shfl((int)pk[hi][0], s1);
        u32 b3 = (u32)__shfl((int)pk[hi][1], s1);
        union { u32 u[4]; short8 s; } pb;
        pb.u[0] = hi_sel ? b0 : a0;
        pb.u[1] = hi_sel ? b1 : a1;
        pb.u[2] = hi_sel ? b2 : a2;
        pb.u[3] = hi_sel ? b3 : a3;
        int col = (kh * 32 + g * 8) ^ xorm;
#pragma unroll
        for (int dt = 0; dt < 8; ++dt) {
          short8 vv = *(const short8*)&vs[(dt * 16 + q) * 64 + col];
          of[dt] = __builtin_amdgcn_mfma_f32_16x16x32_bf16(vv, pb.s, of[dt], 0, 0, 0);
        }
      }
      __builtin_amdgcn_s_setprio(0);
    }
    asm volatile("s_waitcnt vmcnt(0)" ::: "memory");
    __builtin_amdgcn_s_barrier();
    cur ^= 1;
  }
  float inv = 1.f / lsum;
  u16* op = O + (size_t)(qrow + q) * 4096 + h * 128 + g * 4;
#pragma unroll
  for (int dt = 0; dt < 8; ++dt) {
    s16x4 o4;
#pragma unroll
    for (int r = 0; r < 4; ++r) o4[r] = (short)f2bf(of[dt][r] * inv);
    *(s16x4*)(op + dt * 16) = o4;
  }
}

extern "C" void kernel_launch(void* const* d_in, const int* in_sizes, int n_in,
                              void* d_out, int out_size, void* d_ws, size_t ws_size,
                              hipStream_t stream) {
  (void)in_sizes; (void)n_in; (void)out_size;
  const float* hs = (const float*)d_in[0];
  const float* Wq = (const float*)d_in[3];
  const float* Wk = (const float*)d_in[4];
  const float* Wv = (const float*)d_in[5];
  const float* Wo = (const float*)d_in[6];
  float* out = (float*)d_out;
  char* ws = (char*)d_ws;

  u16* Xb   = (u16*)(ws + 0);          // 16 MB : X bf16; reused as attn output Ao
  u16* Wt   = (u16*)(ws + 16777216);   // 32 MB : WqT, then KV partial arena, then WoT
  u16* WkvT = (u16*)(ws + 50331648);   // 16 MB : [Wk^T;Wv^T]; later P0o
  u16* Qb   = (u16*)(ws + 67108864);   // 16 MB : Q-proj half-0 partial; later P1o
  u16* Kb   = (u16*)(ws + 83886080);   // 4 MB  : K (rope'd) [2048][1024]
  u16* Vtb  = (u16*)(ws + 88080384);   // 4 MB  : V^T [1024][2048]
  float* Tab = (float*)(ws + 92274688);// 1 MB  : RoPE cos/sin table [2048][64][2]
  u16* P1q  = (u16*)(ws + 96468992);   // 16 MB : Q-proj half-1 partial (read by attn)
  u16* PKV  = Wt;                      // KV split-K partial arena (WqT dead post-Q-proj)
  u16* P0o  = WkvT;                    // O-proj half-0 partial (WkvT dead post-KV-proj)
  u16* P1o  = Qb;                      // O-proj half-1 partial (Qb dead post-attn)
  u16* Ao   = Xb;                      // attn output (X dead post-KV-proj)
  if (ws_size < 113246208u) return;

  // fused prep: Wq/Wk/Wv transpose + X cvt + RoPE table
  prep_kernel<<<dim3(14848), 256, 0, stream>>>(Wq, Wk, Wv, Wt, WkvT, hs, Xb, Tab);

  // Q projection: 256^2 split-K=2, bf16 partials (combine+rope fused into attn)
  gemm256_kernel<<<dim3(16, 8, 2), 512, 0, stream>>>(Xb, Wt, Qb, P1q, 4096, 4096, 2048);

  // fused K+V projection: 256^2 split-K=4 into partial arena
  gemm_kv256_kernel<<<dim3(8, 8, 4), 512, 0, stream>>>(Xb, WkvT, PKV, 4096, 1024);
  // combine partials + K RoPE (table)
  combine_kv_rope_kernel<<<dim3(1536), 256, 0, stream>>>(PKV, Kb, Vtb, Tab);

  // attention (Q combine + RoPE + scale fused); output -> Ao (=Xb)
  attn_kernel<<<dim3(16, 32), 512, 0, stream>>>(Qb, P1q, Kb, Vtb, Tab, Ao);

  // output projection: transpose Wo, 256^2 split-K=2 (bf16 partials), combine to f32
  tconv1_kernel<<<dim3(4096), 256, 0, stream>>>(Wo, Wt);
  gemm256_kernel<<<dim3(16, 8, 2), 512, 0, stream>>>(Ao, Wt, P0o, P1o, 4096, 4096, 2048);
  combine2_f32_kernel<<<dim3(4096), 256, 0, stream>>>(out, P0o, P1o, 1048576);
}

// Round 20
// 294.319 us; speedup vs baseline: 1.1098x; 1.0185x over previous
//
#include <hip/hip_runtime.h>

typedef __attribute__((ext_vector_type(8))) short short8;
typedef __attribute__((ext_vector_type(4))) short s16x4;
typedef __attribute__((ext_vector_type(4))) float f32x4;
typedef unsigned short u16;
typedef unsigned int u32;

__device__ __forceinline__ u16 f2bf(float f) {
  union { float f; unsigned int u; } v; v.f = f;
  unsigned int r = (v.u + 0x7FFFu + ((v.u >> 16) & 1u)) >> 16;
  return (u16)r;
}
__device__ __forceinline__ float bf2f(u16 b) {
  union { unsigned int u; float f; } v; v.u = ((unsigned int)b) << 16;
  return v.f;
}
__device__ __forceinline__ void load_lds16(const void* g, void* l) {
  __builtin_amdgcn_global_load_lds((const __attribute__((address_space(1))) void*)g,
                                   (__attribute__((address_space(3))) void*)l, 16, 0, 0);
}

// ---------------- 64x64-tile fp32 [K][N] -> bf16 [N][K] transpose core ----------------
__device__ __forceinline__ void tconv64_tile(const float* __restrict__ W, u16* __restrict__ Wt,
                                             int K, int N, int nb, int kb, int tid) {
  __shared__ float tile[64][65];
  int tx = tid & 15, ty = tid >> 4;          // 16 x 16
  const float* src = W + (size_t)(kb + ty) * N + nb + tx * 4;
#pragma unroll
  for (int i = 0; i < 4; ++i) {
    float4 v = *(const float4*)(src + (size_t)i * 16 * N);
    tile[ty + i * 16][tx * 4 + 0] = v.x;
    tile[ty + i * 16][tx * 4 + 1] = v.y;
    tile[ty + i * 16][tx * 4 + 2] = v.z;
    tile[ty + i * 16][tx * 4 + 3] = v.w;
  }
  __syncthreads();
  u16* dst = Wt + (size_t)(nb + ty) * K + kb + tx * 4;
#pragma unroll
  for (int i = 0; i < 4; ++i) {
    s16x4 o;
#pragma unroll
    for (int j = 0; j < 4; ++j) o[j] = (short)f2bf(tile[tx * 4 + j][ty + i * 16]);
    *(s16x4*)(dst + (size_t)i * 16 * K) = o;
  }
}

// fused: Wq/Wk/Wv transpose-convert + X cvt f32->bf16 + RoPE cos/sin table
__global__ void prep_kernel(const float* __restrict__ Wq, const float* __restrict__ Wk,
                            const float* __restrict__ Wv, u16* __restrict__ WqT,
                            u16* __restrict__ WkvT, const float* __restrict__ X,
                            u16* __restrict__ Xb, float* __restrict__ Tab) {
  int id = blockIdx.x;
  int tid = threadIdx.x;
  if (id < 4096) { tconv64_tile(Wq, WqT, 4096, 4096, (id & 63) * 64, (id >> 6) * 64, tid); return; }
  if (id < 5120) { int t = id - 4096; tconv64_tile(Wk, WkvT, 4096, 1024, (t & 15) * 64, (t >> 4) * 64, tid); return; }
  if (id < 6144) { int t = id - 5120; tconv64_tile(Wv, WkvT + (size_t)1024 * 4096, 4096, 1024, (t & 15) * 64, (t >> 4) * 64, tid); return; }
  if (id < 14336) {
    int i = (id - 6144) * 256 + tid;             // float4 index, 2097152 total
    float4 v = ((const float4*)X)[i];
    ushort4 o;
    o.x = f2bf(v.x); o.y = f2bf(v.y); o.z = f2bf(v.z); o.w = f2bf(v.w);
    ((ushort4*)Xb)[i] = o;
    return;
  }
  {
    int i = (id - 14336) * 256 + tid;            // 0..131071 : (s, j)
    int s = i >> 6, j = i & 63;
    float invf = exp2f(-(float)j * (13.287712379549449f / 64.0f)); // 10000^(-j/64)
    float sn, cs;
    sincosf((float)s * invf, &sn, &cs);
    Tab[(size_t)s * 128 + j * 2]     = cs;
    Tab[(size_t)s * 128 + j * 2 + 1] = sn;
  }
}

// single-weight transpose (Wo)
__global__ void tconv1_kernel(const float* __restrict__ W, u16* __restrict__ Wt) {
  int id = blockIdx.x;
  tconv64_tile(W, Wt, 4096, 4096, (id & 63) * 64, (id >> 6) * 64, threadIdx.x);
}

// out_f32 = bf16(p0) + bf16(p1)
__global__ void combine2_f32_kernel(float* __restrict__ out, const u16* __restrict__ p0,
                                    const u16* __restrict__ p1, int n8) {
  int i = blockIdx.x * blockDim.x + threadIdx.x;
  if (i >= n8) return;
  short8 a = ((const short8*)p0)[i];
  short8 b = ((const short8*)p1)[i];
  float4 o0, o1;
  o0.x = bf2f((u16)a[0]) + bf2f((u16)b[0]);
  o0.y = bf2f((u16)a[1]) + bf2f((u16)b[1]);
  o0.z = bf2f((u16)a[2]) + bf2f((u16)b[2]);
  o0.w = bf2f((u16)a[3]) + bf2f((u16)b[3]);
  o1.x = bf2f((u16)a[4]) + bf2f((u16)b[4]);
  o1.y = bf2f((u16)a[5]) + bf2f((u16)b[5]);
  o1.z = bf2f((u16)a[6]) + bf2f((u16)b[6]);
  o1.w = bf2f((u16)a[7]) + bf2f((u16)b[7]);
  ((float4*)out)[i * 2]     = o0;
  ((float4*)out)[i * 2 + 1] = o1;
}

// sum 4 KV split-K partials; apply RoPE (table) to K; -> Kb, Vt
__global__ void combine_kv_rope_kernel(const u16* __restrict__ PKV, u16* __restrict__ Kb,
                                       u16* __restrict__ Vt, const float* __restrict__ Tab) {
  int i = blockIdx.x * blockDim.x + threadIdx.x;   // 0..393215
  if (i < 131072) {
    int s = i >> 6, r = i & 63, hh = r >> 3, c = r & 7;
    size_t lo8 = (size_t)s * 128 + hh * 16 + c;    // short8 index
    size_t hi8 = lo8 + 8;
    float lo[8] = {0,0,0,0,0,0,0,0}, hi[8] = {0,0,0,0,0,0,0,0};
#pragma unroll
    for (int z = 0; z < 4; ++z) {
      short8 a = *(const short8*)(PKV + (size_t)z * 4194304 + lo8 * 8);
      short8 b = *(const short8*)(PKV + (size_t)z * 4194304 + hi8 * 8);
#pragma unroll
      for (int j = 0; j < 8; ++j) { lo[j] += bf2f((u16)a[j]); hi[j] += bf2f((u16)b[j]); }
    }
    const float* tr = Tab + (size_t)s * 128 + c * 16;
    short8 olo, ohi;
#pragma unroll
    for (int ii = 0; ii < 8; ++ii) {
      float cs = tr[ii * 2], sn = tr[ii * 2 + 1];
      olo[ii] = (short)f2bf(lo[ii] * cs - hi[ii] * sn);
      ohi[ii] = (short)f2bf(hi[ii] * cs + lo[ii] * sn);
    }
    *(short8*)(Kb + lo8 * 8) = olo;
    *(short8*)(Kb + hi8 * 8) = ohi;
  } else {
    int v = i - 131072;                             // 0..262143
    const u16* src = PKV + 2097152;
    float sm[8] = {0,0,0,0,0,0,0,0};
#pragma unroll
    for (int z = 0; z < 4; ++z) {
      short8 a = *(const short8*)(src + (size_t)z * 4194304 + (size_t)v * 8);
#pragma unroll
      for (int j = 0; j < 8; ++j) sm[j] += bf2f((u16)a[j]);
    }
    short8 o;
#pragma unroll
    for (int j = 0; j < 8; ++j) o[j] = (short)f2bf(sm[j]);
    ((short8*)Vt)[v] = o;
  }
}

// ---------------- 256x256 split-K bf16 GEMM, fat per-wave tile (r15 verified) ----------------
__global__ __launch_bounds__(512, 1) void gemm256_kernel(
    const u16* __restrict__ A, const u16* __restrict__ B,
    u16* __restrict__ C0, u16* __restrict__ C1, int N, int K, int KH) {
  __shared__ u16 As[2][256 * 64];
  __shared__ u16 Bs[2][256 * 64];
  int tid = threadIdx.x, lane = tid & 63, wid = tid >> 6;
  int wr = wid >> 2, wc = wid & 3;
  int g = lane >> 4, q = lane & 15;
  int id = blockIdx.z * gridDim.x * gridDim.y + blockIdx.y * gridDim.x + blockIdx.x;
  int tot = gridDim.x * gridDim.y * gridDim.z;
  int swz = (id & 7) * (tot >> 3) + (id >> 3);
  int perh = gridDim.x * gridDim.y;
  int z = swz / perh, rem = swz % perh;
  int m0 = (rem / gridDim.x) * 256, n0 = (rem % gridDim.x) * 256;
  int k0 = z * KH;
  f32x4 acc[8][4];
#pragma unroll
  for (int i = 0; i < 8; ++i)
#pragma unroll
    for (int j = 0; j < 4; ++j) acc[i][j] = (f32x4){0.f, 0.f, 0.f, 0.f};
  int srow = tid >> 3;
  int scol = ((tid & 7) ^ (srow & 7)) << 3;
  const u16* ga = A + (size_t)(m0 + srow) * K + k0 + scol;
  const u16* gb = B + (size_t)(n0 + srow) * K + k0 + scol;
  int xorm = (q & 7) << 3;
  int arow = wr * 128 + q;
  int brow = wc * 64 + q;
  int nt = KH >> 6;

  auto stage = [&](int buf, int t) {
    const u16* pa = ga + t * 64;
    const u16* pb = gb + t * 64;
#pragma unroll
    for (int it = 0; it < 4; ++it) {
      load_lds16(pa + (size_t)it * 64 * K, (char*)(&As[buf][0]) + it * 8192 + tid * 16);
      load_lds16(pb + (size_t)it * 64 * K, (char*)(&Bs[buf][0]) + it * 8192 + tid * 16);
    }
  };

  stage(0, 0);
  stage(1, 1);
  asm volatile("s_waitcnt vmcnt(8)" ::: "memory");
  __builtin_amdgcn_s_barrier();
  for (int t = 0; t < nt; ++t) {
    int cur = t & 1;
    int col0 = (g * 8) ^ xorm;
    short8 a0[8], b0[4];
#pragma unroll
    for (int m = 0; m < 8; ++m) a0[m] = *(const short8*)&As[cur][(arow + m * 16) * 64 + col0];
#pragma unroll
    for (int n = 0; n < 4; ++n) b0[n] = *(const short8*)&Bs[cur][(brow + n * 16) * 64 + col0];
    __builtin_amdgcn_s_setprio(1);
#pragma unroll
    for (int m = 0; m < 8; ++m)
#pragma unroll
      for (int n = 0; n < 4; ++n)
        acc[m][n] = __builtin_amdgcn_mfma_f32_16x16x32_bf16(a0[m], b0[n], acc[m][n], 0, 0, 0);
    __builtin_amdgcn_s_setprio(0);
    int col1 = (32 + g * 8) ^ xorm;
    short8 a1[8], b1[4];
#pragma unroll
    for (int m = 0; m < 8; ++m) a1[m] = *(const short8*)&As[cur][(arow + m * 16) * 64 + col1];
#pragma unroll
    for (int n = 0; n < 4; ++n) b1[n] = *(const short8*)&Bs[cur][(brow + n * 16) * 64 + col1];
    asm volatile("s_waitcnt lgkmcnt(0)" ::: "memory");
    __builtin_amdgcn_s_barrier();
    if (t + 2 < nt) stage(cur, t + 2);
    __builtin_amdgcn_sched_barrier(0);
    __builtin_amdgcn_s_setprio(1);
#pragma unroll
    for (int m = 0; m < 8; ++m)
#pragma unroll
      for (int n = 0; n < 4; ++n)
        acc[m][n] = __builtin_amdgcn_mfma_f32_16x16x32_bf16(a1[m], b1[n], acc[m][n], 0, 0, 0);
    __builtin_amdgcn_s_setprio(0);
    if (t + 2 < nt)      { asm volatile("s_waitcnt vmcnt(8)" ::: "memory"); }
    else if (t + 1 < nt) { asm volatile("s_waitcnt vmcnt(0)" ::: "memory"); }
    __builtin_amdgcn_s_barrier();
  }
  int crow = m0 + wr * 128 + g * 4;
  int ccol = n0 + wc * 64 + q;
  u16* dst = z ? C1 : C0;
#pragma unroll
  for (int fm = 0; fm < 8; ++fm)
#pragma unroll
    for (int fn = 0; fn < 4; ++fn)
#pragma unroll
      for (int r = 0; r < 4; ++r)
        dst[(size_t)(crow + fm * 16 + r) * N + ccol + fn * 16] = f2bf(acc[fm][fn][r]);
}

// ---------------- KV-proj: same fat-tile body, grid (8,8,4) split-K=4 (r15 verified) -------
__global__ __launch_bounds__(512, 1) void gemm_kv256_kernel(
    const u16* __restrict__ A, const u16* __restrict__ B,
    u16* __restrict__ PKV, int K, int KH) {
  __shared__ u16 As[2][256 * 64];
  __shared__ u16 Bs[2][256 * 64];
  int tid = threadIdx.x, lane = tid & 63, wid = tid >> 6;
  int wr = wid >> 2, wc = wid & 3;
  int g = lane >> 4, q = lane & 15;
  int id = blockIdx.z * 64 + blockIdx.y * 8 + blockIdx.x;   // 256 blocks
  int swz = (id & 7) * 32 + (id >> 3);
  int z = swz >> 6, rem = swz & 63;
  int m0 = (rem >> 3) * 256, n0 = (rem & 7) * 256;
  int k0 = z * KH;
  f32x4 acc[8][4];
#pragma unroll
  for (int i = 0; i < 8; ++i)
#pragma unroll
    for (int j = 0; j < 4; ++j) acc[i][j] = (f32x4){0.f, 0.f, 0.f, 0.f};
  int srow = tid >> 3;
  int scol = ((tid & 7) ^ (srow & 7)) << 3;
  const u16* ga = A + (size_t)(m0 + srow) * K + k0 + scol;
  const u16* gb = B + (size_t)(n0 + srow) * K + k0 + scol;
  int xorm = (q & 7) << 3;
  int arow = wr * 128 + q;
  int brow = wc * 64 + q;
  int nt = KH >> 6;   // 16

  auto stage = [&](int buf, int t) {
    const u16* pa = ga + t * 64;
    const u16* pb = gb + t * 64;
#pragma unroll
    for (int it = 0; it < 4; ++it) {
      load_lds16(pa + (size_t)it * 64 * K, (char*)(&As[buf][0]) + it * 8192 + tid * 16);
      load_lds16(pb + (size_t)it * 64 * K, (char*)(&Bs[buf][0]) + it * 8192 + tid * 16);
    }
  };

  stage(0, 0);
  stage(1, 1);
  asm volatile("s_waitcnt vmcnt(8)" ::: "memory");
  __builtin_amdgcn_s_barrier();
  for (int t = 0; t < nt; ++t) {
    int cur = t & 1;
    int col0 = (g * 8) ^ xorm;
    short8 a0[8], b0[4];
#pragma unroll
    for (int m = 0; m < 8; ++m) a0[m] = *(const short8*)&As[cur][(arow + m * 16) * 64 + col0];
#pragma unroll
    for (int n = 0; n < 4; ++n) b0[n] = *(const short8*)&Bs[cur][(brow + n * 16) * 64 + col0];
    __builtin_amdgcn_s_setprio(1);
#pragma unroll
    for (int m = 0; m < 8; ++m)
#pragma unroll
      for (int n = 0; n < 4; ++n)
        acc[m][n] = __builtin_amdgcn_mfma_f32_16x16x32_bf16(a0[m], b0[n], acc[m][n], 0, 0, 0);
    __builtin_amdgcn_s_setprio(0);
    int col1 = (32 + g * 8) ^ xorm;
    short8 a1[8], b1[4];
#pragma unroll
    for (int m = 0; m < 8; ++m) a1[m] = *(const short8*)&As[cur][(arow + m * 16) * 64 + col1];
#pragma unroll
    for (int n = 0; n < 4; ++n) b1[n] = *(const short8*)&Bs[cur][(brow + n * 16) * 64 + col1];
    asm volatile("s_waitcnt lgkmcnt(0)" ::: "memory");
    __builtin_amdgcn_s_barrier();
    if (t + 2 < nt) stage(cur, t + 2);
    __builtin_amdgcn_sched_barrier(0);
    __builtin_amdgcn_s_setprio(1);
#pragma unroll
    for (int m = 0; m < 8; ++m)
#pragma unroll
      for (int n = 0; n < 4; ++n)
        acc[m][n] = __builtin_amdgcn_mfma_f32_16x16x32_bf16(a1[m], b1[n], acc[m][n], 0, 0, 0);
    __builtin_amdgcn_s_setprio(0);
    if (t + 2 < nt)      { asm volatile("s_waitcnt vmcnt(8)" ::: "memory"); }
    else if (t + 1 < nt) { asm volatile("s_waitcnt vmcnt(0)" ::: "memory"); }
    __builtin_amdgcn_s_barrier();
  }
  int crow = m0 + wr * 128 + g * 4;
  int ccol = n0 + wc * 64 + q;
  u16* Kpart = PKV + (size_t)z * 4194304;
  u16* Vpart = Kpart + 2097152;
  if (n0 < 1024) {
#pragma unroll
    for (int fm = 0; fm < 8; ++fm)
#pragma unroll
      for (int fn = 0; fn < 4; ++fn)
#pragma unroll
        for (int r = 0; r < 4; ++r)
          Kpart[(size_t)(crow + fm * 16 + r) * 1024 + ccol + fn * 16] = f2bf(acc[fm][fn][r]);
  } else {
#pragma unroll
    for (int fn = 0; fn < 4; ++fn) {
      int vcol = ccol + fn * 16 - 1024;
#pragma unroll
      for (int fm = 0; fm < 8; ++fm) {
        s16x4 o;
#pragma unroll
        for (int r = 0; r < 4; ++r) o[r] = (short)f2bf(acc[fm][fn][r]);
        *(s16x4*)(Vpart + (size_t)vcol * 2048 + crow + fm * 16) = o;
      }
    }
  }
}

// ---------------- flash attention + fused Q combine/RoPE (table), window 1024 -------------
// P exchange via wave-private LDS (4x ds_write_b64 + 2x ds_read_b128, swizzled)
// instead of 16 ds_bpermute shfls. LDS total 80KB -> 2 blocks/CU.
__global__ __launch_bounds__(512, 4) void attn_kernel(
    const u16* __restrict__ Q0, const u16* __restrict__ Q1,
    const u16* __restrict__ Kg, const u16* __restrict__ Vt,
    const float* __restrict__ Tab, u16* __restrict__ O) {
  __shared__ u16 Ks[2][64 * 128];
  __shared__ u16 Vs[2][128 * 64];
  __shared__ u16 Ps[8][16 * 64];
  int tid = threadIdx.x, lane = tid & 63, w = tid >> 6;
  int wg = w >> 2;
  int g = lane >> 4, q = lane & 15;
  int q0 = blockIdx.x * 128;
  int h = blockIdx.y, hk = h >> 2;
  int qbase = q0 + wg * 64;
  int qrow = qbase + (w & 3) * 16;
  int xorm = (lane & 7) << 3;       // == (q&7)<<3
  int bjt_lo = (q0 >= 1024) ? ((q0 - 1023) >> 6) : 0;
  int bjt_hi = (q0 + 64) >> 6;
  int wjt_lo = (qbase >= 1024) ? ((qbase - 1023) >> 6) : 0;
  int wjt_hi = qbase >> 6;
  int krow = tid >> 4;
  int kchunk = (tid & 15) ^ (krow & 7);
  const u16* kbase = Kg + (size_t)krow * 1024 + hk * 128 + (kchunk << 3);
  int vrow = tid >> 3;
  int vchunk = (tid & 7) ^ (vrow & 7);
  const u16* vbase = Vt + (size_t)(hk * 128 + vrow) * 2048 + (vchunk << 3);

  auto stageK = [&](int buf, int j0) {
    const u16* gp = kbase + (size_t)j0 * 1024;
#pragma unroll
    for (int it = 0; it < 2; ++it)
      load_lds16(gp + (size_t)it * 32 * 1024, (char*)(&Ks[buf][0]) + it * 8192 + tid * 16);
  };
  auto stageV = [&](int buf, int j0) {
    const u16* gp = vbase + j0;
#pragma unroll
    for (int it = 0; it < 2; ++it)
      load_lds16(gp + (size_t)it * 64 * 2048, (char*)(&Vs[buf][0]) + it * 8192 + tid * 16);
  };

  // issue first K/V stage, then do Q combine+rope under the load latency
  stageK(0, bjt_lo << 6);
  stageV(0, bjt_lo << 6);
  short8 qf[4];
  {
    size_t qoff = (size_t)(qrow + q) * 4096 + h * 128 + g * 8;
    float sum[4][8];
#pragma unroll
    for (int kk = 0; kk < 4; ++kk) {
      short8 a = *(const short8*)(Q0 + qoff + kk * 32);
      short8 b = *(const short8*)(Q1 + qoff + kk * 32);
#pragma unroll
      for (int i = 0; i < 8; ++i) sum[kk][i] = bf2f((u16)a[i]) + bf2f((u16)b[i]);
    }
    const float scale = 0.12751781828987514f;   // log2(e)/sqrt(128)
    const float* tr = Tab + (size_t)(qrow + q) * 128;
#pragma unroll
    for (int kk = 0; kk < 2; ++kk)
#pragma unroll
      for (int i = 0; i < 8; ++i) {
        int j = kk * 32 + g * 8 + i;
        float cs = tr[j * 2], sn = tr[j * 2 + 1];
        float lo = sum[kk][i], hi = sum[kk + 2][i];
        qf[kk][i]     = (short)f2bf((lo * cs - hi * sn) * scale);
        qf[kk + 2][i] = (short)f2bf((hi * cs + lo * sn) * scale);
      }
  }
  float mrow = -1e30f, lsum = 0.f;
  f32x4 of[8];
#pragma unroll
  for (int d = 0; d < 8; ++d) of[d] = (f32x4){0.f, 0.f, 0.f, 0.f};

  u16* pl = &Ps[w][(size_t)q * 64];   // wave-private P row buffer

  int cur = 0;
  asm volatile("s_waitcnt vmcnt(0)" ::: "memory");
  __syncthreads();
  for (int jt = bjt_lo; jt <= bjt_hi; ++jt) {
    int j0 = jt << 6;
    if (jt < bjt_hi) { stageK(cur ^ 1, j0 + 64); stageV(cur ^ 1, j0 + 64); }
    if (jt >= wjt_lo && jt <= wjt_hi) {
      f32x4 sf[4];
#pragma unroll
      for (int nt = 0; nt < 4; ++nt) sf[nt] = (f32x4){0.f, 0.f, 0.f, 0.f};
      const u16* ks = &Ks[cur][0];
      __builtin_amdgcn_s_setprio(1);
#pragma unroll
      for (int kk = 0; kk < 4; ++kk) {
        short8 qv = qf[kk];
        int col = (kk * 32 + g * 8) ^ xorm;
#pragma unroll
        for (int nt = 0; nt < 4; ++nt) {
          short8 kf = *(const short8*)&ks[(nt * 16 + q) * 128 + col];
          sf[nt] = __builtin_amdgcn_mfma_f32_16x16x32_bf16(kf, qv, sf[nt], 0, 0, 0);
        }
      }
      __builtin_amdgcn_s_setprio(0);
      float p[4][4];
#pragma unroll
      for (int nt = 0; nt < 4; ++nt)
#pragma unroll
        for (int r = 0; r < 4; ++r) p[nt][r] = sf[nt][r];
      if (j0 + 63 > qrow || j0 + 1009 <= qrow) {
        int qq = qrow + q;
        int kb = j0 + g * 4;
#pragma unroll
        for (int nt = 0; nt < 4; ++nt)
#pragma unroll
          for (int r = 0; r < 4; ++r) {
            int key = kb + nt * 16 + r;
            if (key > qq || key + 1024 <= qq) p[nt][r] = -1e9f;
          }
      }
      float tm = p[0][0];
#pragma unroll
      for (int nt = 0; nt < 4; ++nt)
#pragma unroll
        for (int r = 0; r < 4; ++r) tm = fmaxf(tm, p[nt][r]);
      tm = fmaxf(tm, __shfl_xor(tm, 16));
      tm = fmaxf(tm, __shfl_xor(tm, 32));
      if (__any(tm > mrow + 8.f)) {
        float nm = fmaxf(mrow, tm);
        float sc = __builtin_amdgcn_exp2f(mrow - nm);
        mrow = nm;
        lsum *= sc;
#pragma unroll
        for (int d = 0; d < 8; ++d) of[d] *= sc;
      }
      float ps = 0.f;
#pragma unroll
      for (int nt = 0; nt < 4; ++nt)
#pragma unroll
        for (int r = 0; r < 4; ++r) {
          float e = __builtin_amdgcn_exp2f(p[nt][r] - mrow);
          p[nt][r] = e;
          ps += e;
        }
      ps += __shfl_xor(ps, 16);
      ps += __shfl_xor(ps, 32);
      lsum += ps;
      // pack P (truncating bf16 pairs) and write to wave-private LDS (swizzled)
#pragma unroll
      for (int nt = 0; nt < 4; ++nt) {
        u32 u0 = __builtin_amdgcn_perm(__float_as_uint(p[nt][1]), __float_as_uint(p[nt][0]), 0x07060302u);
        u32 u1 = __builtin_amdgcn_perm(__float_as_uint(p[nt][3]), __float_as_uint(p[nt][2]), 0x07060302u);
        int col = (nt * 16 + g * 4) ^ xorm;
        union { u32 u[2]; double d; } wv;
        wv.u[0] = u0; wv.u[1] = u1;
        *(double*)&pl[col] = wv.d;
      }
      asm volatile("s_waitcnt lgkmcnt(0)" ::: "memory");
      // PV: read back P fragment (B-operand rows) + V fragments
      const u16* vs = &Vs[cur][0];
      __builtin_amdgcn_s_setprio(1);
#pragma unroll
      for (int kh = 0; kh < 2; ++kh) {
        short8 pb = *(const short8*)&pl[(kh * 32 + g * 8) ^ xorm];
        int col = (kh * 32 + g * 8) ^ xorm;
#pragma unroll
        for (int dt = 0; dt < 8; ++dt) {
          short8 vv = *(const short8*)&vs[(dt * 16 + q) * 64 + col];
          of[dt] = __builtin_amdgcn_mfma_f32_16x16x32_bf16(vv, pb, of[dt], 0, 0, 0);
        }
      }
      __builtin_amdgcn_s_setprio(0);
    }
    asm volatile("s_waitcnt vmcnt(0)" ::: "memory");
    __builtin_amdgcn_s_barrier();
    cur ^= 1;
  }
  float inv = 1.f / lsum;
  u16* op = O + (size_t)(qrow + q) * 4096 + h * 128 + g * 4;
#pragma unroll
  for (int dt = 0; dt < 8; ++dt) {
    s16x4 o4;
#pragma unroll
    for (int r = 0; r < 4; ++r) o4[r] = (short)f2bf(of[dt][r] * inv);
    *(s16x4*)(op + dt * 16) = o4;
  }
}

extern "C" void kernel_launch(void* const* d_in, const int* in_sizes, int n_in,
                              void* d_out, int out_size, void* d_ws, size_t ws_size,
                              hipStream_t stream) {
  (void)in_sizes; (void)n_in; (void)out_size;
  const float* hs = (const float*)d_in[0];
  const float* Wq = (const float*)d_in[3];
  const float* Wk = (const float*)d_in[4];
  const float* Wv = (const float*)d_in[5];
  const float* Wo = (const float*)d_in[6];
  float* out = (float*)d_out;
  char* ws = (char*)d_ws;

  u16* Xb   = (u16*)(ws + 0);          // 16 MB : X bf16; reused as attn output Ao
  u16* Wt   = (u16*)(ws + 16777216);   // 32 MB : WqT, then KV partial arena, then WoT
  u16* WkvT = (u16*)(ws + 50331648);   // 16 MB : [Wk^T;Wv^T]; later P0o
  u16* Qb   = (u16*)(ws + 67108864);   // 16 MB : Q-proj half-0 partial; later P1o
  u16* Kb   = (u16*)(ws + 83886080);   // 4 MB  : K (rope'd) [2048][1024]
  u16* Vtb  = (u16*)(ws + 88080384);   // 4 MB  : V^T [1024][2048]
  float* Tab = (float*)(ws + 92274688);// 1 MB  : RoPE cos/sin table [2048][64][2]
  u16* P1q  = (u16*)(ws + 96468992);   // 16 MB : Q-proj half-1 partial (read by attn)
  u16* PKV  = Wt;                      // KV split-K partial arena (WqT dead post-Q-proj)
  u16* P0o  = WkvT;                    // O-proj half-0 partial (WkvT dead post-KV-proj)
  u16* P1o  = Qb;                      // O-proj half-1 partial (Qb dead post-attn)
  u16* Ao   = Xb;                      // attn output (X dead post-KV-proj)
  if (ws_size < 113246208u) return;

  // fused prep: Wq/Wk/Wv transpose + X cvt + RoPE table
  prep_kernel<<<dim3(14848), 256, 0, stream>>>(Wq, Wk, Wv, Wt, WkvT, hs, Xb, Tab);

  // Q projection: 256^2 split-K=2, bf16 partials (combine+rope fused into attn)
  gemm256_kernel<<<dim3(16, 8, 2), 512, 0, stream>>>(Xb, Wt, Qb, P1q, 4096, 4096, 2048);

  // fused K+V projection: 256^2 split-K=4 into partial arena
  gemm_kv256_kernel<<<dim3(8, 8, 4), 512, 0, stream>>>(Xb, WkvT, PKV, 4096, 1024);
  // combine partials + K RoPE (table)
  combine_kv_rope_kernel<<<dim3(1536), 256, 0, stream>>>(PKV, Kb, Vtb, Tab);

  // attention (Q combine + RoPE + scale fused); output -> Ao (=Xb)
  attn_kernel<<<dim3(16, 32), 512, 0, stream>>>(Qb, P1q, Kb, Vtb, Tab, Ao);

  // output projection: transpose Wo, 256^2 split-K=2 (bf16 partials), combine to f32
  tconv1_kernel<<<dim3(4096), 256, 0, stream>>>(Wo, Wt);
  gemm256_kernel<<<dim3(16, 8, 2), 512, 0, stream>>>(Ao, Wt, P0o, P1o, 4096, 4096, 2048);
  combine2_f32_kernel<<<dim3(4096), 256, 0, stream>>>(out, P0o, P1o, 1048576);
}

// Round 21
// 285.120 us; speedup vs baseline: 1.1456x; 1.0323x over previous
//
#include <hip/hip_runtime.h>

typedef __attribute__((ext_vector_type(8))) short short8;
typedef __attribute__((ext_vector_type(4))) short s16x4;
typedef __attribute__((ext_vector_type(4))) float f32x4;
typedef unsigned short u16;
typedef unsigned int u32;

__device__ __forceinline__ u16 f2bf(float f) {
  union { float f; unsigned int u; } v; v.f = f;
  unsigned int r = (v.u + 0x7FFFu + ((v.u >> 16) & 1u)) >> 16;
  return (u16)r;
}
__device__ __forceinline__ float bf2f(u16 b) {
  union { unsigned int u; float f; } v; v.u = ((unsigned int)b) << 16;
  return v.f;
}
__device__ __forceinline__ void load_lds16(const void* g, void* l) {
  __builtin_amdgcn_global_load_lds((const __attribute__((address_space(1))) void*)g,
                                   (__attribute__((address_space(3))) void*)l, 16, 0, 0);
}

// ---------------- 64x64-tile fp32 [K][N] -> bf16 [N][K] transpose core (static LDS) -------
__device__ __forceinline__ void tconv64_tile(const float* __restrict__ W, u16* __restrict__ Wt,
                                             int K, int N, int nb, int kb, int tid) {
  __shared__ float tile[64][65];
  int tx = tid & 15, ty = tid >> 4;          // 16 x 16
  const float* src = W + (size_t)(kb + ty) * N + nb + tx * 4;
#pragma unroll
  for (int i = 0; i < 4; ++i) {
    float4 v = *(const float4*)(src + (size_t)i * 16 * N);
    tile[ty + i * 16][tx * 4 + 0] = v.x;
    tile[ty + i * 16][tx * 4 + 1] = v.y;
    tile[ty + i * 16][tx * 4 + 2] = v.z;
    tile[ty + i * 16][tx * 4 + 3] = v.w;
  }
  __syncthreads();
  u16* dst = Wt + (size_t)(nb + ty) * K + kb + tx * 4;
#pragma unroll
  for (int i = 0; i < 4; ++i) {
    s16x4 o;
#pragma unroll
    for (int j = 0; j < 4; ++j) o[j] = (short)f2bf(tile[tx * 4 + j][ty + i * 16]);
    *(s16x4*)(dst + (size_t)i * 16 * K) = o;
  }
}

// pointer-LDS variant (for merged attn+tconv kernel)
__device__ __forceinline__ void tconv64_tile_p(const float* __restrict__ W, u16* __restrict__ Wt,
                                               int K, int N, int nb, int kb, int tid,
                                               float* __restrict__ tile) {
  int tx = tid & 15, ty = tid >> 4;          // 16 x 16
  const float* src = W + (size_t)(kb + ty) * N + nb + tx * 4;
#pragma unroll
  for (int i = 0; i < 4; ++i) {
    float4 v = *(const float4*)(src + (size_t)i * 16 * N);
    tile[(ty + i * 16) * 65 + tx * 4 + 0] = v.x;
    tile[(ty + i * 16) * 65 + tx * 4 + 1] = v.y;
    tile[(ty + i * 16) * 65 + tx * 4 + 2] = v.z;
    tile[(ty + i * 16) * 65 + tx * 4 + 3] = v.w;
  }
  __syncthreads();
  u16* dst = Wt + (size_t)(nb + ty) * K + kb + tx * 4;
#pragma unroll
  for (int i = 0; i < 4; ++i) {
    s16x4 o;
#pragma unroll
    for (int j = 0; j < 4; ++j) o[j] = (short)f2bf(tile[(tx * 4 + j) * 65 + ty + i * 16]);
    *(s16x4*)(dst + (size_t)i * 16 * K) = o;
  }
}

// fused: Wq/Wk/Wv transpose-convert + X cvt f32->bf16 + RoPE cos/sin table
__global__ void prep_kernel(const float* __restrict__ Wq, const float* __restrict__ Wk,
                            const float* __restrict__ Wv, u16* __restrict__ WqT,
                            u16* __restrict__ WkvT, const float* __restrict__ X,
                            u16* __restrict__ Xb, float* __restrict__ Tab) {
  int id = blockIdx.x;
  int tid = threadIdx.x;
  if (id < 4096) { tconv64_tile(Wq, WqT, 4096, 4096, (id & 63) * 64, (id >> 6) * 64, tid); return; }
  if (id < 5120) { int t = id - 4096; tconv64_tile(Wk, WkvT, 4096, 1024, (t & 15) * 64, (t >> 4) * 64, tid); return; }
  if (id < 6144) { int t = id - 5120; tconv64_tile(Wv, WkvT + (size_t)1024 * 4096, 4096, 1024, (t & 15) * 64, (t >> 4) * 64, tid); return; }
  if (id < 14336) {
    int i = (id - 6144) * 256 + tid;             // float4 index, 2097152 total
    float4 v = ((const float4*)X)[i];
    ushort4 o;
    o.x = f2bf(v.x); o.y = f2bf(v.y); o.z = f2bf(v.z); o.w = f2bf(v.w);
    ((ushort4*)Xb)[i] = o;
    return;
  }
  {
    int i = (id - 14336) * 256 + tid;            // 0..131071 : (s, j)
    int s = i >> 6, j = i & 63;
    float invf = exp2f(-(float)j * (13.287712379549449f / 64.0f)); // 10000^(-j/64)
    float sn, cs;
    sincosf((float)s * invf, &sn, &cs);
    Tab[(size_t)s * 128 + j * 2]     = cs;
    Tab[(size_t)s * 128 + j * 2 + 1] = sn;
  }
}

// out_f32 = bf16(p0) + bf16(p1)
__global__ void combine2_f32_kernel(float* __restrict__ out, const u16* __restrict__ p0,
                                    const u16* __restrict__ p1, int n8) {
  int i = blockIdx.x * blockDim.x + threadIdx.x;
  if (i >= n8) return;
  short8 a = ((const short8*)p0)[i];
  short8 b = ((const short8*)p1)[i];
  float4 o0, o1;
  o0.x = bf2f((u16)a[0]) + bf2f((u16)b[0]);
  o0.y = bf2f((u16)a[1]) + bf2f((u16)b[1]);
  o0.z = bf2f((u16)a[2]) + bf2f((u16)b[2]);
  o0.w = bf2f((u16)a[3]) + bf2f((u16)b[3]);
  o1.x = bf2f((u16)a[4]) + bf2f((u16)b[4]);
  o1.y = bf2f((u16)a[5]) + bf2f((u16)b[5]);
  o1.z = bf2f((u16)a[6]) + bf2f((u16)b[6]);
  o1.w = bf2f((u16)a[7]) + bf2f((u16)b[7]);
  ((float4*)out)[i * 2]     = o0;
  ((float4*)out)[i * 2 + 1] = o1;
}

// sum 4 KV split-K partials; apply RoPE (table) to K; -> Kb, Vt
__global__ void combine_kv_rope_kernel(const u16* __restrict__ PKV, u16* __restrict__ Kb,
                                       u16* __restrict__ Vt, const float* __restrict__ Tab) {
  int i = blockIdx.x * blockDim.x + threadIdx.x;   // 0..393215
  if (i < 131072) {
    int s = i >> 6, r = i & 63, hh = r >> 3, c = r & 7;
    size_t lo8 = (size_t)s * 128 + hh * 16 + c;    // short8 index
    size_t hi8 = lo8 + 8;
    float lo[8] = {0,0,0,0,0,0,0,0}, hi[8] = {0,0,0,0,0,0,0,0};
#pragma unroll
    for (int z = 0; z < 4; ++z) {
      short8 a = *(const short8*)(PKV + (size_t)z * 4194304 + lo8 * 8);
      short8 b = *(const short8*)(PKV + (size_t)z * 4194304 + hi8 * 8);
#pragma unroll
      for (int j = 0; j < 8; ++j) { lo[j] += bf2f((u16)a[j]); hi[j] += bf2f((u16)b[j]); }
    }
    const float* tr = Tab + (size_t)s * 128 + c * 16;
    short8 olo, ohi;
#pragma unroll
    for (int ii = 0; ii < 8; ++ii) {
      float cs = tr[ii * 2], sn = tr[ii * 2 + 1];
      olo[ii] = (short)f2bf(lo[ii] * cs - hi[ii] * sn);
      ohi[ii] = (short)f2bf(hi[ii] * cs + lo[ii] * sn);
    }
    *(short8*)(Kb + lo8 * 8) = olo;
    *(short8*)(Kb + hi8 * 8) = ohi;
  } else {
    int v = i - 131072;                             // 0..262143
    const u16* src = PKV + 2097152;
    float sm[8] = {0,0,0,0,0,0,0,0};
#pragma unroll
    for (int z = 0; z < 4; ++z) {
      short8 a = *(const short8*)(src + (size_t)z * 4194304 + (size_t)v * 8);
#pragma unroll
      for (int j = 0; j < 8; ++j) sm[j] += bf2f((u16)a[j]);
    }
    short8 o;
#pragma unroll
    for (int j = 0; j < 8; ++j) o[j] = (short)f2bf(sm[j]);
    ((short8*)Vt)[v] = o;
  }
}

// ---------------- 256x256 split-K bf16 GEMM, fat per-wave tile (r15 verified) ----------------
__global__ __launch_bounds__(512, 1) void gemm256_kernel(
    const u16* __restrict__ A, const u16* __restrict__ B,
    u16* __restrict__ C0, u16* __restrict__ C1, int N, int K, int KH) {
  __shared__ u16 As[2][256 * 64];
  __shared__ u16 Bs[2][256 * 64];
  int tid = threadIdx.x, lane = tid & 63, wid = tid >> 6;
  int wr = wid >> 2, wc = wid & 3;
  int g = lane >> 4, q = lane & 15;
  int id = blockIdx.z * gridDim.x * gridDim.y + blockIdx.y * gridDim.x + blockIdx.x;
  int tot = gridDim.x * gridDim.y * gridDim.z;
  int swz = (id & 7) * (tot >> 3) + (id >> 3);
  int perh = gridDim.x * gridDim.y;
  int z = swz / perh, rem = swz % perh;
  int m0 = (rem / gridDim.x) * 256, n0 = (rem % gridDim.x) * 256;
  int k0 = z * KH;
  f32x4 acc[8][4];
#pragma unroll
  for (int i = 0; i < 8; ++i)
#pragma unroll
    for (int j = 0; j < 4; ++j) acc[i][j] = (f32x4){0.f, 0.f, 0.f, 0.f};
  int srow = tid >> 3;
  int scol = ((tid & 7) ^ (srow & 7)) << 3;
  const u16* ga = A + (size_t)(m0 + srow) * K + k0 + scol;
  const u16* gb = B + (size_t)(n0 + srow) * K + k0 + scol;
  int xorm = (q & 7) << 3;
  int arow = wr * 128 + q;
  int brow = wc * 64 + q;
  int nt = KH >> 6;

  auto stage = [&](int buf, int t) {
    const u16* pa = ga + t * 64;
    const u16* pb = gb + t * 64;
#pragma unroll
    for (int it = 0; it < 4; ++it) {
      load_lds16(pa + (size_t)it * 64 * K, (char*)(&As[buf][0]) + it * 8192 + tid * 16);
      load_lds16(pb + (size_t)it * 64 * K, (char*)(&Bs[buf][0]) + it * 8192 + tid * 16);
    }
  };

  stage(0, 0);
  stage(1, 1);
  asm volatile("s_waitcnt vmcnt(8)" ::: "memory");
  __builtin_amdgcn_s_barrier();
  for (int t = 0; t < nt; ++t) {
    int cur = t & 1;
    int col0 = (g * 8) ^ xorm;
    short8 a0[8], b0[4];
#pragma unroll
    for (int m = 0; m < 8; ++m) a0[m] = *(const short8*)&As[cur][(arow + m * 16) * 64 + col0];
#pragma unroll
    for (int n = 0; n < 4; ++n) b0[n] = *(const short8*)&Bs[cur][(brow + n * 16) * 64 + col0];
    __builtin_amdgcn_s_setprio(1);
#pragma unroll
    for (int m = 0; m < 8; ++m)
#pragma unroll
      for (int n = 0; n < 4; ++n)
        acc[m][n] = __builtin_amdgcn_mfma_f32_16x16x32_bf16(a0[m], b0[n], acc[m][n], 0, 0, 0);
    __builtin_amdgcn_s_setprio(0);
    int col1 = (32 + g * 8) ^ xorm;
    short8 a1[8], b1[4];
#pragma unroll
    for (int m = 0; m < 8; ++m) a1[m] = *(const short8*)&As[cur][(arow + m * 16) * 64 + col1];
#pragma unroll
    for (int n = 0; n < 4; ++n) b1[n] = *(const short8*)&Bs[cur][(brow + n * 16) * 64 + col1];
    asm volatile("s_waitcnt lgkmcnt(0)" ::: "memory");
    __builtin_amdgcn_s_barrier();
    if (t + 2 < nt) stage(cur, t + 2);
    __builtin_amdgcn_sched_barrier(0);
    __builtin_amdgcn_s_setprio(1);
#pragma unroll
    for (int m = 0; m < 8; ++m)
#pragma unroll
      for (int n = 0; n < 4; ++n)
        acc[m][n] = __builtin_amdgcn_mfma_f32_16x16x32_bf16(a1[m], b1[n], acc[m][n], 0, 0, 0);
    __builtin_amdgcn_s_setprio(0);
    if (t + 2 < nt)      { asm volatile("s_waitcnt vmcnt(8)" ::: "memory"); }
    else if (t + 1 < nt) { asm volatile("s_waitcnt vmcnt(0)" ::: "memory"); }
    __builtin_amdgcn_s_barrier();
  }
  int crow = m0 + wr * 128 + g * 4;
  int ccol = n0 + wc * 64 + q;
  u16* dst = z ? C1 : C0;
#pragma unroll
  for (int fm = 0; fm < 8; ++fm)
#pragma unroll
    for (int fn = 0; fn < 4; ++fn)
#pragma unroll
      for (int r = 0; r < 4; ++r)
        dst[(size_t)(crow + fm * 16 + r) * N + ccol + fn * 16] = f2bf(acc[fm][fn][r]);
}

// ---------------- KV-proj: same fat-tile body, grid (8,8,4) split-K=4 (r15 verified) -------
__global__ __launch_bounds__(512, 1) void gemm_kv256_kernel(
    const u16* __restrict__ A, const u16* __restrict__ B,
    u16* __restrict__ PKV, int K, int KH) {
  __shared__ u16 As[2][256 * 64];
  __shared__ u16 Bs[2][256 * 64];
  int tid = threadIdx.x, lane = tid & 63, wid = tid >> 6;
  int wr = wid >> 2, wc = wid & 3;
  int g = lane >> 4, q = lane & 15;
  int id = blockIdx.z * 64 + blockIdx.y * 8 + blockIdx.x;   // 256 blocks
  int swz = (id & 7) * 32 + (id >> 3);
  int z = swz >> 6, rem = swz & 63;
  int m0 = (rem >> 3) * 256, n0 = (rem & 7) * 256;
  int k0 = z * KH;
  f32x4 acc[8][4];
#pragma unroll
  for (int i = 0; i < 8; ++i)
#pragma unroll
    for (int j = 0; j < 4; ++j) acc[i][j] = (f32x4){0.f, 0.f, 0.f, 0.f};
  int srow = tid >> 3;
  int scol = ((tid & 7) ^ (srow & 7)) << 3;
  const u16* ga = A + (size_t)(m0 + srow) * K + k0 + scol;
  const u16* gb = B + (size_t)(n0 + srow) * K + k0 + scol;
  int xorm = (q & 7) << 3;
  int arow = wr * 128 + q;
  int brow = wc * 64 + q;
  int nt = KH >> 6;   // 16

  auto stage = [&](int buf, int t) {
    const u16* pa = ga + t * 64;
    const u16* pb = gb + t * 64;
#pragma unroll
    for (int it = 0; it < 4; ++it) {
      load_lds16(pa + (size_t)it * 64 * K, (char*)(&As[buf][0]) + it * 8192 + tid * 16);
      load_lds16(pb + (size_t)it * 64 * K, (char*)(&Bs[buf][0]) + it * 8192 + tid * 16);
    }
  };

  stage(0, 0);
  stage(1, 1);
  asm volatile("s_waitcnt vmcnt(8)" ::: "memory");
  __builtin_amdgcn_s_barrier();
  for (int t = 0; t < nt; ++t) {
    int cur = t & 1;
    int col0 = (g * 8) ^ xorm;
    short8 a0[8], b0[4];
#pragma unroll
    for (int m = 0; m < 8; ++m) a0[m] = *(const short8*)&As[cur][(arow + m * 16) * 64 + col0];
#pragma unroll
    for (int n = 0; n < 4; ++n) b0[n] = *(const short8*)&Bs[cur][(brow + n * 16) * 64 + col0];
    __builtin_amdgcn_s_setprio(1);
#pragma unroll
    for (int m = 0; m < 8; ++m)
#pragma unroll
      for (int n = 0; n < 4; ++n)
        acc[m][n] = __builtin_amdgcn_mfma_f32_16x16x32_bf16(a0[m], b0[n], acc[m][n], 0, 0, 0);
    __builtin_amdgcn_s_setprio(0);
    int col1 = (32 + g * 8) ^ xorm;
    short8 a1[8], b1[4];
#pragma unroll
    for (int m = 0; m < 8; ++m) a1[m] = *(const short8*)&As[cur][(arow + m * 16) * 64 + col1];
#pragma unroll
    for (int n = 0; n < 4; ++n) b1[n] = *(const short8*)&Bs[cur][(brow + n * 16) * 64 + col1];
    asm volatile("s_waitcnt lgkmcnt(0)" ::: "memory");
    __builtin_amdgcn_s_barrier();
    if (t + 2 < nt) stage(cur, t + 2);
    __builtin_amdgcn_sched_barrier(0);
    __builtin_amdgcn_s_setprio(1);
#pragma unroll
    for (int m = 0; m < 8; ++m)
#pragma unroll
      for (int n = 0; n < 4; ++n)
        acc[m][n] = __builtin_amdgcn_mfma_f32_16x16x32_bf16(a1[m], b1[n], acc[m][n], 0, 0, 0);
    __builtin_amdgcn_s_setprio(0);
    if (t + 2 < nt)      { asm volatile("s_waitcnt vmcnt(8)" ::: "memory"); }
    else if (t + 1 < nt) { asm volatile("s_waitcnt vmcnt(0)" ::: "memory"); }
    __builtin_amdgcn_s_barrier();
  }
  int crow = m0 + wr * 128 + g * 4;
  int ccol = n0 + wc * 64 + q;
  u16* Kpart = PKV + (size_t)z * 4194304;
  u16* Vpart = Kpart + 2097152;
  if (n0 < 1024) {
#pragma unroll
    for (int fm = 0; fm < 8; ++fm)
#pragma unroll
      for (int fn = 0; fn < 4; ++fn)
#pragma unroll
        for (int r = 0; r < 4; ++r)
          Kpart[(size_t)(crow + fm * 16 + r) * 1024 + ccol + fn * 16] = f2bf(acc[fm][fn][r]);
  } else {
#pragma unroll
    for (int fn = 0; fn < 4; ++fn) {
      int vcol = ccol + fn * 16 - 1024;
#pragma unroll
      for (int fm = 0; fm < 8; ++fm) {
        s16x4 o;
#pragma unroll
        for (int r = 0; r < 4; ++r) o[r] = (short)f2bf(acc[fm][fn][r]);
        *(s16x4*)(Vpart + (size_t)vcol * 2048 + crow + fm * 16) = o;
      }
    }
  }
}

// ---------------- merged: flash attention (blocks 0..511) + Wo transpose (512..2559) ------
// attn: fused Q combine/RoPE (table); P exchange via wave-private LDS; 80KB sbuf.
// tconv: 2x 64x64 tiles per block using the same sbuf (33KB of it).
__global__ __launch_bounds__(512, 4) void attn_tconv_kernel(
    const u16* __restrict__ Q0, const u16* __restrict__ Q1,
    const u16* __restrict__ Kg, const u16* __restrict__ Vt,
    const float* __restrict__ Tab, u16* __restrict__ O,
    const float* __restrict__ Wo, u16* __restrict__ WoT) {
  __shared__ char sbuf[81920];
  int tid = threadIdx.x;
  if (blockIdx.x >= 512) {
    // ---- Wo transpose: 2 tiles per block ----
    int t2 = (blockIdx.x - 512) * 2 + (tid >> 8);
    float* tile = (float*)(sbuf + (tid >> 8) * 16640);
    tconv64_tile_p(Wo, WoT, 4096, 4096, (t2 & 63) * 64, (t2 >> 6) * 64, tid & 255, tile);
    return;
  }
  u16 (*Ks)[8192] = (u16(*)[8192])sbuf;               // 2 x 16KB
  u16 (*Vs)[8192] = (u16(*)[8192])(sbuf + 32768);     // 2 x 16KB
  u16 (*Ps)[1024] = (u16(*)[1024])(sbuf + 65536);     // 8 x 2KB
  int lane = tid & 63, w = tid >> 6;
  int wg = w >> 2;
  int g = lane >> 4, q = lane & 15;
  int q0 = (blockIdx.x & 15) * 128;
  int h = blockIdx.x >> 4, hk = h >> 2;
  int qbase = q0 + wg * 64;
  int qrow = qbase + (w & 3) * 16;
  int xorm = (lane & 7) << 3;       // == (q&7)<<3
  int bjt_lo = (q0 >= 1024) ? ((q0 - 1023) >> 6) : 0;
  int bjt_hi = (q0 + 64) >> 6;
  int wjt_lo = (qbase >= 1024) ? ((qbase - 1023) >> 6) : 0;
  int wjt_hi = qbase >> 6;
  int krow = tid >> 4;
  int kchunk = (tid & 15) ^ (krow & 7);
  const u16* kbase = Kg + (size_t)krow * 1024 + hk * 128 + (kchunk << 3);
  int vrow = tid >> 3;
  int vchunk = (tid & 7) ^ (vrow & 7);
  const u16* vbase = Vt + (size_t)(hk * 128 + vrow) * 2048 + (vchunk << 3);

  auto stageK = [&](int buf, int j0) {
    const u16* gp = kbase + (size_t)j0 * 1024;
#pragma unroll
    for (int it = 0; it < 2; ++it)
      load_lds16(gp + (size_t)it * 32 * 1024, (char*)(&Ks[buf][0]) + it * 8192 + tid * 16);
  };
  auto stageV = [&](int buf, int j0) {
    const u16* gp = vbase + j0;
#pragma unroll
    for (int it = 0; it < 2; ++it)
      load_lds16(gp + (size_t)it * 64 * 2048, (char*)(&Vs[buf][0]) + it * 8192 + tid * 16);
  };

  // issue first K/V stage, then do Q combine+rope under the load latency
  stageK(0, bjt_lo << 6);
  stageV(0, bjt_lo << 6);
  short8 qf[4];
  {
    size_t qoff = (size_t)(qrow + q) * 4096 + h * 128 + g * 8;
    float sum[4][8];
#pragma unroll
    for (int kk = 0; kk < 4; ++kk) {
      short8 a = *(const short8*)(Q0 + qoff + kk * 32);
      short8 b = *(const short8*)(Q1 + qoff + kk * 32);
#pragma unroll
      for (int i = 0; i < 8; ++i) sum[kk][i] = bf2f((u16)a[i]) + bf2f((u16)b[i]);
    }
    const float scale = 0.12751781828987514f;   // log2(e)/sqrt(128)
    const float* tr = Tab + (size_t)(qrow + q) * 128;
#pragma unroll
    for (int kk = 0; kk < 2; ++kk)
#pragma unroll
      for (int i = 0; i < 8; ++i) {
        int j = kk * 32 + g * 8 + i;
        float cs = tr[j * 2], sn = tr[j * 2 + 1];
        float lo = sum[kk][i], hi = sum[kk + 2][i];
        qf[kk][i]     = (short)f2bf((lo * cs - hi * sn) * scale);
        qf[kk + 2][i] = (short)f2bf((hi * cs + lo * sn) * scale);
      }
  }
  float mrow = -1e30f, lsum = 0.f;
  f32x4 of[8];
#pragma unroll
  for (int d = 0; d < 8; ++d) of[d] = (f32x4){0.f, 0.f, 0.f, 0.f};

  u16* pl = &Ps[w][(size_t)q * 64];   // wave-private P row buffer

  int cur = 0;
  asm volatile("s_waitcnt vmcnt(0)" ::: "memory");
  __syncthreads();
  for (int jt = bjt_lo; jt <= bjt_hi; ++jt) {
    int j0 = jt << 6;
    if (jt < bjt_hi) { stageK(cur ^ 1, j0 + 64); stageV(cur ^ 1, j0 + 64); }
    if (jt >= wjt_lo && jt <= wjt_hi) {
      f32x4 sf[4];
#pragma unroll
      for (int nt = 0; nt < 4; ++nt) sf[nt] = (f32x4){0.f, 0.f, 0.f, 0.f};
      const u16* ks = &Ks[cur][0];
      __builtin_amdgcn_s_setprio(1);
#pragma unroll
      for (int kk = 0; kk < 4; ++kk) {
        short8 qv = qf[kk];
        int col = (kk * 32 + g * 8) ^ xorm;
#pragma unroll
        for (int nt = 0; nt < 4; ++nt) {
          short8 kf = *(const short8*)&ks[(nt * 16 + q) * 128 + col];
          sf[nt] = __builtin_amdgcn_mfma_f32_16x16x32_bf16(kf, qv, sf[nt], 0, 0, 0);
        }
      }
      __builtin_amdgcn_s_setprio(0);
      float p[4][4];
#pragma unroll
      for (int nt = 0; nt < 4; ++nt)
#pragma unroll
        for (int r = 0; r < 4; ++r) p[nt][r] = sf[nt][r];
      if (j0 + 63 > qrow || j0 + 1009 <= qrow) {
        int qq = qrow + q;
        int kb = j0 + g * 4;
#pragma unroll
        for (int nt = 0; nt < 4; ++nt)
#pragma unroll
          for (int r = 0; r < 4; ++r) {
            int key = kb + nt * 16 + r;
            if (key > qq || key + 1024 <= qq) p[nt][r] = -1e9f;
          }
      }
      float tm = p[0][0];
#pragma unroll
      for (int nt = 0; nt < 4; ++nt)
#pragma unroll
        for (int r = 0; r < 4; ++r) tm = fmaxf(tm, p[nt][r]);
      tm = fmaxf(tm, __shfl_xor(tm, 16));
      tm = fmaxf(tm, __shfl_xor(tm, 32));
      if (__any(tm > mrow + 8.f)) {
        float nm = fmaxf(mrow, tm);
        float sc = __builtin_amdgcn_exp2f(mrow - nm);
        mrow = nm;
        lsum *= sc;
#pragma unroll
        for (int d = 0; d < 8; ++d) of[d] *= sc;
      }
      float ps = 0.f;
#pragma unroll
      for (int nt = 0; nt < 4; ++nt)
#pragma unroll
        for (int r = 0; r < 4; ++r) {
          float e = __builtin_amdgcn_exp2f(p[nt][r] - mrow);
          p[nt][r] = e;
          ps += e;
        }
      ps += __shfl_xor(ps, 16);
      ps += __shfl_xor(ps, 32);
      lsum += ps;
      // pack P (truncating bf16 pairs) and write to wave-private LDS (swizzled)
#pragma unroll
      for (int nt = 0; nt < 4; ++nt) {
        u32 u0 = __builtin_amdgcn_perm(__float_as_uint(p[nt][1]), __float_as_uint(p[nt][0]), 0x07060302u);
        u32 u1 = __builtin_amdgcn_perm(__float_as_uint(p[nt][3]), __float_as_uint(p[nt][2]), 0x07060302u);
        int col = (nt * 16 + g * 4) ^ xorm;
        union { u32 u[2]; double d; } wv;
        wv.u[0] = u0; wv.u[1] = u1;
        *(double*)&pl[col] = wv.d;
      }
      asm volatile("s_waitcnt lgkmcnt(0)" ::: "memory");
      // PV: read back P fragment (B-operand rows) + V fragments
      const u16* vs = &Vs[cur][0];
      __builtin_amdgcn_s_setprio(1);
#pragma unroll
      for (int kh = 0; kh < 2; ++kh) {
        short8 pb = *(const short8*)&pl[(kh * 32 + g * 8) ^ xorm];
        int col = (kh * 32 + g * 8) ^ xorm;
#pragma unroll
        for (int dt = 0; dt < 8; ++dt) {
          short8 vv = *(const short8*)&vs[(dt * 16 + q) * 64 + col];
          of[dt] = __builtin_amdgcn_mfma_f32_16x16x32_bf16(vv, pb, of[dt], 0, 0, 0);
        }
      }
      __builtin_amdgcn_s_setprio(0);
    }
    asm volatile("s_waitcnt vmcnt(0)" ::: "memory");
    __builtin_amdgcn_s_barrier();
    cur ^= 1;
  }
  float inv = 1.f / lsum;
  u16* op = O + (size_t)(qrow + q) * 4096 + h * 128 + g * 4;
#pragma unroll
  for (int dt = 0; dt < 8; ++dt) {
    s16x4 o4;
#pragma unroll
    for (int r = 0; r < 4; ++r) o4[r] = (short)f2bf(of[dt][r] * inv);
    *(s16x4*)(op + dt * 16) = o4;
  }
}

extern "C" void kernel_launch(void* const* d_in, const int* in_sizes, int n_in,
                              void* d_out, int out_size, void* d_ws, size_t ws_size,
                              hipStream_t stream) {
  (void)in_sizes; (void)n_in; (void)out_size;
  const float* hs = (const float*)d_in[0];
  const float* Wq = (const float*)d_in[3];
  const float* Wk = (const float*)d_in[4];
  const float* Wv = (const float*)d_in[5];
  const float* Wo = (const float*)d_in[6];
  float* out = (float*)d_out;
  char* ws = (char*)d_ws;

  u16* Xb   = (u16*)(ws + 0);          // 16 MB : X bf16; reused as attn output Ao
  u16* Wt   = (u16*)(ws + 16777216);   // 32 MB : WqT, then KV partial arena, then WoT
  u16* WkvT = (u16*)(ws + 50331648);   // 16 MB : [Wk^T;Wv^T]; later P0o
  u16* Qb   = (u16*)(ws + 67108864);   // 16 MB : Q-proj half-0 partial; later P1o
  u16* Kb   = (u16*)(ws + 83886080);   // 4 MB  : K (rope'd) [2048][1024]
  u16* Vtb  = (u16*)(ws + 88080384);   // 4 MB  : V^T [1024][2048]
  float* Tab = (float*)(ws + 92274688);// 1 MB  : RoPE cos/sin table [2048][64][2]
  u16* P1q  = (u16*)(ws + 96468992);   // 16 MB : Q-proj half-1 partial (read by attn)
  u16* PKV  = Wt;                      // KV split-K partial arena (WqT dead post-Q-proj)
  u16* P0o  = WkvT;                    // O-proj half-0 partial (WkvT dead post-KV-proj)
  u16* P1o  = Qb;                      // O-proj half-1 partial (Qb dead post-attn)
  u16* Ao   = Xb;                      // attn output (X dead post-KV-proj)
  if (ws_size < 113246208u) return;

  // fused prep: Wq/Wk/Wv transpose + X cvt + RoPE table
  prep_kernel<<<dim3(14848), 256, 0, stream>>>(Wq, Wk, Wv, Wt, WkvT, hs, Xb, Tab);

  // Q projection: 256^2 split-K=2, bf16 partials (combine+rope fused into attn)
  gemm256_kernel<<<dim3(16, 8, 2), 512, 0, stream>>>(Xb, Wt, Qb, P1q, 4096, 4096, 2048);

  // fused K+V projection: 256^2 split-K=4 into partial arena
  gemm_kv256_kernel<<<dim3(8, 8, 4), 512, 0, stream>>>(Xb, WkvT, PKV, 4096, 1024);
  // combine partials + K RoPE (table)
  combine_kv_rope_kernel<<<dim3(1536), 256, 0, stream>>>(PKV, Kb, Vtb, Tab);

  // merged: attention (Q combine + RoPE fused) -> Ao, plus Wo transpose -> Wt
  attn_tconv_kernel<<<dim3(2560), 512, 0, stream>>>(Qb, P1q, Kb, Vtb, Tab, Ao, Wo, Wt);

  // output projection: 256^2 split-K=2 (bf16 partials), combine to f32
  gemm256_kernel<<<dim3(16, 8, 2), 512, 0, stream>>>(Ao, Wt, P0o, P1o, 4096, 4096, 2048);
  combine2_f32_kernel<<<dim3(4096), 256, 0, stream>>>(out, P0o, P1o, 1048576);
}

// Round 22
// 280.143 us; speedup vs baseline: 1.1659x; 1.0178x over previous
//
#include <hip/hip_runtime.h>

typedef __attribute__((ext_vector_type(8))) short short8;
typedef __attribute__((ext_vector_type(4))) short s16x4;
typedef __attribute__((ext_vector_type(4))) float f32x4;
typedef unsigned short u16;
typedef unsigned int u32;

__device__ __forceinline__ u16 f2bf(float f) {
  union { float f; unsigned int u; } v; v.f = f;
  unsigned int r = (v.u + 0x7FFFu + ((v.u >> 16) & 1u)) >> 16;
  return (u16)r;
}
__device__ __forceinline__ float bf2f(u16 b) {
  union { unsigned int u; float f; } v; v.u = ((unsigned int)b) << 16;
  return v.f;
}
__device__ __forceinline__ void load_lds16(const void* g, void* l) {
  __builtin_amdgcn_global_load_lds((const __attribute__((address_space(1))) void*)g,
                                   (__attribute__((address_space(3))) void*)l, 16, 0, 0);
}

// ---------------- 64x64-tile fp32 [K][N] -> bf16 [N][K] transpose core (static LDS) -------
__device__ __forceinline__ void tconv64_tile(const float* __restrict__ W, u16* __restrict__ Wt,
                                             int K, int N, int nb, int kb, int tid) {
  __shared__ float tile[64][65];
  int tx = tid & 15, ty = tid >> 4;          // 16 x 16
  const float* src = W + (size_t)(kb + ty) * N + nb + tx * 4;
#pragma unroll
  for (int i = 0; i < 4; ++i) {
    float4 v = *(const float4*)(src + (size_t)i * 16 * N);
    tile[ty + i * 16][tx * 4 + 0] = v.x;
    tile[ty + i * 16][tx * 4 + 1] = v.y;
    tile[ty + i * 16][tx * 4 + 2] = v.z;
    tile[ty + i * 16][tx * 4 + 3] = v.w;
  }
  __syncthreads();
  u16* dst = Wt + (size_t)(nb + ty) * K + kb + tx * 4;
#pragma unroll
  for (int i = 0; i < 4; ++i) {
    s16x4 o;
#pragma unroll
    for (int j = 0; j < 4; ++j) o[j] = (short)f2bf(tile[tx * 4 + j][ty + i * 16]);
    *(s16x4*)(dst + (size_t)i * 16 * K) = o;
  }
}

// pointer-LDS variant (for merged attn+tconv kernel)
__device__ __forceinline__ void tconv64_tile_p(const float* __restrict__ W, u16* __restrict__ Wt,
                                               int K, int N, int nb, int kb, int tid,
                                               float* __restrict__ tile) {
  int tx = tid & 15, ty = tid >> 4;          // 16 x 16
  const float* src = W + (size_t)(kb + ty) * N + nb + tx * 4;
#pragma unroll
  for (int i = 0; i < 4; ++i) {
    float4 v = *(const float4*)(src + (size_t)i * 16 * N);
    tile[(ty + i * 16) * 65 + tx * 4 + 0] = v.x;
    tile[(ty + i * 16) * 65 + tx * 4 + 1] = v.y;
    tile[(ty + i * 16) * 65 + tx * 4 + 2] = v.z;
    tile[(ty + i * 16) * 65 + tx * 4 + 3] = v.w;
  }
  __syncthreads();
  u16* dst = Wt + (size_t)(nb + ty) * K + kb + tx * 4;
#pragma unroll
  for (int i = 0; i < 4; ++i) {
    s16x4 o;
#pragma unroll
    for (int j = 0; j < 4; ++j) o[j] = (short)f2bf(tile[(tx * 4 + j) * 65 + ty + i * 16]);
    *(s16x4*)(dst + (size_t)i * 16 * K) = o;
  }
}

// fused: Wq/Wk/Wv transpose-convert + X cvt f32->bf16 + RoPE cos/sin table
__global__ void prep_kernel(const float* __restrict__ Wq, const float* __restrict__ Wk,
                            const float* __restrict__ Wv, u16* __restrict__ WqT,
                            u16* __restrict__ WkvT, const float* __restrict__ X,
                            u16* __restrict__ Xb, float* __restrict__ Tab) {
  int id = blockIdx.x;
  int tid = threadIdx.x;
  if (id < 4096) { tconv64_tile(Wq, WqT, 4096, 4096, (id & 63) * 64, (id >> 6) * 64, tid); return; }
  if (id < 5120) { int t = id - 4096; tconv64_tile(Wk, WkvT, 4096, 1024, (t & 15) * 64, (t >> 4) * 64, tid); return; }
  if (id < 6144) { int t = id - 5120; tconv64_tile(Wv, WkvT + (size_t)1024 * 4096, 4096, 1024, (t & 15) * 64, (t >> 4) * 64, tid); return; }
  if (id < 14336) {
    int i = (id - 6144) * 256 + tid;             // float4 index, 2097152 total
    float4 v = ((const float4*)X)[i];
    ushort4 o;
    o.x = f2bf(v.x); o.y = f2bf(v.y); o.z = f2bf(v.z); o.w = f2bf(v.w);
    ((ushort4*)Xb)[i] = o;
    return;
  }
  {
    int i = (id - 14336) * 256 + tid;            // 0..131071 : (s, j)
    int s = i >> 6, j = i & 63;
    float invf = exp2f(-(float)j * (13.287712379549449f / 64.0f)); // 10000^(-j/64)
    float sn, cs;
    sincosf((float)s * invf, &sn, &cs);
    Tab[(size_t)s * 128 + j * 2]     = cs;
    Tab[(size_t)s * 128 + j * 2 + 1] = sn;
  }
}

// out_f32 = bf16(p0) + bf16(p1)
__global__ void combine2_f32_kernel(float* __restrict__ out, const u16* __restrict__ p0,
                                    const u16* __restrict__ p1, int n8) {
  int i = blockIdx.x * blockDim.x + threadIdx.x;
  if (i >= n8) return;
  short8 a = ((const short8*)p0)[i];
  short8 b = ((const short8*)p1)[i];
  float4 o0, o1;
  o0.x = bf2f((u16)a[0]) + bf2f((u16)b[0]);
  o0.y = bf2f((u16)a[1]) + bf2f((u16)b[1]);
  o0.z = bf2f((u16)a[2]) + bf2f((u16)b[2]);
  o0.w = bf2f((u16)a[3]) + bf2f((u16)b[3]);
  o1.x = bf2f((u16)a[4]) + bf2f((u16)b[4]);
  o1.y = bf2f((u16)a[5]) + bf2f((u16)b[5]);
  o1.z = bf2f((u16)a[6]) + bf2f((u16)b[6]);
  o1.w = bf2f((u16)a[7]) + bf2f((u16)b[7]);
  ((float4*)out)[i * 2]     = o0;
  ((float4*)out)[i * 2 + 1] = o1;
}

// sum 4 KV split-K partials; apply RoPE (table) to K; -> Kb, Vt
__global__ void combine_kv_rope_kernel(const u16* __restrict__ PKV, u16* __restrict__ Kb,
                                       u16* __restrict__ Vt, const float* __restrict__ Tab) {
  int i = blockIdx.x * blockDim.x + threadIdx.x;   // 0..393215
  if (i < 131072) {
    int s = i >> 6, r = i & 63, hh = r >> 3, c = r & 7;
    size_t lo8 = (size_t)s * 128 + hh * 16 + c;    // short8 index
    size_t hi8 = lo8 + 8;
    float lo[8] = {0,0,0,0,0,0,0,0}, hi[8] = {0,0,0,0,0,0,0,0};
#pragma unroll
    for (int z = 0; z < 4; ++z) {
      short8 a = *(const short8*)(PKV + (size_t)z * 4194304 + lo8 * 8);
      short8 b = *(const short8*)(PKV + (size_t)z * 4194304 + hi8 * 8);
#pragma unroll
      for (int j = 0; j < 8; ++j) { lo[j] += bf2f((u16)a[j]); hi[j] += bf2f((u16)b[j]); }
    }
    const float* tr = Tab + (size_t)s * 128 + c * 16;
    short8 olo, ohi;
#pragma unroll
    for (int ii = 0; ii < 8; ++ii) {
      float cs = tr[ii * 2], sn = tr[ii * 2 + 1];
      olo[ii] = (short)f2bf(lo[ii] * cs - hi[ii] * sn);
      ohi[ii] = (short)f2bf(hi[ii] * cs + lo[ii] * sn);
    }
    *(short8*)(Kb + lo8 * 8) = olo;
    *(short8*)(Kb + hi8 * 8) = ohi;
  } else {
    int v = i - 131072;                             // 0..262143
    const u16* src = PKV + 2097152;
    float sm[8] = {0,0,0,0,0,0,0,0};
#pragma unroll
    for (int z = 0; z < 4; ++z) {
      short8 a = *(const short8*)(src + (size_t)z * 4194304 + (size_t)v * 8);
#pragma unroll
      for (int j = 0; j < 8; ++j) sm[j] += bf2f((u16)a[j]);
    }
    short8 o;
#pragma unroll
    for (int j = 0; j < 8; ++j) o[j] = (short)f2bf(sm[j]);
    ((short8*)Vt)[v] = o;
  }
}

// ---------------- 256x256 split-K bf16 GEMM, fat per-wave tile (r15 verified) ----------------
__global__ __launch_bounds__(512, 1) void gemm256_kernel(
    const u16* __restrict__ A, const u16* __restrict__ B,
    u16* __restrict__ C0, u16* __restrict__ C1, int N, int K, int KH) {
  __shared__ u16 As[2][256 * 64];
  __shared__ u16 Bs[2][256 * 64];
  int tid = threadIdx.x, lane = tid & 63, wid = tid >> 6;
  int wr = wid >> 2, wc = wid & 3;
  int g = lane >> 4, q = lane & 15;
  int id = blockIdx.z * gridDim.x * gridDim.y + blockIdx.y * gridDim.x + blockIdx.x;
  int tot = gridDim.x * gridDim.y * gridDim.z;
  int swz = (id & 7) * (tot >> 3) + (id >> 3);
  int perh = gridDim.x * gridDim.y;
  int z = swz / perh, rem = swz % perh;
  int m0 = (rem / gridDim.x) * 256, n0 = (rem % gridDim.x) * 256;
  int k0 = z * KH;
  f32x4 acc[8][4];
#pragma unroll
  for (int i = 0; i < 8; ++i)
#pragma unroll
    for (int j = 0; j < 4; ++j) acc[i][j] = (f32x4){0.f, 0.f, 0.f, 0.f};
  int srow = tid >> 3;
  int scol = ((tid & 7) ^ (srow & 7)) << 3;
  const u16* ga = A + (size_t)(m0 + srow) * K + k0 + scol;
  const u16* gb = B + (size_t)(n0 + srow) * K + k0 + scol;
  int xorm = (q & 7) << 3;
  int arow = wr * 128 + q;
  int brow = wc * 64 + q;
  int nt = KH >> 6;

  auto stage = [&](int buf, int t) {
    const u16* pa = ga + t * 64;
    const u16* pb = gb + t * 64;
#pragma unroll
    for (int it = 0; it < 4; ++it) {
      load_lds16(pa + (size_t)it * 64 * K, (char*)(&As[buf][0]) + it * 8192 + tid * 16);
      load_lds16(pb + (size_t)it * 64 * K, (char*)(&Bs[buf][0]) + it * 8192 + tid * 16);
    }
  };

  stage(0, 0);
  stage(1, 1);
  asm volatile("s_waitcnt vmcnt(8)" ::: "memory");
  __builtin_amdgcn_s_barrier();
  for (int t = 0; t < nt; ++t) {
    int cur = t & 1;
    int col0 = (g * 8) ^ xorm;
    short8 a0[8], b0[4];
#pragma unroll
    for (int m = 0; m < 8; ++m) a0[m] = *(const short8*)&As[cur][(arow + m * 16) * 64 + col0];
#pragma unroll
    for (int n = 0; n < 4; ++n) b0[n] = *(const short8*)&Bs[cur][(brow + n * 16) * 64 + col0];
    __builtin_amdgcn_s_setprio(1);
#pragma unroll
    for (int m = 0; m < 8; ++m)
#pragma unroll
      for (int n = 0; n < 4; ++n)
        acc[m][n] = __builtin_amdgcn_mfma_f32_16x16x32_bf16(a0[m], b0[n], acc[m][n], 0, 0, 0);
    __builtin_amdgcn_s_setprio(0);
    int col1 = (32 + g * 8) ^ xorm;
    short8 a1[8], b1[4];
#pragma unroll
    for (int m = 0; m < 8; ++m) a1[m] = *(const short8*)&As[cur][(arow + m * 16) * 64 + col1];
#pragma unroll
    for (int n = 0; n < 4; ++n) b1[n] = *(const short8*)&Bs[cur][(brow + n * 16) * 64 + col1];
    asm volatile("s_waitcnt lgkmcnt(0)" ::: "memory");
    __builtin_amdgcn_s_barrier();
    if (t + 2 < nt) stage(cur, t + 2);
    __builtin_amdgcn_sched_barrier(0);
    __builtin_amdgcn_s_setprio(1);
#pragma unroll
    for (int m = 0; m < 8; ++m)
#pragma unroll
      for (int n = 0; n < 4; ++n)
        acc[m][n] = __builtin_amdgcn_mfma_f32_16x16x32_bf16(a1[m], b1[n], acc[m][n], 0, 0, 0);
    __builtin_amdgcn_s_setprio(0);
    if (t + 2 < nt)      { asm volatile("s_waitcnt vmcnt(8)" ::: "memory"); }
    else if (t + 1 < nt) { asm volatile("s_waitcnt vmcnt(0)" ::: "memory"); }
    __builtin_amdgcn_s_barrier();
  }
  int crow = m0 + wr * 128 + g * 4;
  int ccol = n0 + wc * 64 + q;
  u16* dst = z ? C1 : C0;
#pragma unroll
  for (int fm = 0; fm < 8; ++fm)
#pragma unroll
    for (int fn = 0; fn < 4; ++fn)
#pragma unroll
      for (int r = 0; r < 4; ++r)
        dst[(size_t)(crow + fm * 16 + r) * N + ccol + fn * 16] = f2bf(acc[fm][fn][r]);
}

// ---------------- KV-proj: same fat-tile body, grid (8,8,4) split-K=4 (r15 verified) -------
__global__ __launch_bounds__(512, 1) void gemm_kv256_kernel(
    const u16* __restrict__ A, const u16* __restrict__ B,
    u16* __restrict__ PKV, int K, int KH) {
  __shared__ u16 As[2][256 * 64];
  __shared__ u16 Bs[2][256 * 64];
  int tid = threadIdx.x, lane = tid & 63, wid = tid >> 6;
  int wr = wid >> 2, wc = wid & 3;
  int g = lane >> 4, q = lane & 15;
  int id = blockIdx.z * 64 + blockIdx.y * 8 + blockIdx.x;   // 256 blocks
  int swz = (id & 7) * 32 + (id >> 3);
  int z = swz >> 6, rem = swz & 63;
  int m0 = (rem >> 3) * 256, n0 = (rem & 7) * 256;
  int k0 = z * KH;
  f32x4 acc[8][4];
#pragma unroll
  for (int i = 0; i < 8; ++i)
#pragma unroll
    for (int j = 0; j < 4; ++j) acc[i][j] = (f32x4){0.f, 0.f, 0.f, 0.f};
  int srow = tid >> 3;
  int scol = ((tid & 7) ^ (srow & 7)) << 3;
  const u16* ga = A + (size_t)(m0 + srow) * K + k0 + scol;
  const u16* gb = B + (size_t)(n0 + srow) * K + k0 + scol;
  int xorm = (q & 7) << 3;
  int arow = wr * 128 + q;
  int brow = wc * 64 + q;
  int nt = KH >> 6;   // 16

  auto stage = [&](int buf, int t) {
    const u16* pa = ga + t * 64;
    const u16* pb = gb + t * 64;
#pragma unroll
    for (int it = 0; it < 4; ++it) {
      load_lds16(pa + (size_t)it * 64 * K, (char*)(&As[buf][0]) + it * 8192 + tid * 16);
      load_lds16(pb + (size_t)it * 64 * K, (char*)(&Bs[buf][0]) + it * 8192 + tid * 16);
    }
  };

  stage(0, 0);
  stage(1, 1);
  asm volatile("s_waitcnt vmcnt(8)" ::: "memory");
  __builtin_amdgcn_s_barrier();
  for (int t = 0; t < nt; ++t) {
    int cur = t & 1;
    int col0 = (g * 8) ^ xorm;
    short8 a0[8], b0[4];
#pragma unroll
    for (int m = 0; m < 8; ++m) a0[m] = *(const short8*)&As[cur][(arow + m * 16) * 64 + col0];
#pragma unroll
    for (int n = 0; n < 4; ++n) b0[n] = *(const short8*)&Bs[cur][(brow + n * 16) * 64 + col0];
    __builtin_amdgcn_s_setprio(1);
#pragma unroll
    for (int m = 0; m < 8; ++m)
#pragma unroll
      for (int n = 0; n < 4; ++n)
        acc[m][n] = __builtin_amdgcn_mfma_f32_16x16x32_bf16(a0[m], b0[n], acc[m][n], 0, 0, 0);
    __builtin_amdgcn_s_setprio(0);
    int col1 = (32 + g * 8) ^ xorm;
    short8 a1[8], b1[4];
#pragma unroll
    for (int m = 0; m < 8; ++m) a1[m] = *(const short8*)&As[cur][(arow + m * 16) * 64 + col1];
#pragma unroll
    for (int n = 0; n < 4; ++n) b1[n] = *(const short8*)&Bs[cur][(brow + n * 16) * 64 + col1];
    asm volatile("s_waitcnt lgkmcnt(0)" ::: "memory");
    __builtin_amdgcn_s_barrier();
    if (t + 2 < nt) stage(cur, t + 2);
    __builtin_amdgcn_sched_barrier(0);
    __builtin_amdgcn_s_setprio(1);
#pragma unroll
    for (int m = 0; m < 8; ++m)
#pragma unroll
      for (int n = 0; n < 4; ++n)
        acc[m][n] = __builtin_amdgcn_mfma_f32_16x16x32_bf16(a1[m], b1[n], acc[m][n], 0, 0, 0);
    __builtin_amdgcn_s_setprio(0);
    if (t + 2 < nt)      { asm volatile("s_waitcnt vmcnt(8)" ::: "memory"); }
    else if (t + 1 < nt) { asm volatile("s_waitcnt vmcnt(0)" ::: "memory"); }
    __builtin_amdgcn_s_barrier();
  }
  int crow = m0 + wr * 128 + g * 4;
  int ccol = n0 + wc * 64 + q;
  u16* Kpart = PKV + (size_t)z * 4194304;
  u16* Vpart = Kpart + 2097152;
  if (n0 < 1024) {
#pragma unroll
    for (int fm = 0; fm < 8; ++fm)
#pragma unroll
      for (int fn = 0; fn < 4; ++fn)
#pragma unroll
        for (int r = 0; r < 4; ++r)
          Kpart[(size_t)(crow + fm * 16 + r) * 1024 + ccol + fn * 16] = f2bf(acc[fm][fn][r]);
  } else {
#pragma unroll
    for (int fn = 0; fn < 4; ++fn) {
      int vcol = ccol + fn * 16 - 1024;
#pragma unroll
      for (int fm = 0; fm < 8; ++fm) {
        s16x4 o;
#pragma unroll
        for (int r = 0; r < 4; ++r) o[r] = (short)f2bf(acc[fm][fn][r]);
        *(s16x4*)(Vpart + (size_t)vcol * 2048 + crow + fm * 16) = o;
      }
    }
  }
}

// ---------------- merged: flash attention (blocks 0..511) + Wo transpose (512..2559) ------
// attn: fused Q combine/RoPE (table); P exchange via wave-private LDS; 80KB sbuf.
// q-block index mirrored for heads>=16 so co-resident blocks pair heavy+light work.
__global__ __launch_bounds__(512, 4) void attn_tconv_kernel(
    const u16* __restrict__ Q0, const u16* __restrict__ Q1,
    const u16* __restrict__ Kg, const u16* __restrict__ Vt,
    const float* __restrict__ Tab, u16* __restrict__ O,
    const float* __restrict__ Wo, u16* __restrict__ WoT) {
  __shared__ char sbuf[81920];
  int tid = threadIdx.x;
  if (blockIdx.x >= 512) {
    // ---- Wo transpose: 2 tiles per block ----
    int t2 = (blockIdx.x - 512) * 2 + (tid >> 8);
    float* tile = (float*)(sbuf + (tid >> 8) * 16640);
    tconv64_tile_p(Wo, WoT, 4096, 4096, (t2 & 63) * 64, (t2 >> 6) * 64, tid & 255, tile);
    return;
  }
  u16 (*Ks)[8192] = (u16(*)[8192])sbuf;               // 2 x 16KB
  u16 (*Vs)[8192] = (u16(*)[8192])(sbuf + 32768);     // 2 x 16KB
  u16 (*Ps)[1024] = (u16(*)[1024])(sbuf + 65536);     // 8 x 2KB
  int lane = tid & 63, w = tid >> 6;
  int wg = w >> 2;
  int g = lane >> 4, q = lane & 15;
  int h = blockIdx.x >> 4, hk = h >> 2;
  int bi = blockIdx.x & 15;
  if (h >= 16) bi = 15 - bi;          // pair heavy+light blocks on the same CU
  int q0 = bi * 128;
  int qbase = q0 + wg * 64;
  int qrow = qbase + (w & 3) * 16;
  int xorm = (lane & 7) << 3;         // == (q&7)<<3
  int bjt_lo = (q0 >= 1024) ? ((q0 - 1023) >> 6) : 0;
  int bjt_hi = (q0 + 64) >> 6;
  int wjt_lo = (qbase >= 1024) ? ((qbase - 1023) >> 6) : 0;
  int wjt_hi = qbase >> 6;
  int krow = tid >> 4;
  int kchunk = (tid & 15) ^ (krow & 7);
  const u16* kbase = Kg + (size_t)krow * 1024 + hk * 128 + (kchunk << 3);
  int vrow = tid >> 3;
  int vchunk = (tid & 7) ^ (vrow & 7);
  const u16* vbase = Vt + (size_t)(hk * 128 + vrow) * 2048 + (vchunk << 3);

  auto stageK = [&](int buf, int j0) {
    const u16* gp = kbase + (size_t)j0 * 1024;
#pragma unroll
    for (int it = 0; it < 2; ++it)
      load_lds16(gp + (size_t)it * 32 * 1024, (char*)(&Ks[buf][0]) + it * 8192 + tid * 16);
  };
  auto stageV = [&](int buf, int j0) {
    const u16* gp = vbase + j0;
#pragma unroll
    for (int it = 0; it < 2; ++it)
      load_lds16(gp + (size_t)it * 64 * 2048, (char*)(&Vs[buf][0]) + it * 8192 + tid * 16);
  };

  // issue first K/V stage, then do Q combine+rope under the load latency
  stageK(0, bjt_lo << 6);
  stageV(0, bjt_lo << 6);
  short8 qf[4];
  {
    size_t qoff = (size_t)(qrow + q) * 4096 + h * 128 + g * 8;
    float sum[4][8];
#pragma unroll
    for (int kk = 0; kk < 4; ++kk) {
      short8 a = *(const short8*)(Q0 + qoff + kk * 32);
      short8 b = *(const short8*)(Q1 + qoff + kk * 32);
#pragma unroll
      for (int i = 0; i < 8; ++i) sum[kk][i] = bf2f((u16)a[i]) + bf2f((u16)b[i]);
    }
    const float scale = 0.12751781828987514f;   // log2(e)/sqrt(128)
    const float* tr = Tab + (size_t)(qrow + q) * 128;
#pragma unroll
    for (int kk = 0; kk < 2; ++kk)
#pragma unroll
      for (int i = 0; i < 8; ++i) {
        int j = kk * 32 + g * 8 + i;
        float cs = tr[j * 2], sn = tr[j * 2 + 1];
        float lo = sum[kk][i], hi = sum[kk + 2][i];
        qf[kk][i]     = (short)f2bf((lo * cs - hi * sn) * scale);
        qf[kk + 2][i] = (short)f2bf((hi * cs + lo * sn) * scale);
      }
  }
  float mrow = -1e30f, lsum = 0.f;
  f32x4 of[8];
#pragma unroll
  for (int d = 0; d < 8; ++d) of[d] = (f32x4){0.f, 0.f, 0.f, 0.f};

  u16* pl = &Ps[w][(size_t)q * 64];   // wave-private P row buffer

  int cur = 0;
  asm volatile("s_waitcnt vmcnt(0)" ::: "memory");
  __syncthreads();
  for (int jt = bjt_lo; jt <= bjt_hi; ++jt) {
    int j0 = jt << 6;
    if (jt < bjt_hi) { stageK(cur ^ 1, j0 + 64); stageV(cur ^ 1, j0 + 64); }
    if (jt >= wjt_lo && jt <= wjt_hi) {
      f32x4 sf[4];
#pragma unroll
      for (int nt = 0; nt < 4; ++nt) sf[nt] = (f32x4){0.f, 0.f, 0.f, 0.f};
      const u16* ks = &Ks[cur][0];
      __builtin_amdgcn_s_setprio(1);
#pragma unroll
      for (int kk = 0; kk < 4; ++kk) {
        short8 qv = qf[kk];
        int col = (kk * 32 + g * 8) ^ xorm;
#pragma unroll
        for (int nt = 0; nt < 4; ++nt) {
          short8 kf = *(const short8*)&ks[(nt * 16 + q) * 128 + col];
          sf[nt] = __builtin_amdgcn_mfma_f32_16x16x32_bf16(kf, qv, sf[nt], 0, 0, 0);
        }
      }
      __builtin_amdgcn_s_setprio(0);
      float p[4][4];
#pragma unroll
      for (int nt = 0; nt < 4; ++nt)
#pragma unroll
        for (int r = 0; r < 4; ++r) p[nt][r] = sf[nt][r];
      if (j0 + 63 > qrow || j0 + 1009 <= qrow) {
        int qq = qrow + q;
        int kb = j0 + g * 4;
#pragma unroll
        for (int nt = 0; nt < 4; ++nt)
#pragma unroll
          for (int r = 0; r < 4; ++r) {
            int key = kb + nt * 16 + r;
            if (key > qq || key + 1024 <= qq) p[nt][r] = -1e9f;
          }
      }
      float tm = p[0][0];
#pragma unroll
      for (int nt = 0; nt < 4; ++nt)
#pragma unroll
        for (int r = 0; r < 4; ++r) tm = fmaxf(tm, p[nt][r]);
      tm = fmaxf(tm, __shfl_xor(tm, 16));
      tm = fmaxf(tm, __shfl_xor(tm, 32));
      if (__any(tm > mrow + 8.f)) {
        float nm = fmaxf(mrow, tm);
        float sc = __builtin_amdgcn_exp2f(mrow - nm);
        mrow = nm;
        lsum *= sc;
#pragma unroll
        for (int d = 0; d < 8; ++d) of[d] *= sc;
      }
      float ps = 0.f;
#pragma unroll
      for (int nt = 0; nt < 4; ++nt)
#pragma unroll
        for (int r = 0; r < 4; ++r) {
          float e = __builtin_amdgcn_exp2f(p[nt][r] - mrow);
          p[nt][r] = e;
          ps += e;
        }
      ps += __shfl_xor(ps, 16);
      ps += __shfl_xor(ps, 32);
      lsum += ps;
      // pack P (truncating bf16 pairs) and write to wave-private LDS (swizzled)
#pragma unroll
      for (int nt = 0; nt < 4; ++nt) {
        u32 u0 = __builtin_amdgcn_perm(__float_as_uint(p[nt][1]), __float_as_uint(p[nt][0]), 0x07060302u);
        u32 u1 = __builtin_amdgcn_perm(__float_as_uint(p[nt][3]), __float_as_uint(p[nt][2]), 0x07060302u);
        int col = (nt * 16 + g * 4) ^ xorm;
        union { u32 u[2]; double d; } wv;
        wv.u[0] = u0; wv.u[1] = u1;
        *(double*)&pl[col] = wv.d;
      }
      asm volatile("s_waitcnt lgkmcnt(0)" ::: "memory");
      // PV: read back P fragment (B-operand rows) + V fragments
      const u16* vs = &Vs[cur][0];
      __builtin_amdgcn_s_setprio(1);
#pragma unroll
      for (int kh = 0; kh < 2; ++kh) {
        short8 pb = *(const short8*)&pl[(kh * 32 + g * 8) ^ xorm];
        int col = (kh * 32 + g * 8) ^ xorm;
#pragma unroll
        for (int dt = 0; dt < 8; ++dt) {
          short8 vv = *(const short8*)&vs[(dt * 16 + q) * 64 + col];
          of[dt] = __builtin_amdgcn_mfma_f32_16x16x32_bf16(vv, pb, of[dt], 0, 0, 0);
        }
      }
      __builtin_amdgcn_s_setprio(0);
    }
    asm volatile("s_waitcnt vmcnt(0)" ::: "memory");
    __builtin_amdgcn_s_barrier();
    cur ^= 1;
  }
  float inv = 1.f / lsum;
  u16* op = O + (size_t)(qrow + q) * 4096 + h * 128 + g * 4;
#pragma unroll
  for (int dt = 0; dt < 8; ++dt) {
    s16x4 o4;
#pragma unroll
    for (int r = 0; r < 4; ++r) o4[r] = (short)f2bf(of[dt][r] * inv);
    *(s16x4*)(op + dt * 16) = o4;
  }
}

extern "C" void kernel_launch(void* const* d_in, const int* in_sizes, int n_in,
                              void* d_out, int out_size, void* d_ws, size_t ws_size,
                              hipStream_t stream) {
  (void)in_sizes; (void)n_in; (void)out_size;
  const float* hs = (const float*)d_in[0];
  const float* Wq = (const float*)d_in[3];
  const float* Wk = (const float*)d_in[4];
  const float* Wv = (const float*)d_in[5];
  const float* Wo = (const float*)d_in[6];
  float* out = (float*)d_out;
  char* ws = (char*)d_ws;

  u16* Xb   = (u16*)(ws + 0);          // 16 MB : X bf16; reused as attn output Ao
  u16* Wt   = (u16*)(ws + 16777216);   // 32 MB : WqT, then KV partial arena, then WoT
  u16* WkvT = (u16*)(ws + 50331648);   // 16 MB : [Wk^T;Wv^T]; later P0o
  u16* Qb   = (u16*)(ws + 67108864);   // 16 MB : Q-proj half-0 partial; later P1o
  u16* Kb   = (u16*)(ws + 83886080);   // 4 MB  : K (rope'd) [2048][1024]
  u16* Vtb  = (u16*)(ws + 88080384);   // 4 MB  : V^T [1024][2048]
  float* Tab = (float*)(ws + 92274688);// 1 MB  : RoPE cos/sin table [2048][64][2]
  u16* P1q  = (u16*)(ws + 96468992);   // 16 MB : Q-proj half-1 partial (read by attn)
  u16* PKV  = Wt;                      // KV split-K partial arena (WqT dead post-Q-proj)
  u16* P0o  = WkvT;                    // O-proj half-0 partial (WkvT dead post-KV-proj)
  u16* P1o  = Qb;                      // O-proj half-1 partial (Qb dead post-attn)
  u16* Ao   = Xb;                      // attn output (X dead post-KV-proj)
  if (ws_size < 113246208u) return;

  // fused prep: Wq/Wk/Wv transpose + X cvt + RoPE table
  prep_kernel<<<dim3(14848), 256, 0, stream>>>(Wq, Wk, Wv, Wt, WkvT, hs, Xb, Tab);

  // Q projection: 256^2 split-K=2, bf16 partials (combine+rope fused into attn)
  gemm256_kernel<<<dim3(16, 8, 2), 512, 0, stream>>>(Xb, Wt, Qb, P1q, 4096, 4096, 2048);

  // fused K+V projection: 256^2 split-K=4 into partial arena (WqT now dead)
  gemm_kv256_kernel<<<dim3(8, 8, 4), 512, 0, stream>>>(Xb, WkvT, PKV, 4096, 1024);
  // combine partials + K RoPE (table)
  combine_kv_rope_kernel<<<dim3(1536), 256, 0, stream>>>(PKV, Kb, Vtb, Tab);

  // merged: attention (Q combine + RoPE fused, load-balanced) -> Ao, plus Wo transpose -> Wt
  attn_tconv_kernel<<<dim3(2560), 512, 0, stream>>>(Qb, P1q, Kb, Vtb, Tab, Ao, Wo, Wt);

  // output projection: 256^2 split-K=2 (bf16 partials), combine to f32
  gemm256_kernel<<<dim3(16, 8, 2), 512, 0, stream>>>(Ao, Wt, P0o, P1o, 4096, 4096, 2048);
  combine2_f32_kernel<<<dim3(4096), 256, 0, stream>>>(out, P0o, P1o, 1048576);
}